// Round 1
// baseline (8239.996 us; speedup 1.0000x reference)
//
#include <hip/hip_runtime.h>
#include <cmath>

// ---- model constants ----
constexpr int kB = 4, kN = 640, kD = 1024, kH = 16, kDH = 64;
constexpr int kDepth = 6, kMLP = 2048, kPD = 3072, kNC = 1000, kM = 18;
constexpr float kScale = 0.125f;        // DH^-0.5
constexpr float kNegInf = -3.4028235e38f;

// ============================================================
// LayerNorm over last dim K, one block (256 threads) per row.
// ============================================================
__global__ __launch_bounds__(256) void ln_kernel(
    const float* __restrict__ in, float* __restrict__ out,
    const float* __restrict__ g, const float* __restrict__ b, int K) {
  const int row = blockIdx.x;
  const float* x = in + (size_t)row * K;
  float* o = out + (size_t)row * K;
  float s = 0.f, s2 = 0.f;
  for (int d = threadIdx.x; d < K; d += 256) { float v = x[d]; s += v; s2 += v * v; }
#pragma unroll
  for (int off = 32; off; off >>= 1) { s += __shfl_down(s, off); s2 += __shfl_down(s2, off); }
  __shared__ float ls[4], ls2[4];
  __shared__ float sm, sr;
  const int wid = threadIdx.x >> 6, lane = threadIdx.x & 63;
  if (lane == 0) { ls[wid] = s; ls2[wid] = s2; }
  __syncthreads();
  if (threadIdx.x == 0) {
    float a = ls[0] + ls[1] + ls[2] + ls[3];
    float a2 = ls2[0] + ls2[1] + ls2[2] + ls2[3];
    float mean = a / K;
    float var = a2 / K - mean * mean;
    sm = mean; sr = rsqrtf(var + 1e-5f);
  }
  __syncthreads();
  const float mean = sm, r = sr;
  for (int d = threadIdx.x; d < K; d += 256)
    o[d] = (x[d] - mean) * r * g[d] + b[d];
}

// ============================================================
// Per-head LayerNorm (dim DH=64), in place. One wave per (outer, head).
// p layout: [outer][stride] with head h at offset h*64.
// ============================================================
__global__ __launch_bounds__(64) void headln_kernel(
    float* __restrict__ p, int stride,
    const float* __restrict__ g, const float* __restrict__ b) {
  const int blk = blockIdx.x;
  const int outer = blk / kH, h = blk % kH;
  float* x = p + (size_t)outer * stride + h * kDH;
  const int lane = threadIdx.x;
  float v = x[lane];
  float s = v, s2 = v * v;
#pragma unroll
  for (int off = 32; off; off >>= 1) { s += __shfl_xor(s, off); s2 += __shfl_xor(s2, off); }
  const float m = s * (1.f / kDH);
  const float var = s2 * (1.f / kDH) - m * m;
  const float r = rsqrtf(var + 1e-5f);
  x[lane] = (v - m) * r * g[lane] + b[lane];
}

// ============================================================
// Tiled f32 GEMM: C[Mr,Ncol] = A[Mr,K] @ W[K,Ncol] (+bias)(+res)
// resmode: 0 none, 1 full-matrix residual, 2 broadcast-vector residual
// 64x64 tile, TK=16, 256 threads, 4x4 microtile.
// ============================================================
__global__ __launch_bounds__(256) void gemm_kernel(
    const float* __restrict__ A, const float* __restrict__ W,
    float* __restrict__ C, const float* __restrict__ bias,
    const float* __restrict__ res, int Mr, int K, int Ncol, int resmode) {
  __shared__ float As[16][64];
  __shared__ float Bs[16][65];
  const int tx = threadIdx.x, ty = threadIdx.y;
  const int tid = ty * 16 + tx;
  const int row0 = blockIdx.y * 64, col0 = blockIdx.x * 64;
  const int tr = ty * 4, tc = tx * 4;
  float acc[4][4] = {};
  const int ea = tid * 4;
  const int am = ea >> 4, ak = ea & 15;   // A: kk-fast (4 contiguous k)
  const int bn = ea & 63, bk = ea >> 6;   // B: n-fast (4 contiguous n)
  for (int k0 = 0; k0 < K; k0 += 16) {
    float4 av;
    if (row0 + am < Mr)
      av = *(const float4*)(A + (size_t)(row0 + am) * K + (k0 + ak));
    else
      av = float4{0.f, 0.f, 0.f, 0.f};
    As[ak + 0][am] = av.x; As[ak + 1][am] = av.y;
    As[ak + 2][am] = av.z; As[ak + 3][am] = av.w;
    const float* wp = W + (size_t)(k0 + bk) * Ncol + (col0 + bn);
    if (col0 + bn + 3 < Ncol) {
      float4 wv = *(const float4*)wp;
      Bs[bk][bn] = wv.x; Bs[bk][bn + 1] = wv.y;
      Bs[bk][bn + 2] = wv.z; Bs[bk][bn + 3] = wv.w;
    } else {
      for (int t = 0; t < 4; ++t)
        Bs[bk][bn + t] = (col0 + bn + t < Ncol) ? wp[t] : 0.f;
    }
    __syncthreads();
#pragma unroll
    for (int kk = 0; kk < 16; ++kk) {
      const float a0 = As[kk][tr], a1 = As[kk][tr + 1], a2 = As[kk][tr + 2], a3 = As[kk][tr + 3];
      const float b0 = Bs[kk][tc], b1 = Bs[kk][tc + 1], b2 = Bs[kk][tc + 2], b3 = Bs[kk][tc + 3];
      acc[0][0] += a0 * b0; acc[0][1] += a0 * b1; acc[0][2] += a0 * b2; acc[0][3] += a0 * b3;
      acc[1][0] += a1 * b0; acc[1][1] += a1 * b1; acc[1][2] += a1 * b2; acc[1][3] += a1 * b3;
      acc[2][0] += a2 * b0; acc[2][1] += a2 * b1; acc[2][2] += a2 * b2; acc[2][3] += a2 * b3;
      acc[3][0] += a3 * b0; acc[3][1] += a3 * b1; acc[3][2] += a3 * b2; acc[3][3] += a3 * b3;
    }
    __syncthreads();
  }
#pragma unroll
  for (int i = 0; i < 4; ++i) {
    const int r = row0 + tr + i;
    if (r >= Mr) break;
#pragma unroll
    for (int j = 0; j < 4; ++j) {
      const int c = col0 + tc + j;
      if (c >= Ncol) continue;
      float v = acc[i][j];
      if (bias) v += bias[c];
      if (resmode == 1) v += res[(size_t)r * Ncol + c];
      else if (resmode == 2) v += res[c];
      C[(size_t)r * Ncol + c] = v;
    }
  }
}

// ============================================================
// x = in + pos_h[h_idx] + pos_w[w_idx], elementwise over [B,N,D]
// ============================================================
__global__ __launch_bounds__(256) void posadd_kernel(
    const float* __restrict__ in, float* __restrict__ out,
    const float* __restrict__ ph, const float* __restrict__ pw,
    const int* __restrict__ hi, const int* __restrict__ wi) {
  const size_t idx = (size_t)blockIdx.x * 256 + threadIdx.x;
  if (idx >= (size_t)kB * kN * kD) return;
  const int d = (int)(idx & (kD - 1));
  const int bnidx = (int)(idx >> 10);
  out[idx] = in[idx] + ph[hi[bnidx] * kD + d] + pw[wi[bnidx] * kD + d];
}

// ============================================================
// exact GELU in place
// ============================================================
__global__ __launch_bounds__(256) void gelu_kernel(float* __restrict__ p, size_t n) {
  const size_t i = (size_t)blockIdx.x * 256 + threadIdx.x;
  if (i < n) {
    const float v = p[i];
    p[i] = 0.5f * v * (1.f + erff(v * 0.70710678118654752f));
  }
}

// ============================================================
// Self-attention: one wave per (b,h,i) row. Scores over all N j's
// in LDS, masked by image_ids, wave softmax, then lane-per-dim PV.
// q: [B,N,H*DH] (head-LN'd), kv: [B,N,2*H*DH] (k head-LN'd).
// o: [B,N,H*DH]
// ============================================================
__global__ __launch_bounds__(64) void attn_kernel(
    const float* __restrict__ q, const float* __restrict__ kv,
    const int* __restrict__ ids, float* __restrict__ o) {
  const int blk = blockIdx.x;
  const int i = blk % kN;
  const int bh = blk / kN;
  const int h = bh % kH, b = bh / kH;
  const int lane = threadIdx.x;
  __shared__ float sc[kN];
  __shared__ float qs[kDH];
  qs[lane] = q[((size_t)(b * kN + i)) * (kH * kDH) + h * kDH + lane];
  const int myid = ids[b * kN + i];
  __syncthreads();
  // phase 1: scores
  float mymax = kNegInf;
  for (int j = lane; j < kN; j += 64) {
    const int idj = ids[b * kN + j];
    float s;
    if (idj == myid) {
      const float* krow = kv + ((size_t)(b * kN + j)) * (2 * kH * kDH) + h * kDH;
      float dot = 0.f;
#pragma unroll
      for (int d = 0; d < kDH; ++d) dot += qs[d] * krow[d];
      s = dot * kScale;
    } else {
      s = kNegInf;
    }
    sc[j] = s;
    mymax = fmaxf(mymax, s);
  }
#pragma unroll
  for (int off = 32; off; off >>= 1) mymax = fmaxf(mymax, __shfl_xor(mymax, off));
  // phase 1b: exp + sum (each lane touches only its own sc[j])
  float mysum = 0.f;
  for (int j = lane; j < kN; j += 64) {
    const float p = __expf(sc[j] - mymax);
    sc[j] = p;
    mysum += p;
  }
#pragma unroll
  for (int off = 32; off; off >>= 1) mysum += __shfl_xor(mysum, off);
  const float inv = 1.f / mysum;
  __syncthreads();
  // phase 2: lane = output dim d
  float acc = 0.f;
  const float* vbase = kv + ((size_t)(b * kN)) * (2 * kH * kDH) + kH * kDH + h * kDH + lane;
  for (int j = 0; j < kN; ++j)
    acc += sc[j] * vbase[(size_t)j * (2 * kH * kDH)];
  o[((size_t)(b * kN + i)) * (kH * kDH) + h * kDH + lane] = acc * inv;
}

// ============================================================
// Attention pooling: one wave per (b,m,h). Query is the single
// head-LN'd pooled query vector qp[H*DH]; mask is ids[b,j]==m.
// o: [B*M, H*DH]
// ============================================================
__global__ __launch_bounds__(64) void poolattn_kernel(
    const float* __restrict__ qp, const float* __restrict__ kv,
    const int* __restrict__ ids, float* __restrict__ o) {
  const int blk = blockIdx.x;
  const int h = blk % kH;
  const int bm = blk / kH;
  const int m = bm % kM, b = bm / kM;
  const int lane = threadIdx.x;
  __shared__ float sc[kN];
  __shared__ float qs[kDH];
  qs[lane] = qp[h * kDH + lane];
  __syncthreads();
  float mymax = kNegInf;
  for (int j = lane; j < kN; j += 64) {
    const int idj = ids[b * kN + j];
    float s;
    if (idj == m) {
      const float* krow = kv + ((size_t)(b * kN + j)) * (2 * kH * kDH) + h * kDH;
      float dot = 0.f;
#pragma unroll
      for (int d = 0; d < kDH; ++d) dot += qs[d] * krow[d];
      s = dot * kScale;
    } else {
      s = kNegInf;
    }
    sc[j] = s;
    mymax = fmaxf(mymax, s);
  }
#pragma unroll
  for (int off = 32; off; off >>= 1) mymax = fmaxf(mymax, __shfl_xor(mymax, off));
  float mysum = 0.f;
  for (int j = lane; j < kN; j += 64) {
    const float p = __expf(sc[j] - mymax);
    sc[j] = p;
    mysum += p;
  }
#pragma unroll
  for (int off = 32; off; off >>= 1) mysum += __shfl_xor(mysum, off);
  const float inv = 1.f / mysum;
  __syncthreads();
  float acc = 0.f;
  const float* vbase = kv + ((size_t)(b * kN)) * (2 * kH * kDH) + kH * kDH + h * kDH + lane;
  for (int j = 0; j < kN; ++j)
    acc += sc[j] * vbase[(size_t)j * (2 * kH * kDH)];
  o[((size_t)(b * kM + m)) * (kH * kDH) + h * kDH + lane] = acc * inv;
}

// ============================================================
// driver
// ============================================================
extern "C" void kernel_launch(void* const* d_in, const int* in_sizes, int n_in,
                              void* d_out, int out_size, void* d_ws, size_t ws_size,
                              hipStream_t stream) {
  const float* patches  = (const float*)d_in[0];
  const float* pe_ln1_g = (const float*)d_in[1];
  const float* pe_ln1_b = (const float*)d_in[2];
  const float* W_pe     = (const float*)d_in[3];
  const float* b_pe     = (const float*)d_in[4];
  const float* pe_ln2_g = (const float*)d_in[5];
  const float* pe_ln2_b = (const float*)d_in[6];
  const float* pos_h    = (const float*)d_in[7];
  const float* pos_w    = (const float*)d_in[8];
  const float* ln1_g    = (const float*)d_in[9];
  const float* ln1_b    = (const float*)d_in[10];
  const float* qn_g     = (const float*)d_in[11];
  const float* qn_b     = (const float*)d_in[12];
  const float* kn_g     = (const float*)d_in[13];
  const float* kn_b     = (const float*)d_in[14];
  const float* Wq       = (const float*)d_in[15];
  const float* Wkv      = (const float*)d_in[16];
  const float* Wo       = (const float*)d_in[17];
  const float* ln2_g    = (const float*)d_in[18];
  const float* ln2_b    = (const float*)d_in[19];
  const float* W1       = (const float*)d_in[20];
  const float* b1       = (const float*)d_in[21];
  const float* W2       = (const float*)d_in[22];
  const float* b2       = (const float*)d_in[23];
  const float* fin_g    = (const float*)d_in[24];
  const float* fin_b    = (const float*)d_in[25];
  const float* pool_q   = (const float*)d_in[26];
  const float* pl_ln_g  = (const float*)d_in[27];
  const float* pl_ln_b  = (const float*)d_in[28];
  const float* pl_qn_g  = (const float*)d_in[29];
  const float* pl_qn_b  = (const float*)d_in[30];
  const float* pl_kn_g  = (const float*)d_in[31];
  const float* pl_kn_b  = (const float*)d_in[32];
  const float* pl_Wq    = (const float*)d_in[33];
  const float* pl_Wkv   = (const float*)d_in[34];
  const float* pl_Wo    = (const float*)d_in[35];
  const float* head_g   = (const float*)d_in[36];
  const float* head_b   = (const float*)d_in[37];
  const float* W_head   = (const float*)d_in[38];
  const float* b_head   = (const float*)d_in[39];
  const int* h_idx      = (const int*)d_in[40];
  const int* w_idx      = (const int*)d_in[41];
  const int* image_ids  = (const int*)d_in[42];
  float* out = (float*)d_out;

  // workspace layout (floats). scratch window (4*SZ) is time-shared:
  //   embed phase : pln (3*SZ)
  //   attn phase  : qb (1*SZ) | kvb (2*SZ) | attno (1*SZ)
  //   mlp phase   : h1 (2*SZ)
  //   pool phase  : kvb (2*SZ)
  float* ws = (float*)d_ws;
  const size_t SZ = (size_t)kB * kN * kD;        // 2,621,440
  float* x       = ws;
  float* xn      = ws + SZ;
  float* scratch = ws + 2 * SZ;
  float* qb      = scratch;
  float* kvb     = scratch + SZ;
  float* attno   = scratch + 3 * SZ;
  float* h1      = scratch;
  float* pln     = scratch;
  float* smalls  = ws + 6 * SZ;
  float* qn_vec  = smalls;            // D
  float* qpool   = smalls + kD;       // D
  float* opool   = smalls + 2 * kD;                     // B*M*D
  float* pooled  = opool + (size_t)kB * kM * kD;        // B*M*D
  float* pooledn = pooled + (size_t)kB * kM * kD;       // B*M*D

  const int BN = kB * kN;                 // 2560 rows
  const dim3 t256(16, 16);

  auto gemm = [&](const float* A, const float* Wt, float* Cm, const float* bias,
                  const float* res, int Mr, int K, int Ncol, int resmode) {
    dim3 g((Ncol + 63) / 64, (Mr + 63) / 64);
    gemm_kernel<<<g, t256, 0, stream>>>(A, Wt, Cm, bias, res, Mr, K, Ncol, resmode);
  };

  // ---- patch embedding ----
  ln_kernel<<<BN, 256, 0, stream>>>(patches, pln, pe_ln1_g, pe_ln1_b, kPD);
  gemm(pln, W_pe, x, b_pe, nullptr, BN, kPD, kD, 0);
  ln_kernel<<<BN, 256, 0, stream>>>(x, xn, pe_ln2_g, pe_ln2_b, kD);
  posadd_kernel<<<(BN * kD) / 256, 256, 0, stream>>>(xn, x, pos_h, pos_w, h_idx, w_idx);

  // ---- transformer layers ----
  for (int l = 0; l < kDepth; ++l) {
    ln_kernel<<<BN, 256, 0, stream>>>(x, xn, ln1_g + (size_t)l * kD, ln1_b + (size_t)l * kD, kD);
    gemm(xn, Wq + (size_t)l * kD * kD, qb, nullptr, nullptr, BN, kD, kD, 0);
    gemm(xn, Wkv + (size_t)l * kD * 2 * kD, kvb, nullptr, nullptr, BN, kD, 2 * kD, 0);
    headln_kernel<<<BN * kH, 64, 0, stream>>>(qb, kD, qn_g + (size_t)l * kDH, qn_b + (size_t)l * kDH);
    headln_kernel<<<BN * kH, 64, 0, stream>>>(kvb, 2 * kD, kn_g + (size_t)l * kDH, kn_b + (size_t)l * kDH);
    attn_kernel<<<kB * kH * kN, 64, 0, stream>>>(qb, kvb, image_ids, attno);
    gemm(attno, Wo + (size_t)l * kD * kD, x, nullptr, x, BN, kD, kD, 1);
    ln_kernel<<<BN, 256, 0, stream>>>(x, xn, ln2_g + (size_t)l * kD, ln2_b + (size_t)l * kD, kD);
    gemm(xn, W1 + (size_t)l * kD * kMLP, h1, b1 + (size_t)l * kMLP, nullptr, BN, kD, kMLP, 0);
    gelu_kernel<<<(BN * kMLP) / 256, 256, 0, stream>>>(h1, (size_t)BN * kMLP);
    gemm(h1, W2 + (size_t)l * kMLP * kD, x, b2 + (size_t)l * kD, x, BN, kMLP, kD, 1);
  }

  // ---- final LN (context for pooling) ----
  ln_kernel<<<BN, 256, 0, stream>>>(x, xn, fin_g, fin_b, kD);

  // ---- attention pooling ----
  ln_kernel<<<1, 256, 0, stream>>>(pool_q, qn_vec, pl_ln_g, pl_ln_b, kD);
  gemm(qn_vec, pl_Wq, qpool, nullptr, nullptr, 1, kD, kD, 0);
  headln_kernel<<<kH, 64, 0, stream>>>(qpool, kD, pl_qn_g, pl_qn_b);
  gemm(xn, pl_Wkv, kvb, nullptr, nullptr, BN, kD, 2 * kD, 0);
  headln_kernel<<<BN * kH, 64, 0, stream>>>(kvb, 2 * kD, pl_kn_g, pl_kn_b);
  poolattn_kernel<<<kB * kM * kH, 64, 0, stream>>>(qpool, kvb, image_ids, opool);
  gemm(opool, pl_Wo, pooled, nullptr, pool_q, kB * kM, kD, kD, 2);

  // ---- classifier head ----
  ln_kernel<<<kB * kM, 256, 0, stream>>>(pooled, pooledn, head_g, head_b, kD);
  gemm(pooledn, W_head, out, b_head, nullptr, kB * kM, kD, kNC, 0);
}

// Round 2
// 2828.037 us; speedup vs baseline: 2.9137x; 2.9137x over previous
//
#include <hip/hip_runtime.h>
#include <cmath>

// ---- model constants ----
constexpr int kB = 4, kN = 640, kD = 1024, kH = 16, kDH = 64;
constexpr int kDepth = 6, kMLP = 2048, kPD = 3072, kNC = 1000, kM = 18;
constexpr float kScale = 0.125f;        // DH^-0.5
constexpr float kNegInf = -3.4028235e38f;

typedef __bf16 bf16;
typedef __attribute__((ext_vector_type(8))) __bf16 bf16x8;
typedef __attribute__((ext_vector_type(4))) float f32x4;

// ============================================================
// LayerNorm over last dim K, one block (256 threads) per row.
// Output type templated (float or bf16).
// ============================================================
template <typename OT>
__global__ __launch_bounds__(256) void ln_kernel(
    const float* __restrict__ in, OT* __restrict__ out,
    const float* __restrict__ g, const float* __restrict__ b, int K) {
  const int row = blockIdx.x;
  const float* x = in + (size_t)row * K;
  OT* o = out + (size_t)row * K;
  float s = 0.f, s2 = 0.f;
  for (int d = threadIdx.x; d < K; d += 256) { float v = x[d]; s += v; s2 += v * v; }
#pragma unroll
  for (int off = 32; off; off >>= 1) { s += __shfl_down(s, off); s2 += __shfl_down(s2, off); }
  __shared__ float ls[4], ls2[4];
  __shared__ float sm, sr;
  const int wid = threadIdx.x >> 6, lane = threadIdx.x & 63;
  if (lane == 0) { ls[wid] = s; ls2[wid] = s2; }
  __syncthreads();
  if (threadIdx.x == 0) {
    float a = ls[0] + ls[1] + ls[2] + ls[3];
    float a2 = ls2[0] + ls2[1] + ls2[2] + ls2[3];
    float mean = a / K;
    float var = a2 / K - mean * mean;
    sm = mean; sr = rsqrtf(var + 1e-5f);
  }
  __syncthreads();
  const float mean = sm, r = sr;
  for (int d = threadIdx.x; d < K; d += 256)
    o[d] = (OT)((x[d] - mean) * r * g[d] + b[d]);
}

// ============================================================
// Fused pe_ln2 + factorized pos-embed add. f32 out (residual base).
// ============================================================
__global__ __launch_bounds__(256) void ln_pos_kernel(
    const float* __restrict__ in, float* __restrict__ out,
    const float* __restrict__ g, const float* __restrict__ b,
    const float* __restrict__ ph, const float* __restrict__ pw,
    const int* __restrict__ hi, const int* __restrict__ wi) {
  const int row = blockIdx.x;
  const float* x = in + (size_t)row * kD;
  float* o = out + (size_t)row * kD;
  float s = 0.f, s2 = 0.f;
  for (int d = threadIdx.x; d < kD; d += 256) { float v = x[d]; s += v; s2 += v * v; }
#pragma unroll
  for (int off = 32; off; off >>= 1) { s += __shfl_down(s, off); s2 += __shfl_down(s2, off); }
  __shared__ float ls[4], ls2[4];
  __shared__ float sm, sr;
  const int wid = threadIdx.x >> 6, lane = threadIdx.x & 63;
  if (lane == 0) { ls[wid] = s; ls2[wid] = s2; }
  __syncthreads();
  if (threadIdx.x == 0) {
    float a = ls[0] + ls[1] + ls[2] + ls[3];
    float a2 = ls2[0] + ls2[1] + ls2[2] + ls2[3];
    float mean = a / kD;
    float var = a2 / kD - mean * mean;
    sm = mean; sr = rsqrtf(var + 1e-5f);
  }
  __syncthreads();
  const float mean = sm, r = sr;
  const float* phr = ph + (size_t)hi[row] * kD;
  const float* pwr = pw + (size_t)wi[row] * kD;
  for (int d = threadIdx.x; d < kD; d += 256)
    o[d] = (x[d] - mean) * r * g[d] + b[d] + phr[d] + pwr[d];
}

// ============================================================
// Per-head LayerNorm (dim DH=64), in place f32. One wave per (outer, head).
// ============================================================
__global__ __launch_bounds__(64) void headln_kernel(
    float* __restrict__ p, int stride,
    const float* __restrict__ g, const float* __restrict__ b) {
  const int blk = blockIdx.x;
  const int outer = blk / kH, h = blk % kH;
  float* x = p + (size_t)outer * stride + h * kDH;
  const int lane = threadIdx.x;
  float v = x[lane];
  float s = v, s2 = v * v;
#pragma unroll
  for (int off = 32; off; off >>= 1) { s += __shfl_xor(s, off); s2 += __shfl_xor(s2, off); }
  const float m = s * (1.f / kDH);
  const float var = s2 * (1.f / kDH) - m * m;
  const float r = rsqrtf(var + 1e-5f);
  x[lane] = (v - m) * r * g[lane] + b[lane];
}

// ============================================================
// Weight transpose: f32 W[K][N] -> bf16 WT[N][K].
// ============================================================
__global__ __launch_bounds__(256) void wt_kernel(
    const float* __restrict__ W, bf16* __restrict__ WT, int K, int Ncol) {
  __shared__ float s[32][33];
  const int n0 = blockIdx.x * 32, k0 = blockIdx.y * 32;
  const int tx = threadIdx.x & 31, ty = threadIdx.x >> 5;
#pragma unroll
  for (int i = 0; i < 4; ++i) {
    const int k = ty + i * 8;
    s[k][tx] = W[(size_t)(k0 + k) * Ncol + (n0 + tx)];
  }
  __syncthreads();
#pragma unroll
  for (int i = 0; i < 4; ++i) {
    const int n = ty + i * 8;
    WT[(size_t)(n0 + n) * K + (k0 + tx)] = (bf16)s[tx][n];
  }
}

// ============================================================
// bf16 MFMA GEMM: C[M,N] = A[M,K](bf16) @ WT[N,K](bf16)^T
// BM=64, BN=128, BK=32. 256 threads = 4 waves, each wave 64x32 cols.
// Epilogue: +bias, +res(f32), optional GELU, out f32 OR bf16.
// M multiple of 64, N multiple of 128, K multiple of 32 (guaranteed).
// ============================================================
template <bool OUT_BF, bool GELU>
__global__ __launch_bounds__(256) void gemm_bf_kernel(
    const bf16* __restrict__ A, const bf16* __restrict__ WT,
    float* __restrict__ Cf, bf16* __restrict__ Cb,
    const float* __restrict__ bias, const float* __restrict__ res,
    int K, int Ncol) {
  __shared__ __align__(16) bf16 As[64][40];
  __shared__ __align__(16) bf16 Bs[128][40];
  const int tid = threadIdx.x;
  const int lane = tid & 63, wid = tid >> 6;
  const int row0 = blockIdx.y * 64, col0 = blockIdx.x * 128;
  f32x4 acc[4][2] = {};
  const int am = tid >> 2, ako = (tid & 3) * 8;   // A: 256 chunks of 8 bf16
  const int fr = lane & 15, fg = (lane >> 4) * 8;
  for (int k0 = 0; k0 < K; k0 += 32) {
    *(bf16x8*)&As[am][ako] =
        *(const bf16x8*)(A + (size_t)(row0 + am) * K + k0 + ako);
#pragma unroll
    for (int it = 0; it < 2; ++it) {
      const int c = it * 256 + tid;
      const int n = c >> 2, ko = (c & 3) * 8;
      *(bf16x8*)&Bs[n][ko] =
          *(const bf16x8*)(WT + (size_t)(col0 + n) * K + k0 + ko);
    }
    __syncthreads();
    bf16x8 af[4], bfr[2];
#pragma unroll
    for (int mi = 0; mi < 4; ++mi) af[mi] = *(const bf16x8*)&As[mi * 16 + fr][fg];
#pragma unroll
    for (int ni = 0; ni < 2; ++ni) bfr[ni] = *(const bf16x8*)&Bs[wid * 32 + ni * 16 + fr][fg];
#pragma unroll
    for (int mi = 0; mi < 4; ++mi)
#pragma unroll
      for (int ni = 0; ni < 2; ++ni)
        acc[mi][ni] = __builtin_amdgcn_mfma_f32_16x16x32_bf16(af[mi], bfr[ni], acc[mi][ni], 0, 0, 0);
    __syncthreads();
  }
  // epilogue: D row = mi*16 + (lane>>4)*4 + r, col = wid*32 + ni*16 + (lane&15)
  const int r4 = (lane >> 4) * 4;
  const int cc0 = col0 + wid * 32 + (lane & 15);
#pragma unroll
  for (int mi = 0; mi < 4; ++mi) {
#pragma unroll
    for (int ni = 0; ni < 2; ++ni) {
      const int cc = cc0 + ni * 16;
#pragma unroll
      for (int r = 0; r < 4; ++r) {
        const int rr = row0 + mi * 16 + r4 + r;
        float v = acc[mi][ni][r];
        if (bias) v += bias[cc];
        if (res) v += res[(size_t)rr * Ncol + cc];
        if (GELU) v = 0.5f * v * (1.f + erff(v * 0.70710678118654752f));
        if (OUT_BF) Cb[(size_t)rr * Ncol + cc] = (bf16)v;
        else        Cf[(size_t)rr * Ncol + cc] = v;
      }
    }
  }
}

// ============================================================
// f32 GEMM for the small tail ops (pool q, pool out, head).
// ============================================================
__global__ __launch_bounds__(256) void gemm_kernel(
    const float* __restrict__ A, const float* __restrict__ W,
    float* __restrict__ C, const float* __restrict__ bias,
    const float* __restrict__ res, int Mr, int K, int Ncol, int resmode) {
  __shared__ float As[16][64];
  __shared__ float Bs[16][65];
  const int tx = threadIdx.x, ty = threadIdx.y;
  const int tid = ty * 16 + tx;
  const int row0 = blockIdx.y * 64, col0 = blockIdx.x * 64;
  const int tr = ty * 4, tc = tx * 4;
  float acc[4][4] = {};
  const int ea = tid * 4;
  const int am = ea >> 4, ak = ea & 15;
  const int bn = ea & 63, bk = ea >> 6;
  for (int k0 = 0; k0 < K; k0 += 16) {
    float4 av;
    if (row0 + am < Mr)
      av = *(const float4*)(A + (size_t)(row0 + am) * K + (k0 + ak));
    else
      av = float4{0.f, 0.f, 0.f, 0.f};
    As[ak + 0][am] = av.x; As[ak + 1][am] = av.y;
    As[ak + 2][am] = av.z; As[ak + 3][am] = av.w;
    const float* wp = W + (size_t)(k0 + bk) * Ncol + (col0 + bn);
    if (col0 + bn + 3 < Ncol) {
      float4 wv = *(const float4*)wp;
      Bs[bk][bn] = wv.x; Bs[bk][bn + 1] = wv.y;
      Bs[bk][bn + 2] = wv.z; Bs[bk][bn + 3] = wv.w;
    } else {
      for (int t = 0; t < 4; ++t)
        Bs[bk][bn + t] = (col0 + bn + t < Ncol) ? wp[t] : 0.f;
    }
    __syncthreads();
#pragma unroll
    for (int kk = 0; kk < 16; ++kk) {
      const float a0 = As[kk][tr], a1 = As[kk][tr + 1], a2 = As[kk][tr + 2], a3 = As[kk][tr + 3];
      const float b0 = Bs[kk][tc], b1 = Bs[kk][tc + 1], b2 = Bs[kk][tc + 2], b3 = Bs[kk][tc + 3];
      acc[0][0] += a0 * b0; acc[0][1] += a0 * b1; acc[0][2] += a0 * b2; acc[0][3] += a0 * b3;
      acc[1][0] += a1 * b0; acc[1][1] += a1 * b1; acc[1][2] += a1 * b2; acc[1][3] += a1 * b3;
      acc[2][0] += a2 * b0; acc[2][1] += a2 * b1; acc[2][2] += a2 * b2; acc[2][3] += a2 * b3;
      acc[3][0] += a3 * b0; acc[3][1] += a3 * b1; acc[3][2] += a3 * b2; acc[3][3] += a3 * b3;
    }
    __syncthreads();
  }
#pragma unroll
  for (int i = 0; i < 4; ++i) {
    const int r = row0 + tr + i;
    if (r >= Mr) break;
#pragma unroll
    for (int j = 0; j < 4; ++j) {
      const int c = col0 + tc + j;
      if (c >= Ncol) continue;
      float v = acc[i][j];
      if (bias) v += bias[c];
      if (resmode == 1) v += res[(size_t)r * Ncol + c];
      else if (resmode == 2) v += res[c];
      C[(size_t)r * Ncol + c] = v;
    }
  }
}

// ============================================================
// Self-attention over packed qkv [B,N,3072] (q|k|v each 1024).
// One wave per (b,h,i). Exploits contiguous image blocks: finds
// [jlo,jhi) and only iterates that span in exp/PV. Output bf16.
// ============================================================
__global__ __launch_bounds__(64) void attn_kernel(
    const float* __restrict__ qkv, const int* __restrict__ ids,
    bf16* __restrict__ o) {
  const int blk = blockIdx.x;
  const int i = blk % kN;
  const int bh = blk / kN;
  const int h = bh % kH, b = bh / kH;
  const int lane = threadIdx.x;
  __shared__ float sc[kN];
  __shared__ float qs[kDH];
  qs[lane] = qkv[((size_t)(b * kN + i)) * 3072 + h * kDH + lane];
  const int myid = ids[b * kN + i];
  __syncthreads();
  float mymax = kNegInf;
  int jmn = kN, jmx = -1;
  for (int j = lane; j < kN; j += 64) {
    const int idj = ids[b * kN + j];
    float s;
    if (idj == myid) {
      const float* krow = qkv + ((size_t)(b * kN + j)) * 3072 + 1024 + h * kDH;
      float dot = 0.f;
#pragma unroll
      for (int d = 0; d < kDH; ++d) dot += qs[d] * krow[d];
      s = dot * kScale;
      jmn = min(jmn, j); jmx = max(jmx, j);
    } else {
      s = kNegInf;
    }
    sc[j] = s;
    mymax = fmaxf(mymax, s);
  }
#pragma unroll
  for (int off = 32; off; off >>= 1) {
    mymax = fmaxf(mymax, __shfl_xor(mymax, off));
    jmn = min(jmn, __shfl_xor(jmn, off));
    jmx = max(jmx, __shfl_xor(jmx, off));
  }
  const int jlo = jmn, jhi = jmx + 1;
  float mysum = 0.f;
  for (int j = jlo + lane; j < jhi; j += 64) {
    const float p = __expf(sc[j] - mymax);
    sc[j] = p;
    mysum += p;
  }
#pragma unroll
  for (int off = 32; off; off >>= 1) mysum += __shfl_xor(mysum, off);
  const float inv = 1.f / mysum;
  __syncthreads();
  float acc = 0.f;
  const float* vptr = qkv + ((size_t)(b * kN + jlo)) * 3072 + 2048 + h * kDH + lane;
  for (int j = jlo; j < jhi; ++j, vptr += 3072) acc += sc[j] * vptr[0];
  o[((size_t)(b * kN + i)) * kD + h * kDH + lane] = (bf16)(acc * inv);
}

// ============================================================
// Attention pooling: one wave per (b,m,h). kv layout [B,N,2048].
// ============================================================
__global__ __launch_bounds__(64) void poolattn_kernel(
    const float* __restrict__ qp, const float* __restrict__ kv,
    const int* __restrict__ ids, float* __restrict__ o) {
  const int blk = blockIdx.x;
  const int h = blk % kH;
  const int bm = blk / kH;
  const int m = bm % kM, b = bm / kM;
  const int lane = threadIdx.x;
  __shared__ float sc[kN];
  __shared__ float qs[kDH];
  qs[lane] = qp[h * kDH + lane];
  __syncthreads();
  float mymax = kNegInf;
  int jmn = kN, jmx = -1;
  for (int j = lane; j < kN; j += 64) {
    const int idj = ids[b * kN + j];
    float s;
    if (idj == m) {
      const float* krow = kv + ((size_t)(b * kN + j)) * (2 * kD) + h * kDH;
      float dot = 0.f;
#pragma unroll
      for (int d = 0; d < kDH; ++d) dot += qs[d] * krow[d];
      s = dot * kScale;
      jmn = min(jmn, j); jmx = max(jmx, j);
    } else {
      s = kNegInf;
    }
    sc[j] = s;
    mymax = fmaxf(mymax, s);
  }
#pragma unroll
  for (int off = 32; off; off >>= 1) {
    mymax = fmaxf(mymax, __shfl_xor(mymax, off));
    jmn = min(jmn, __shfl_xor(jmn, off));
    jmx = max(jmx, __shfl_xor(jmx, off));
  }
  const int jlo = jmn, jhi = jmx + 1;
  float mysum = 0.f;
  for (int j = jlo + lane; j < jhi; j += 64) {
    const float p = __expf(sc[j] - mymax);
    sc[j] = p;
    mysum += p;
  }
#pragma unroll
  for (int off = 32; off; off >>= 1) mysum += __shfl_xor(mysum, off);
  const float inv = 1.f / mysum;
  __syncthreads();
  float acc = 0.f;
  const float* vptr = kv + ((size_t)(b * kN + jlo)) * (2 * kD) + kD + h * kDH + lane;
  for (int j = jlo; j < jhi; ++j, vptr += 2 * kD) acc += sc[j] * vptr[0];
  o[((size_t)(b * kM + m)) * kD + h * kDH + lane] = acc * inv;
}

// ============================================================
// driver
// ============================================================
extern "C" void kernel_launch(void* const* d_in, const int* in_sizes, int n_in,
                              void* d_out, int out_size, void* d_ws, size_t ws_size,
                              hipStream_t stream) {
  const float* patches  = (const float*)d_in[0];
  const float* pe_ln1_g = (const float*)d_in[1];
  const float* pe_ln1_b = (const float*)d_in[2];
  const float* W_pe     = (const float*)d_in[3];
  const float* b_pe     = (const float*)d_in[4];
  const float* pe_ln2_g = (const float*)d_in[5];
  const float* pe_ln2_b = (const float*)d_in[6];
  const float* pos_h    = (const float*)d_in[7];
  const float* pos_w    = (const float*)d_in[8];
  const float* ln1_g    = (const float*)d_in[9];
  const float* ln1_b    = (const float*)d_in[10];
  const float* qn_g     = (const float*)d_in[11];
  const float* qn_b     = (const float*)d_in[12];
  const float* kn_g     = (const float*)d_in[13];
  const float* kn_b     = (const float*)d_in[14];
  const float* Wq       = (const float*)d_in[15];
  const float* Wkv      = (const float*)d_in[16];
  const float* Wo       = (const float*)d_in[17];
  const float* ln2_g    = (const float*)d_in[18];
  const float* ln2_b    = (const float*)d_in[19];
  const float* W1       = (const float*)d_in[20];
  const float* b1       = (const float*)d_in[21];
  const float* W2       = (const float*)d_in[22];
  const float* b2       = (const float*)d_in[23];
  const float* fin_g    = (const float*)d_in[24];
  const float* fin_b    = (const float*)d_in[25];
  const float* pool_q   = (const float*)d_in[26];
  const float* pl_ln_g  = (const float*)d_in[27];
  const float* pl_ln_b  = (const float*)d_in[28];
  const float* pl_qn_g  = (const float*)d_in[29];
  const float* pl_qn_b  = (const float*)d_in[30];
  const float* pl_kn_g  = (const float*)d_in[31];
  const float* pl_kn_b  = (const float*)d_in[32];
  const float* pl_Wq    = (const float*)d_in[33];
  const float* pl_Wkv   = (const float*)d_in[34];
  const float* pl_Wo    = (const float*)d_in[35];
  const float* head_g   = (const float*)d_in[36];
  const float* head_b   = (const float*)d_in[37];
  const float* W_head   = (const float*)d_in[38];
  const float* b_head   = (const float*)d_in[39];
  const int* h_idx      = (const int*)d_in[40];
  const int* w_idx      = (const int*)d_in[41];
  const int* image_ids  = (const int*)d_in[42];
  float* out = (float*)d_out;

  // ---- workspace layout ----
  const size_t SZ = (size_t)kB * kN * kD;        // 2,621,440
  char* p = (char*)d_ws;
  float* x    = (float*)p;           p += SZ * 4;
  bf16*  xnb  = (bf16*)p;            p += SZ * 2;
  char*  scratch = p;                p += (SZ * 14);      // 3.5*SZ floats = 14*SZ bytes
  bf16*  wtbuf = (bf16*)p;           p += (size_t)kPD * kD * 2;   // 3072*1024 bf16
  float* smalls = (float*)p;
  // scratch overlays:
  float* qkvb  = (float*)scratch;                          // [BN][3072] f32
  bf16*  attno = (bf16*)(scratch + SZ * 12);               // [BN][1024] bf16 (after 3*SZ f32)
  bf16*  plnb  = (bf16*)scratch;                           // [BN][3072] bf16 (embed)
  float* emb   = (float*)(scratch + SZ * 8);               // [BN][1024] f32 (embed, after plnb)
  bf16*  h1b   = (bf16*)scratch;                           // [BN][2048] bf16 (mlp)
  float* kvpool = (float*)scratch;                         // [BN][2048] f32 (pool)
  float* qn_vec  = smalls;
  float* qpool   = smalls + kD;
  float* opool   = smalls + 2 * kD;
  float* pooled  = opool + (size_t)kB * kM * kD;
  float* pooledn = pooled + (size_t)kB * kM * kD;

  const int BN = kB * kN;                 // 2560 rows
  const dim3 t256f(16, 16);

  auto gemm32 = [&](const float* A, const float* Wt, float* Cm, const float* bias,
                    const float* res, int Mr, int K, int Ncol, int resmode) {
    dim3 g((Ncol + 63) / 64, (Mr + 63) / 64);
    gemm_kernel<<<g, t256f, 0, stream>>>(A, Wt, Cm, bias, res, Mr, K, Ncol, resmode);
  };
  auto wt = [&](const float* W, bf16* WT, int K, int Ncol) {
    wt_kernel<<<dim3(Ncol / 32, K / 32), 256, 0, stream>>>(W, WT, K, Ncol);
  };

  // ---- patch embedding ----
  ln_kernel<bf16><<<BN, 256, 0, stream>>>(patches, plnb, pe_ln1_g, pe_ln1_b, kPD);
  wt(W_pe, wtbuf, kPD, kD);
  gemm_bf_kernel<false, false><<<dim3(kD / 128, BN / 64), 256, 0, stream>>>(
      plnb, wtbuf, emb, nullptr, b_pe, nullptr, kPD, kD);
  ln_pos_kernel<<<BN, 256, 0, stream>>>(emb, x, pe_ln2_g, pe_ln2_b, pos_h, pos_w, h_idx, w_idx);

  // ---- transformer layers ----
  for (int l = 0; l < kDepth; ++l) {
    ln_kernel<bf16><<<BN, 256, 0, stream>>>(x, xnb, ln1_g + (size_t)l * kD, ln1_b + (size_t)l * kD, kD);
    // fused qkv: WT rows [0,1024) = Wq^T, [1024,3072) = Wkv^T
    wt(Wq + (size_t)l * kD * kD, wtbuf, kD, kD);
    wt(Wkv + (size_t)l * kD * 2 * kD, wtbuf + (size_t)kD * kD, kD, 2 * kD);
    gemm_bf_kernel<false, false><<<dim3(3 * kD / 128, BN / 64), 256, 0, stream>>>(
        xnb, wtbuf, qkvb, nullptr, nullptr, nullptr, kD, 3 * kD);
    headln_kernel<<<BN * kH, 64, 0, stream>>>(qkvb, 3 * kD, qn_g + (size_t)l * kDH, qn_b + (size_t)l * kDH);
    headln_kernel<<<BN * kH, 64, 0, stream>>>(qkvb + kD, 3 * kD, kn_g + (size_t)l * kDH, kn_b + (size_t)l * kDH);
    attn_kernel<<<kB * kH * kN, 64, 0, stream>>>(qkvb, image_ids, attno);
    wt(Wo + (size_t)l * kD * kD, wtbuf, kD, kD);
    gemm_bf_kernel<false, false><<<dim3(kD / 128, BN / 64), 256, 0, stream>>>(
        attno, wtbuf, x, nullptr, nullptr, x, kD, kD);
    ln_kernel<bf16><<<BN, 256, 0, stream>>>(x, xnb, ln2_g + (size_t)l * kD, ln2_b + (size_t)l * kD, kD);
    wt(W1 + (size_t)l * kD * kMLP, wtbuf, kD, kMLP);
    gemm_bf_kernel<true, true><<<dim3(kMLP / 128, BN / 64), 256, 0, stream>>>(
        xnb, wtbuf, nullptr, h1b, b1 + (size_t)l * kMLP, nullptr, kD, kMLP);
    wt(W2 + (size_t)l * kMLP * kD, wtbuf, kMLP, kD);
    gemm_bf_kernel<false, false><<<dim3(kD / 128, BN / 64), 256, 0, stream>>>(
        h1b, wtbuf, x, nullptr, b2 + (size_t)l * kD, x, kMLP, kD);
  }

  // ---- final LN (context for pooling) ----
  ln_kernel<bf16><<<BN, 256, 0, stream>>>(x, xnb, fin_g, fin_b, kD);

  // ---- attention pooling ----
  ln_kernel<float><<<1, 256, 0, stream>>>(pool_q, qn_vec, pl_ln_g, pl_ln_b, kD);
  gemm32(qn_vec, pl_Wq, qpool, nullptr, nullptr, 1, kD, kD, 0);
  headln_kernel<<<kH, 64, 0, stream>>>(qpool, kD, pl_qn_g, pl_qn_b);
  wt(pl_Wkv, wtbuf, kD, 2 * kD);
  gemm_bf_kernel<false, false><<<dim3(2 * kD / 128, BN / 64), 256, 0, stream>>>(
      xnb, wtbuf, kvpool, nullptr, nullptr, nullptr, kD, 2 * kD);
  headln_kernel<<<BN * kH, 64, 0, stream>>>(kvpool, 2 * kD, pl_kn_g, pl_kn_b);
  poolattn_kernel<<<kB * kM * kH, 64, 0, stream>>>(qpool, kvpool, image_ids, opool);
  gemm32(opool, pl_Wo, pooled, nullptr, pool_q, kB * kM, kD, kD, 2);

  // ---- classifier head ----
  ln_kernel<float><<<kB * kM, 256, 0, stream>>>(pooled, pooledn, head_g, head_b, kD);
  gemm32(pooledn, W_head, out, b_head, nullptr, kB * kM, kD, kNC, 0);
}

// Round 3
// 1670.526 us; speedup vs baseline: 4.9326x; 1.6929x over previous
//
#include <hip/hip_runtime.h>
#include <cmath>

// ---- model constants ----
constexpr int kB = 4, kN = 640, kD = 1024, kH = 16, kDH = 64;
constexpr int kDepth = 6, kMLP = 2048, kPD = 3072, kNC = 1000, kM = 18;
constexpr float kScale = 0.125f;        // DH^-0.5
constexpr float kNegInf = -3.4028235e38f;

typedef __bf16 bf16;
typedef __attribute__((ext_vector_type(8))) __bf16 bf16x8;
typedef __attribute__((ext_vector_type(4))) __bf16 bf16x4;
typedef __attribute__((ext_vector_type(4))) float f32x4;

// ============================================================
// LayerNorm over last dim K, one block (256 threads) per row.
// ============================================================
template <typename OT>
__global__ __launch_bounds__(256) void ln_kernel(
    const float* __restrict__ in, OT* __restrict__ out,
    const float* __restrict__ g, const float* __restrict__ b, int K) {
  const int row = blockIdx.x;
  const float* x = in + (size_t)row * K;
  OT* o = out + (size_t)row * K;
  float s = 0.f, s2 = 0.f;
  for (int d = threadIdx.x; d < K; d += 256) { float v = x[d]; s += v; s2 += v * v; }
#pragma unroll
  for (int off = 32; off; off >>= 1) { s += __shfl_down(s, off); s2 += __shfl_down(s2, off); }
  __shared__ float ls[4], ls2[4];
  __shared__ float sm, sr;
  const int wid = threadIdx.x >> 6, lane = threadIdx.x & 63;
  if (lane == 0) { ls[wid] = s; ls2[wid] = s2; }
  __syncthreads();
  if (threadIdx.x == 0) {
    float a = ls[0] + ls[1] + ls[2] + ls[3];
    float a2 = ls2[0] + ls2[1] + ls2[2] + ls2[3];
    float mean = a / K;
    float var = a2 / K - mean * mean;
    sm = mean; sr = rsqrtf(var + 1e-5f);
  }
  __syncthreads();
  const float mean = sm, r = sr;
  for (int d = threadIdx.x; d < K; d += 256)
    o[d] = (OT)((x[d] - mean) * r * g[d] + b[d]);
}

// ============================================================
// Fused pe_ln2 + factorized pos-embed add. f32 out (residual base).
// ============================================================
__global__ __launch_bounds__(256) void ln_pos_kernel(
    const float* __restrict__ in, float* __restrict__ out,
    const float* __restrict__ g, const float* __restrict__ b,
    const float* __restrict__ ph, const float* __restrict__ pw,
    const int* __restrict__ hi, const int* __restrict__ wi) {
  const int row = blockIdx.x;
  const float* x = in + (size_t)row * kD;
  float* o = out + (size_t)row * kD;
  float s = 0.f, s2 = 0.f;
  for (int d = threadIdx.x; d < kD; d += 256) { float v = x[d]; s += v; s2 += v * v; }
#pragma unroll
  for (int off = 32; off; off >>= 1) { s += __shfl_down(s, off); s2 += __shfl_down(s2, off); }
  __shared__ float ls[4], ls2[4];
  __shared__ float sm, sr;
  const int wid = threadIdx.x >> 6, lane = threadIdx.x & 63;
  if (lane == 0) { ls[wid] = s; ls2[wid] = s2; }
  __syncthreads();
  if (threadIdx.x == 0) {
    float a = ls[0] + ls[1] + ls[2] + ls[3];
    float a2 = ls2[0] + ls2[1] + ls2[2] + ls2[3];
    float mean = a / kD;
    float var = a2 / kD - mean * mean;
    sm = mean; sr = rsqrtf(var + 1e-5f);
  }
  __syncthreads();
  const float mean = sm, r = sr;
  const float* phr = ph + (size_t)hi[row] * kD;
  const float* pwr = pw + (size_t)wi[row] * kD;
  for (int d = threadIdx.x; d < kD; d += 256)
    o[d] = (x[d] - mean) * r * g[d] + b[d] + phr[d] + pwr[d];
}

// ============================================================
// Per-head LayerNorm (dim DH=64), in place f32. One wave per (outer, head).
// (Still used by the pooling path.)
// ============================================================
__global__ __launch_bounds__(64) void headln_kernel(
    float* __restrict__ p, int stride,
    const float* __restrict__ g, const float* __restrict__ b) {
  const int blk = blockIdx.x;
  const int outer = blk / kH, h = blk % kH;
  float* x = p + (size_t)outer * stride + h * kDH;
  const int lane = threadIdx.x;
  float v = x[lane];
  float s = v, s2 = v * v;
#pragma unroll
  for (int off = 32; off; off >>= 1) { s += __shfl_xor(s, off); s2 += __shfl_xor(s2, off); }
  const float m = s * (1.f / kDH);
  const float var = s2 * (1.f / kDH) - m * m;
  const float r = rsqrtf(var + 1e-5f);
  x[lane] = (v - m) * r * g[lane] + b[lane];
}

// ============================================================
// Weight transpose: f32 W[K][N] -> bf16 WT[N][K].
// ============================================================
__global__ __launch_bounds__(256) void wt_kernel(
    const float* __restrict__ W, bf16* __restrict__ WT, int K, int Ncol) {
  __shared__ float s[32][33];
  const int n0 = blockIdx.x * 32, k0 = blockIdx.y * 32;
  const int tx = threadIdx.x & 31, ty = threadIdx.x >> 5;
#pragma unroll
  for (int i = 0; i < 4; ++i) {
    const int k = ty + i * 8;
    s[k][tx] = W[(size_t)(k0 + k) * Ncol + (n0 + tx)];
  }
  __syncthreads();
#pragma unroll
  for (int i = 0; i < 4; ++i) {
    const int n = ty + i * 8;
    WT[(size_t)(n0 + n) * K + (k0 + tx)] = (bf16)s[tx][n];
  }
}

// ============================================================
// bf16 MFMA GEMM: C[M,N] = A[M,K](bf16) @ WT[N,K](bf16)^T
// BM=64, BN=128, BK=32. 256 threads = 4 waves.
// ============================================================
template <bool OUT_BF, bool GELU>
__global__ __launch_bounds__(256) void gemm_bf_kernel(
    const bf16* __restrict__ A, const bf16* __restrict__ WT,
    float* __restrict__ Cf, bf16* __restrict__ Cb,
    const float* __restrict__ bias, const float* __restrict__ res,
    int K, int Ncol) {
  __shared__ __align__(16) bf16 As[64][40];
  __shared__ __align__(16) bf16 Bs[128][40];
  const int tid = threadIdx.x;
  const int lane = tid & 63, wid = tid >> 6;
  const int row0 = blockIdx.y * 64, col0 = blockIdx.x * 128;
  f32x4 acc[4][2] = {};
  const int am = tid >> 2, ako = (tid & 3) * 8;
  const int fr = lane & 15, fg = (lane >> 4) * 8;
  for (int k0 = 0; k0 < K; k0 += 32) {
    *(bf16x8*)&As[am][ako] =
        *(const bf16x8*)(A + (size_t)(row0 + am) * K + k0 + ako);
#pragma unroll
    for (int it = 0; it < 2; ++it) {
      const int c = it * 256 + tid;
      const int n = c >> 2, ko = (c & 3) * 8;
      *(bf16x8*)&Bs[n][ko] =
          *(const bf16x8*)(WT + (size_t)(col0 + n) * K + k0 + ko);
    }
    __syncthreads();
    bf16x8 af[4], bfr[2];
#pragma unroll
    for (int mi = 0; mi < 4; ++mi) af[mi] = *(const bf16x8*)&As[mi * 16 + fr][fg];
#pragma unroll
    for (int ni = 0; ni < 2; ++ni) bfr[ni] = *(const bf16x8*)&Bs[wid * 32 + ni * 16 + fr][fg];
#pragma unroll
    for (int mi = 0; mi < 4; ++mi)
#pragma unroll
      for (int ni = 0; ni < 2; ++ni)
        acc[mi][ni] = __builtin_amdgcn_mfma_f32_16x16x32_bf16(af[mi], bfr[ni], acc[mi][ni], 0, 0, 0);
    __syncthreads();
  }
  const int r4 = (lane >> 4) * 4;
  const int cc0 = col0 + wid * 32 + (lane & 15);
#pragma unroll
  for (int mi = 0; mi < 4; ++mi) {
#pragma unroll
    for (int ni = 0; ni < 2; ++ni) {
      const int cc = cc0 + ni * 16;
#pragma unroll
      for (int r = 0; r < 4; ++r) {
        const int rr = row0 + mi * 16 + r4 + r;
        float v = acc[mi][ni][r];
        if (bias) v += bias[cc];
        if (res) v += res[(size_t)rr * Ncol + cc];
        if (GELU) v = 0.5f * v * (1.f + erff(v * 0.70710678118654752f));
        if (OUT_BF) Cb[(size_t)rr * Ncol + cc] = (bf16)v;
        else        Cf[(size_t)rr * Ncol + cc] = v;
      }
    }
  }
}

// ============================================================
// f32 GEMM for the small tail ops (pool q, pool out, head).
// ============================================================
__global__ __launch_bounds__(256) void gemm_kernel(
    const float* __restrict__ A, const float* __restrict__ W,
    float* __restrict__ C, const float* __restrict__ bias,
    const float* __restrict__ res, int Mr, int K, int Ncol, int resmode) {
  __shared__ float As[16][64];
  __shared__ float Bs[16][65];
  const int tx = threadIdx.x, ty = threadIdx.y;
  const int tid = ty * 16 + tx;
  const int row0 = blockIdx.y * 64, col0 = blockIdx.x * 64;
  const int tr = ty * 4, tc = tx * 4;
  float acc[4][4] = {};
  const int ea = tid * 4;
  const int am = ea >> 4, ak = ea & 15;
  const int bn = ea & 63, bk = ea >> 6;
  for (int k0 = 0; k0 < K; k0 += 16) {
    float4 av;
    if (row0 + am < Mr)
      av = *(const float4*)(A + (size_t)(row0 + am) * K + (k0 + ak));
    else
      av = float4{0.f, 0.f, 0.f, 0.f};
    As[ak + 0][am] = av.x; As[ak + 1][am] = av.y;
    As[ak + 2][am] = av.z; As[ak + 3][am] = av.w;
    const float* wp = W + (size_t)(k0 + bk) * Ncol + (col0 + bn);
    if (col0 + bn + 3 < Ncol) {
      float4 wv = *(const float4*)wp;
      Bs[bk][bn] = wv.x; Bs[bk][bn + 1] = wv.y;
      Bs[bk][bn + 2] = wv.z; Bs[bk][bn + 3] = wv.w;
    } else {
      for (int t = 0; t < 4; ++t)
        Bs[bk][bn + t] = (col0 + bn + t < Ncol) ? wp[t] : 0.f;
    }
    __syncthreads();
#pragma unroll
    for (int kk = 0; kk < 16; ++kk) {
      const float a0 = As[kk][tr], a1 = As[kk][tr + 1], a2 = As[kk][tr + 2], a3 = As[kk][tr + 3];
      const float b0 = Bs[kk][tc], b1 = Bs[kk][tc + 1], b2 = Bs[kk][tc + 2], b3 = Bs[kk][tc + 3];
      acc[0][0] += a0 * b0; acc[0][1] += a0 * b1; acc[0][2] += a0 * b2; acc[0][3] += a0 * b3;
      acc[1][0] += a1 * b0; acc[1][1] += a1 * b1; acc[1][2] += a1 * b2; acc[1][3] += a1 * b3;
      acc[2][0] += a2 * b0; acc[2][1] += a2 * b1; acc[2][2] += a2 * b2; acc[2][3] += a2 * b3;
      acc[3][0] += a3 * b0; acc[3][1] += a3 * b1; acc[3][2] += a3 * b2; acc[3][3] += a3 * b3;
    }
    __syncthreads();
  }
#pragma unroll
  for (int i = 0; i < 4; ++i) {
    const int r = row0 + tr + i;
    if (r >= Mr) break;
#pragma unroll
    for (int j = 0; j < 4; ++j) {
      const int c = col0 + tc + j;
      if (c >= Ncol) continue;
      float v = acc[i][j];
      if (bias) v += bias[c];
      if (resmode == 1) v += res[(size_t)r * Ncol + c];
      else if (resmode == 2) v += res[c];
      C[(size_t)r * Ncol + c] = v;
    }
  }
}

// ============================================================
// Block-diagonal MFMA attention. One 256-thread block per
// (head, image, batch). Images are contiguous token spans of
// T <= 64. Fuses per-head q/k LayerNorm into LDS staging.
// img == kM handles the padding block (id == -1): zero output.
// qkv: [B,N,3072] f32 raw (q|k|v). o: [B,N,1024] bf16.
// ============================================================
__global__ __launch_bounds__(256) void attn_kernel(
    const float* __restrict__ qkv, const int* __restrict__ ids,
    const float* __restrict__ qg, const float* __restrict__ qb,
    const float* __restrict__ kg, const float* __restrict__ kb,
    bf16* __restrict__ o) {
  const int h = blockIdx.x, img = blockIdx.y, b = blockIdx.z;
  const int tid = threadIdx.x, lane = tid & 63, wid = tid >> 6;
  __shared__ __align__(16) bf16 Qs[64][72];
  __shared__ __align__(16) bf16 Ks[64][72];
  __shared__ __align__(16) bf16 Vt[64][72];
  __shared__ __align__(16) bf16 Ps[64][72];
  __shared__ int wlo[4], whi[4];
  __shared__ int sLo, sHi;
  // ---- find this image's token span ----
  {
    const int want = (img < kM) ? img : -1;
    int lo = kN, hi = -1;
    for (int j = tid; j < kN; j += 256) {
      if (ids[b * kN + j] == want) { lo = min(lo, j); hi = max(hi, j); }
    }
#pragma unroll
    for (int off = 32; off; off >>= 1) {
      lo = min(lo, __shfl_xor(lo, off));
      hi = max(hi, __shfl_xor(hi, off));
    }
    if (lane == 0) { wlo[wid] = lo; whi[wid] = hi; }
    __syncthreads();
    if (tid == 0) {
      sLo = min(min(wlo[0], wlo[1]), min(wlo[2], wlo[3]));
      sHi = max(max(whi[0], whi[1]), max(whi[2], whi[3]));
    }
    __syncthreads();
  }
  if (sHi < 0) return;
  const int start = sLo, T = sHi - sLo + 1;
  if (img == kM) {       // padding block: rows are dead downstream; write zeros
    for (int j = start + wid; j <= sHi; j += 4)
      o[((size_t)(b * kN + j)) * kD + h * kDH + lane] = (bf16)0.f;
    return;
  }
  // ---- stage Q,K (fused head-LN) and V^T into LDS as bf16 ----
  // chunk = row (0..63) x 16 float4 slots; 16 consecutive lanes per row.
  for (int ch = tid; ch < 1024; ch += 256) {
    const int r = ch >> 4, d0 = (ch & 15) * 4;
    if (r < T) {
      const float* base = qkv + ((size_t)(b * kN + start + r)) * 3072 + h * kDH + d0;
      const float4 qv = *(const float4*)(base);
      const float4 kv = *(const float4*)(base + 1024);
      const float4 vv = *(const float4*)(base + 2048);
      float sq = qv.x + qv.y + qv.z + qv.w;
      float sq2 = qv.x * qv.x + qv.y * qv.y + qv.z * qv.z + qv.w * qv.w;
      float sk = kv.x + kv.y + kv.z + kv.w;
      float sk2 = kv.x * kv.x + kv.y * kv.y + kv.z * kv.z + kv.w * kv.w;
#pragma unroll
      for (int off = 1; off < 16; off <<= 1) {
        sq += __shfl_xor(sq, off); sq2 += __shfl_xor(sq2, off);
        sk += __shfl_xor(sk, off); sk2 += __shfl_xor(sk2, off);
      }
      const float qm = sq * (1.f / 64);
      const float qr = rsqrtf(sq2 * (1.f / 64) - qm * qm + 1e-5f);
      const float km = sk * (1.f / 64);
      const float kr = rsqrtf(sk2 * (1.f / 64) - km * km + 1e-5f);
      const float qe[4] = {qv.x, qv.y, qv.z, qv.w};
      const float ke[4] = {kv.x, kv.y, kv.z, kv.w};
      bf16x4 qw, kw;
#pragma unroll
      for (int e = 0; e < 4; ++e) {
        qw[e] = (bf16)((qe[e] - qm) * qr * qg[d0 + e] + qb[d0 + e]);
        kw[e] = (bf16)((ke[e] - km) * kr * kg[d0 + e] + kb[d0 + e]);
      }
      *(bf16x4*)&Qs[r][d0] = qw;
      *(bf16x4*)&Ks[r][d0] = kw;
      Vt[d0 + 0][r] = (bf16)vv.x;
      Vt[d0 + 1][r] = (bf16)vv.y;
      Vt[d0 + 2][r] = (bf16)vv.z;
      Vt[d0 + 3][r] = (bf16)vv.w;
    } else {
      const bf16x4 z = {(bf16)0.f, (bf16)0.f, (bf16)0.f, (bf16)0.f};
      *(bf16x4*)&Qs[r][d0] = z;
      *(bf16x4*)&Ks[r][d0] = z;
      Vt[d0 + 0][r] = (bf16)0.f;
      Vt[d0 + 1][r] = (bf16)0.f;
      Vt[d0 + 2][r] = (bf16)0.f;
      Vt[d0 + 3][r] = (bf16)0.f;
    }
  }
  __syncthreads();
  // ---- S = Q K^T for this wave's 16 rows ----
  const int fr = lane & 15, fg = lane >> 4;
  const int r0 = wid * 16;
  f32x4 sacc[4] = {};
#pragma unroll
  for (int k0 = 0; k0 < 64; k0 += 32) {
    const bf16x8 aq = *(const bf16x8*)&Qs[r0 + fr][k0 + fg * 8];
#pragma unroll
    for (int ni = 0; ni < 4; ++ni) {
      const bf16x8 bk = *(const bf16x8*)&Ks[ni * 16 + fr][k0 + fg * 8];
      sacc[ni] = __builtin_amdgcn_mfma_f32_16x16x32_bf16(aq, bk, sacc[ni], 0, 0, 0);
    }
  }
  // ---- softmax: row i = r0 + fg*4 + r lives in 16 consecutive lanes ----
  float inv[4];
#pragma unroll
  for (int r = 0; r < 4; ++r) {
    float mx = kNegInf;
#pragma unroll
    for (int ni = 0; ni < 4; ++ni) {
      const float s = (ni * 16 + fr < T) ? sacc[ni][r] * kScale : kNegInf;
      sacc[ni][r] = s;
      mx = fmaxf(mx, s);
    }
#pragma unroll
    for (int off = 1; off < 16; off <<= 1) mx = fmaxf(mx, __shfl_xor(mx, off));
    float sum = 0.f;
#pragma unroll
    for (int ni = 0; ni < 4; ++ni) {
      const float p = __expf(sacc[ni][r] - mx);
      sacc[ni][r] = p;
      sum += p;
    }
#pragma unroll
    for (int off = 1; off < 16; off <<= 1) sum += __shfl_xor(sum, off);
    inv[r] = 1.f / sum;
  }
  // ---- P -> LDS (C layout -> A fragment layout), wave-local ----
#pragma unroll
  for (int ni = 0; ni < 4; ++ni)
#pragma unroll
    for (int r = 0; r < 4; ++r)
      Ps[r0 + fg * 4 + r][ni * 16 + fr] = (bf16)sacc[ni][r];
  // ---- O = P V ----
  f32x4 oacc[4] = {};
#pragma unroll
  for (int k0 = 0; k0 < 64; k0 += 32) {
    const bf16x8 ap = *(const bf16x8*)&Ps[r0 + fr][k0 + fg * 8];
#pragma unroll
    for (int ni = 0; ni < 4; ++ni) {
      const bf16x8 bv = *(const bf16x8*)&Vt[ni * 16 + fr][k0 + fg * 8];
      oacc[ni] = __builtin_amdgcn_mfma_f32_16x16x32_bf16(ap, bv, oacc[ni], 0, 0, 0);
    }
  }
#pragma unroll
  for (int r = 0; r < 4; ++r) {
    const int i = r0 + fg * 4 + r;
    if (i < T) {
      const size_t orow = ((size_t)(b * kN + start + i)) * kD + h * kDH;
      const float iv = inv[r];
#pragma unroll
      for (int ni = 0; ni < 4; ++ni)
        o[orow + ni * 16 + fr] = (bf16)(oacc[ni][r] * iv);
    }
  }
}

// ============================================================
// Attention pooling: one wave per (b,m,h). kv layout [B,N,2048].
// ============================================================
__global__ __launch_bounds__(64) void poolattn_kernel(
    const float* __restrict__ qp, const float* __restrict__ kv,
    const int* __restrict__ ids, float* __restrict__ o) {
  const int blk = blockIdx.x;
  const int h = blk % kH;
  const int bm = blk / kH;
  const int m = bm % kM, b = bm / kM;
  const int lane = threadIdx.x;
  __shared__ float sc[kN];
  __shared__ float qs[kDH];
  qs[lane] = qp[h * kDH + lane];
  __syncthreads();
  float mymax = kNegInf;
  int jmn = kN, jmx = -1;
  for (int j = lane; j < kN; j += 64) {
    const int idj = ids[b * kN + j];
    float s;
    if (idj == m) {
      const float* krow = kv + ((size_t)(b * kN + j)) * (2 * kD) + h * kDH;
      float dot = 0.f;
#pragma unroll
      for (int d = 0; d < kDH; ++d) dot += qs[d] * krow[d];
      s = dot * kScale;
      jmn = min(jmn, j); jmx = max(jmx, j);
    } else {
      s = kNegInf;
    }
    sc[j] = s;
    mymax = fmaxf(mymax, s);
  }
#pragma unroll
  for (int off = 32; off; off >>= 1) {
    mymax = fmaxf(mymax, __shfl_xor(mymax, off));
    jmn = min(jmn, __shfl_xor(jmn, off));
    jmx = max(jmx, __shfl_xor(jmx, off));
  }
  const int jlo = jmn, jhi = jmx + 1;
  float mysum = 0.f;
  for (int j = jlo + lane; j < jhi; j += 64) {
    const float p = __expf(sc[j] - mymax);
    sc[j] = p;
    mysum += p;
  }
#pragma unroll
  for (int off = 32; off; off >>= 1) mysum += __shfl_xor(mysum, off);
  const float inv = 1.f / mysum;
  __syncthreads();
  float acc = 0.f;
  const float* vptr = kv + ((size_t)(b * kN + jlo)) * (2 * kD) + kD + h * kDH + lane;
  for (int j = jlo; j < jhi; ++j, vptr += 2 * kD) acc += sc[j] * vptr[0];
  o[((size_t)(b * kM + m)) * kD + h * kDH + lane] = acc * inv;
}

// ============================================================
// driver
// ============================================================
extern "C" void kernel_launch(void* const* d_in, const int* in_sizes, int n_in,
                              void* d_out, int out_size, void* d_ws, size_t ws_size,
                              hipStream_t stream) {
  const float* patches  = (const float*)d_in[0];
  const float* pe_ln1_g = (const float*)d_in[1];
  const float* pe_ln1_b = (const float*)d_in[2];
  const float* W_pe     = (const float*)d_in[3];
  const float* b_pe     = (const float*)d_in[4];
  const float* pe_ln2_g = (const float*)d_in[5];
  const float* pe_ln2_b = (const float*)d_in[6];
  const float* pos_h    = (const float*)d_in[7];
  const float* pos_w    = (const float*)d_in[8];
  const float* ln1_g    = (const float*)d_in[9];
  const float* ln1_b    = (const float*)d_in[10];
  const float* qn_g     = (const float*)d_in[11];
  const float* qn_b     = (const float*)d_in[12];
  const float* kn_g     = (const float*)d_in[13];
  const float* kn_b     = (const float*)d_in[14];
  const float* Wq       = (const float*)d_in[15];
  const float* Wkv      = (const float*)d_in[16];
  const float* Wo       = (const float*)d_in[17];
  const float* ln2_g    = (const float*)d_in[18];
  const float* ln2_b    = (const float*)d_in[19];
  const float* W1       = (const float*)d_in[20];
  const float* b1       = (const float*)d_in[21];
  const float* W2       = (const float*)d_in[22];
  const float* b2       = (const float*)d_in[23];
  const float* fin_g    = (const float*)d_in[24];
  const float* fin_b    = (const float*)d_in[25];
  const float* pool_q   = (const float*)d_in[26];
  const float* pl_ln_g  = (const float*)d_in[27];
  const float* pl_ln_b  = (const float*)d_in[28];
  const float* pl_qn_g  = (const float*)d_in[29];
  const float* pl_qn_b  = (const float*)d_in[30];
  const float* pl_kn_g  = (const float*)d_in[31];
  const float* pl_kn_b  = (const float*)d_in[32];
  const float* pl_Wq    = (const float*)d_in[33];
  const float* pl_Wkv   = (const float*)d_in[34];
  const float* pl_Wo    = (const float*)d_in[35];
  const float* head_g   = (const float*)d_in[36];
  const float* head_b   = (const float*)d_in[37];
  const float* W_head   = (const float*)d_in[38];
  const float* b_head   = (const float*)d_in[39];
  const int* h_idx      = (const int*)d_in[40];
  const int* w_idx      = (const int*)d_in[41];
  const int* image_ids  = (const int*)d_in[42];
  float* out = (float*)d_out;

  // ---- workspace layout ----
  const size_t SZ = (size_t)kB * kN * kD;        // 2,621,440
  char* p = (char*)d_ws;
  float* x    = (float*)p;           p += SZ * 4;
  bf16*  xnb  = (bf16*)p;            p += SZ * 2;
  char*  scratch = p;                p += (SZ * 14);
  bf16*  wtbuf = (bf16*)p;           p += (size_t)kPD * kD * 2;
  float* smalls = (float*)p;
  float* qkvb  = (float*)scratch;                          // [BN][3072] f32
  bf16*  attno = (bf16*)(scratch + SZ * 12);               // [BN][1024] bf16
  bf16*  plnb  = (bf16*)scratch;                           // [BN][3072] bf16 (embed)
  float* emb   = (float*)(scratch + SZ * 8);               // [BN][1024] f32 (embed)
  bf16*  h1b   = (bf16*)scratch;                           // [BN][2048] bf16 (mlp)
  float* kvpool = (float*)scratch;                         // [BN][2048] f32 (pool)
  float* qn_vec  = smalls;
  float* qpool   = smalls + kD;
  float* opool   = smalls + 2 * kD;
  float* pooled  = opool + (size_t)kB * kM * kD;
  float* pooledn = pooled + (size_t)kB * kM * kD;

  const int BN = kB * kN;
  const dim3 t256f(16, 16);

  auto gemm32 = [&](const float* A, const float* Wt, float* Cm, const float* bias,
                    const float* res, int Mr, int K, int Ncol, int resmode) {
    dim3 g((Ncol + 63) / 64, (Mr + 63) / 64);
    gemm_kernel<<<g, t256f, 0, stream>>>(A, Wt, Cm, bias, res, Mr, K, Ncol, resmode);
  };
  auto wt = [&](const float* W, bf16* WT, int K, int Ncol) {
    wt_kernel<<<dim3(Ncol / 32, K / 32), 256, 0, stream>>>(W, WT, K, Ncol);
  };

  // ---- patch embedding ----
  ln_kernel<bf16><<<BN, 256, 0, stream>>>(patches, plnb, pe_ln1_g, pe_ln1_b, kPD);
  wt(W_pe, wtbuf, kPD, kD);
  gemm_bf_kernel<false, false><<<dim3(kD / 128, BN / 64), 256, 0, stream>>>(
      plnb, wtbuf, emb, nullptr, b_pe, nullptr, kPD, kD);
  ln_pos_kernel<<<BN, 256, 0, stream>>>(emb, x, pe_ln2_g, pe_ln2_b, pos_h, pos_w, h_idx, w_idx);

  // ---- transformer layers ----
  for (int l = 0; l < kDepth; ++l) {
    ln_kernel<bf16><<<BN, 256, 0, stream>>>(x, xnb, ln1_g + (size_t)l * kD, ln1_b + (size_t)l * kD, kD);
    wt(Wq + (size_t)l * kD * kD, wtbuf, kD, kD);
    wt(Wkv + (size_t)l * kD * 2 * kD, wtbuf + (size_t)kD * kD, kD, 2 * kD);
    gemm_bf_kernel<false, false><<<dim3(3 * kD / 128, BN / 64), 256, 0, stream>>>(
        xnb, wtbuf, qkvb, nullptr, nullptr, nullptr, kD, 3 * kD);
    attn_kernel<<<dim3(kH, kM + 1, kB), 256, 0, stream>>>(
        qkvb, image_ids,
        qn_g + (size_t)l * kDH, qn_b + (size_t)l * kDH,
        kn_g + (size_t)l * kDH, kn_b + (size_t)l * kDH, attno);
    wt(Wo + (size_t)l * kD * kD, wtbuf, kD, kD);
    gemm_bf_kernel<false, false><<<dim3(kD / 128, BN / 64), 256, 0, stream>>>(
        attno, wtbuf, x, nullptr, nullptr, x, kD, kD);
    ln_kernel<bf16><<<BN, 256, 0, stream>>>(x, xnb, ln2_g + (size_t)l * kD, ln2_b + (size_t)l * kD, kD);
    wt(W1 + (size_t)l * kD * kMLP, wtbuf, kD, kMLP);
    gemm_bf_kernel<true, true><<<dim3(kMLP / 128, BN / 64), 256, 0, stream>>>(
        xnb, wtbuf, nullptr, h1b, b1 + (size_t)l * kMLP, nullptr, kD, kMLP);
    wt(W2 + (size_t)l * kMLP * kD, wtbuf, kMLP, kD);
    gemm_bf_kernel<false, false><<<dim3(kD / 128, BN / 64), 256, 0, stream>>>(
        h1b, wtbuf, x, nullptr, b2 + (size_t)l * kD, x, kMLP, kD);
  }

  // ---- final LN (context for pooling) ----
  ln_kernel<bf16><<<BN, 256, 0, stream>>>(x, xnb, fin_g, fin_b, kD);

  // ---- attention pooling ----
  ln_kernel<float><<<1, 256, 0, stream>>>(pool_q, qn_vec, pl_ln_g, pl_ln_b, kD);
  gemm32(qn_vec, pl_Wq, qpool, nullptr, nullptr, 1, kD, kD, 0);
  headln_kernel<<<kH, 64, 0, stream>>>(qpool, kD, pl_qn_g, pl_qn_b);
  wt(pl_Wkv, wtbuf, kD, 2 * kD);
  gemm_bf_kernel<false, false><<<dim3(2 * kD / 128, BN / 64), 256, 0, stream>>>(
      xnb, wtbuf, kvpool, nullptr, nullptr, nullptr, kD, 2 * kD);
  headln_kernel<<<BN * kH, 64, 0, stream>>>(kvpool, 2 * kD, pl_kn_g, pl_kn_b);
  poolattn_kernel<<<kB * kM * kH, 64, 0, stream>>>(qpool, kvpool, image_ids, opool);
  gemm32(opool, pl_Wo, pooled, nullptr, pool_q, kB * kM, kD, kD, 2);

  // ---- classifier head ----
  ln_kernel<float><<<kB * kM, 256, 0, stream>>>(pooled, pooledn, head_g, head_b, kD);
  gemm32(pooledn, W_head, out, b_head, nullptr, kB * kM, kD, kNC, 0);
}

// Round 4
// 1429.767 us; speedup vs baseline: 5.7632x; 1.1684x over previous
//
#include <hip/hip_runtime.h>
#include <cmath>

// ---- model constants ----
constexpr int kB = 4, kN = 640, kD = 1024, kH = 16, kDH = 64;
constexpr int kDepth = 6, kMLP = 2048, kPD = 3072, kNC = 1000, kM = 18;
constexpr float kScale = 0.125f;        // DH^-0.5
constexpr float kNegInf = -3.4028235e38f;

typedef __bf16 bf16;
typedef __attribute__((ext_vector_type(8))) __bf16 bf16x8;
typedef __attribute__((ext_vector_type(4))) __bf16 bf16x4;
typedef __attribute__((ext_vector_type(4))) float f32x4;

#define AS1 __attribute__((address_space(1)))
#define AS3 __attribute__((address_space(3)))

__device__ __forceinline__ void gload16(const void* g, void* l) {
  __builtin_amdgcn_global_load_lds((AS1 void*)g, (AS3 void*)l, 16, 0, 0);
}

// ============================================================
// LayerNorm over last dim K, one block (256 threads) per row.
// ============================================================
template <typename OT>
__global__ __launch_bounds__(256) void ln_kernel(
    const float* __restrict__ in, OT* __restrict__ out,
    const float* __restrict__ g, const float* __restrict__ b, int K) {
  const int row = blockIdx.x;
  const float* x = in + (size_t)row * K;
  OT* o = out + (size_t)row * K;
  float s = 0.f, s2 = 0.f;
  for (int d = threadIdx.x; d < K; d += 256) { float v = x[d]; s += v; s2 += v * v; }
#pragma unroll
  for (int off = 32; off; off >>= 1) { s += __shfl_down(s, off); s2 += __shfl_down(s2, off); }
  __shared__ float ls[4], ls2[4];
  __shared__ float sm, sr;
  const int wid = threadIdx.x >> 6, lane = threadIdx.x & 63;
  if (lane == 0) { ls[wid] = s; ls2[wid] = s2; }
  __syncthreads();
  if (threadIdx.x == 0) {
    float a = ls[0] + ls[1] + ls[2] + ls[3];
    float a2 = ls2[0] + ls2[1] + ls2[2] + ls2[3];
    float mean = a / K;
    float var = a2 / K - mean * mean;
    sm = mean; sr = rsqrtf(var + 1e-5f);
  }
  __syncthreads();
  const float mean = sm, r = sr;
  for (int d = threadIdx.x; d < K; d += 256)
    o[d] = (OT)((x[d] - mean) * r * g[d] + b[d]);
}

// ============================================================
// Fused pe_ln2 + factorized pos-embed add. f32 out (residual base).
// ============================================================
__global__ __launch_bounds__(256) void ln_pos_kernel(
    const float* __restrict__ in, float* __restrict__ out,
    const float* __restrict__ g, const float* __restrict__ b,
    const float* __restrict__ ph, const float* __restrict__ pw,
    const int* __restrict__ hi, const int* __restrict__ wi) {
  const int row = blockIdx.x;
  const float* x = in + (size_t)row * kD;
  float* o = out + (size_t)row * kD;
  float s = 0.f, s2 = 0.f;
  for (int d = threadIdx.x; d < kD; d += 256) { float v = x[d]; s += v; s2 += v * v; }
#pragma unroll
  for (int off = 32; off; off >>= 1) { s += __shfl_down(s, off); s2 += __shfl_down(s2, off); }
  __shared__ float ls[4], ls2[4];
  __shared__ float sm, sr;
  const int wid = threadIdx.x >> 6, lane = threadIdx.x & 63;
  if (lane == 0) { ls[wid] = s; ls2[wid] = s2; }
  __syncthreads();
  if (threadIdx.x == 0) {
    float a = ls[0] + ls[1] + ls[2] + ls[3];
    float a2 = ls2[0] + ls2[1] + ls2[2] + ls2[3];
    float mean = a / kD;
    float var = a2 / kD - mean * mean;
    sm = mean; sr = rsqrtf(var + 1e-5f);
  }
  __syncthreads();
  const float mean = sm, r = sr;
  const float* phr = ph + (size_t)hi[row] * kD;
  const float* pwr = pw + (size_t)wi[row] * kD;
  for (int d = threadIdx.x; d < kD; d += 256)
    o[d] = (x[d] - mean) * r * g[d] + b[d] + phr[d] + pwr[d];
}

// ============================================================
// Per-head LayerNorm (dim DH=64), in place f32.
// ============================================================
__global__ __launch_bounds__(64) void headln_kernel(
    float* __restrict__ p, int stride,
    const float* __restrict__ g, const float* __restrict__ b) {
  const int blk = blockIdx.x;
  const int outer = blk / kH, h = blk % kH;
  float* x = p + (size_t)outer * stride + h * kDH;
  const int lane = threadIdx.x;
  float v = x[lane];
  float s = v, s2 = v * v;
#pragma unroll
  for (int off = 32; off; off >>= 1) { s += __shfl_xor(s, off); s2 += __shfl_xor(s2, off); }
  const float m = s * (1.f / kDH);
  const float var = s2 * (1.f / kDH) - m * m;
  const float r = rsqrtf(var + 1e-5f);
  x[lane] = (v - m) * r * g[lane] + b[lane];
}

// ============================================================
// Weight transpose: f32 W[K][Ncol] -> bf16 WT[Npad][K], zero-padded
// rows for n >= Ncol. grid = (Npad/32, K/32).
// ============================================================
__global__ __launch_bounds__(256) void wt_kernel(
    const float* __restrict__ W, bf16* __restrict__ WT, int K, int Ncol) {
  __shared__ float s[32][33];
  const int n0 = blockIdx.x * 32, k0 = blockIdx.y * 32;
  const int tx = threadIdx.x & 31, ty = threadIdx.x >> 5;
#pragma unroll
  for (int i = 0; i < 4; ++i) {
    const int k = ty + i * 8;
    s[k][tx] = (n0 + tx < Ncol) ? W[(size_t)(k0 + k) * Ncol + (n0 + tx)] : 0.f;
  }
  __syncthreads();
#pragma unroll
  for (int i = 0; i < 4; ++i) {
    const int n = ty + i * 8;
    WT[(size_t)(n0 + n) * K + (k0 + tx)] = (bf16)s[tx][n];
  }
}

// ============================================================
// 128x(NI*32) MFMA GEMM with global_load_lds staging.
// C[M,N] = A[M,K](bf16) @ WT[N,K](bf16)^T. BK=32, 256 thr = 4 waves (2x2),
// wave computes 64 x (NI*16). M%128==0, N%(NI*32)==0, K%32==0.
// Epilogue: +bias, +res(f32 full), optional GELU, f32 or bf16 out.
// ============================================================
template <int NI, bool OUT_BF, bool GELU>
__global__ __launch_bounds__(256) void gemm_mfma_kernel(
    const bf16* __restrict__ A, const bf16* __restrict__ WT,
    float* __restrict__ Cf, bf16* __restrict__ Cb,
    const float* __restrict__ bias, const float* __restrict__ res,
    int K, int Ncol) {
  constexpr int TN = NI * 32;
  __shared__ __align__(16) bf16 As[128 * 32];
  __shared__ __align__(16) bf16 Bs[TN * 32];
  const int tid = threadIdx.x, lane = tid & 63, wid = tid >> 6;
  const int wr = wid >> 1, wc = wid & 1;
  const int row0 = blockIdx.y * 128, col0 = blockIdx.x * TN;
  const int fr = lane & 15, fg = lane >> 4;
  f32x4 acc[4][NI] = {};
  for (int k0 = 0; k0 < K; k0 += 32) {
    // stage A tile [128][32] linearly: chunk c -> row c>>2, elems (c&3)*8
#pragma unroll
    for (int i = 0; i < 2; ++i) {
      const int c = i * 256 + tid;
      gload16(A + (size_t)(row0 + (c >> 2)) * K + k0 + (c & 3) * 8,
              As + (i * 256 + wid * 64) * 8);
    }
#pragma unroll
    for (int i = 0; i < TN / 64; ++i) {
      const int c = i * 256 + tid;
      gload16(WT + (size_t)(col0 + (c >> 2)) * K + k0 + (c & 3) * 8,
              Bs + (i * 256 + wid * 64) * 8);
    }
    __syncthreads();
    bf16x8 af[4], bfr[NI];
#pragma unroll
    for (int mi = 0; mi < 4; ++mi)
      af[mi] = *(const bf16x8*)(As + (wr * 64 + mi * 16 + fr) * 32 + fg * 8);
#pragma unroll
    for (int ni = 0; ni < NI; ++ni)
      bfr[ni] = *(const bf16x8*)(Bs + (wc * (TN / 2) + ni * 16 + fr) * 32 + fg * 8);
#pragma unroll
    for (int mi = 0; mi < 4; ++mi)
#pragma unroll
      for (int ni = 0; ni < NI; ++ni)
        acc[mi][ni] = __builtin_amdgcn_mfma_f32_16x16x32_bf16(af[mi], bfr[ni], acc[mi][ni], 0, 0, 0);
    __syncthreads();
  }
  // C: row = row0 + wr*64 + mi*16 + fg*4 + r; col = col0 + wc*(TN/2) + ni*16 + fr
  const int rbase = row0 + wr * 64 + fg * 4;
  const int cbase = col0 + wc * (TN / 2) + fr;
#pragma unroll
  for (int mi = 0; mi < 4; ++mi) {
#pragma unroll
    for (int ni = 0; ni < NI; ++ni) {
      const int cc = cbase + ni * 16;
      const float bb = bias ? bias[cc] : 0.f;
#pragma unroll
      for (int r = 0; r < 4; ++r) {
        const int rr = rbase + mi * 16 + r;
        float v = acc[mi][ni][r] + bb;
        if (res) v += res[(size_t)rr * Ncol + cc];
        if (GELU) v = 0.5f * v * (1.f + erff(v * 0.70710678118654752f));
        if (OUT_BF) Cb[(size_t)rr * Ncol + cc] = (bf16)v;
        else        Cf[(size_t)rr * Ncol + cc] = v;
      }
    }
  }
}

// ============================================================
// Guarded tail GEMM (reg-staged 64x128): small M, N<=stride of WT pad.
// resmode: 0 none, 1 full, 2 broadcast vector.
// ============================================================
template <bool OUT_BF>
__global__ __launch_bounds__(256) void gemm_tail_kernel(
    const bf16* __restrict__ A, const bf16* __restrict__ WT,
    float* __restrict__ Cf, bf16* __restrict__ Cb,
    const float* __restrict__ bias, const float* __restrict__ resv,
    int Mr, int K, int Nc, int ldc, int resmode) {
  __shared__ __align__(16) bf16 As[64][40];
  __shared__ __align__(16) bf16 Bs[128][40];
  const int tid = threadIdx.x;
  const int lane = tid & 63, wid = tid >> 6;
  const int row0 = blockIdx.y * 64, col0 = blockIdx.x * 128;
  f32x4 acc[4][2] = {};
  const int am = tid >> 2, ako = (tid & 3) * 8;
  const int fr = lane & 15, fg = (lane >> 4) * 8;
  for (int k0 = 0; k0 < K; k0 += 32) {
    if (row0 + am < Mr)
      *(bf16x8*)&As[am][ako] = *(const bf16x8*)(A + (size_t)(row0 + am) * K + k0 + ako);
    else {
      bf16x8 z = {};
      *(bf16x8*)&As[am][ako] = z;
    }
#pragma unroll
    for (int it = 0; it < 2; ++it) {
      const int c = it * 256 + tid;
      const int n = c >> 2, ko = (c & 3) * 8;
      *(bf16x8*)&Bs[n][ko] = *(const bf16x8*)(WT + (size_t)(col0 + n) * K + k0 + ko);
    }
    __syncthreads();
    bf16x8 af[4], bfr[2];
#pragma unroll
    for (int mi = 0; mi < 4; ++mi) af[mi] = *(const bf16x8*)&As[mi * 16 + fr][fg];
#pragma unroll
    for (int ni = 0; ni < 2; ++ni) bfr[ni] = *(const bf16x8*)&Bs[wid * 32 + ni * 16 + fr][fg];
#pragma unroll
    for (int mi = 0; mi < 4; ++mi)
#pragma unroll
      for (int ni = 0; ni < 2; ++ni)
        acc[mi][ni] = __builtin_amdgcn_mfma_f32_16x16x32_bf16(af[mi], bfr[ni], acc[mi][ni], 0, 0, 0);
    __syncthreads();
  }
  const int r4 = (lane >> 4) * 4;
  const int cc0 = col0 + wid * 32 + (lane & 15);
#pragma unroll
  for (int mi = 0; mi < 4; ++mi) {
#pragma unroll
    for (int ni = 0; ni < 2; ++ni) {
      const int cc = cc0 + ni * 16;
      if (cc >= Nc) continue;
#pragma unroll
      for (int r = 0; r < 4; ++r) {
        const int rr = row0 + mi * 16 + r4 + r;
        if (rr >= Mr) continue;
        float v = acc[mi][ni][r];
        if (bias) v += bias[cc];
        if (resmode == 1) v += resv[(size_t)rr * ldc + cc];
        else if (resmode == 2) v += resv[cc];
        if (OUT_BF) Cb[(size_t)rr * ldc + cc] = (bf16)v;
        else        Cf[(size_t)rr * ldc + cc] = v;
      }
    }
  }
}

// ============================================================
// Block-diagonal MFMA attention (one block per head/image/batch).
// ============================================================
__global__ __launch_bounds__(256) void attn_kernel(
    const float* __restrict__ qkv, const int* __restrict__ ids,
    const float* __restrict__ qg, const float* __restrict__ qb,
    const float* __restrict__ kg, const float* __restrict__ kb,
    bf16* __restrict__ o) {
  const int h = blockIdx.x, img = blockIdx.y, b = blockIdx.z;
  const int tid = threadIdx.x, lane = tid & 63, wid = tid >> 6;
  __shared__ __align__(16) bf16 Qs[64][72];
  __shared__ __align__(16) bf16 Ks[64][72];
  __shared__ __align__(16) bf16 Vt[64][72];
  __shared__ __align__(16) bf16 Ps[64][72];
  __shared__ int wlo[4], whi[4];
  __shared__ int sLo, sHi;
  {
    const int want = (img < kM) ? img : -1;
    int lo = kN, hi = -1;
    for (int j = tid; j < kN; j += 256) {
      if (ids[b * kN + j] == want) { lo = min(lo, j); hi = max(hi, j); }
    }
#pragma unroll
    for (int off = 32; off; off >>= 1) {
      lo = min(lo, __shfl_xor(lo, off));
      hi = max(hi, __shfl_xor(hi, off));
    }
    if (lane == 0) { wlo[wid] = lo; whi[wid] = hi; }
    __syncthreads();
    if (tid == 0) {
      sLo = min(min(wlo[0], wlo[1]), min(wlo[2], wlo[3]));
      sHi = max(max(whi[0], whi[1]), max(whi[2], whi[3]));
    }
    __syncthreads();
  }
  if (sHi < 0) return;
  const int start = sLo, T = sHi - sLo + 1;
  if (img == kM) {
    for (int j = start + wid; j <= sHi; j += 4)
      o[((size_t)(b * kN + j)) * kD + h * kDH + lane] = (bf16)0.f;
    return;
  }
  for (int ch = tid; ch < 1024; ch += 256) {
    const int r = ch >> 4, d0 = (ch & 15) * 4;
    if (r < T) {
      const float* base = qkv + ((size_t)(b * kN + start + r)) * 3072 + h * kDH + d0;
      const float4 qv = *(const float4*)(base);
      const float4 kv = *(const float4*)(base + 1024);
      const float4 vv = *(const float4*)(base + 2048);
      float sq = qv.x + qv.y + qv.z + qv.w;
      float sq2 = qv.x * qv.x + qv.y * qv.y + qv.z * qv.z + qv.w * qv.w;
      float sk = kv.x + kv.y + kv.z + kv.w;
      float sk2 = kv.x * kv.x + kv.y * kv.y + kv.z * kv.z + kv.w * kv.w;
#pragma unroll
      for (int off = 1; off < 16; off <<= 1) {
        sq += __shfl_xor(sq, off); sq2 += __shfl_xor(sq2, off);
        sk += __shfl_xor(sk, off); sk2 += __shfl_xor(sk2, off);
      }
      const float qm = sq * (1.f / 64);
      const float qr = rsqrtf(sq2 * (1.f / 64) - qm * qm + 1e-5f);
      const float km = sk * (1.f / 64);
      const float kr = rsqrtf(sk2 * (1.f / 64) - km * km + 1e-5f);
      const float qe[4] = {qv.x, qv.y, qv.z, qv.w};
      const float ke[4] = {kv.x, kv.y, kv.z, kv.w};
      bf16x4 qw, kw;
#pragma unroll
      for (int e = 0; e < 4; ++e) {
        qw[e] = (bf16)((qe[e] - qm) * qr * qg[d0 + e] + qb[d0 + e]);
        kw[e] = (bf16)((ke[e] - km) * kr * kg[d0 + e] + kb[d0 + e]);
      }
      *(bf16x4*)&Qs[r][d0] = qw;
      *(bf16x4*)&Ks[r][d0] = kw;
      Vt[d0 + 0][r] = (bf16)vv.x;
      Vt[d0 + 1][r] = (bf16)vv.y;
      Vt[d0 + 2][r] = (bf16)vv.z;
      Vt[d0 + 3][r] = (bf16)vv.w;
    } else {
      const bf16x4 z = {};
      *(bf16x4*)&Qs[r][d0] = z;
      *(bf16x4*)&Ks[r][d0] = z;
      Vt[d0 + 0][r] = (bf16)0.f;
      Vt[d0 + 1][r] = (bf16)0.f;
      Vt[d0 + 2][r] = (bf16)0.f;
      Vt[d0 + 3][r] = (bf16)0.f;
    }
  }
  __syncthreads();
  const int fr = lane & 15, fg = lane >> 4;
  const int r0 = wid * 16;
  f32x4 sacc[4] = {};
#pragma unroll
  for (int k0 = 0; k0 < 64; k0 += 32) {
    const bf16x8 aq = *(const bf16x8*)&Qs[r0 + fr][k0 + fg * 8];
#pragma unroll
    for (int ni = 0; ni < 4; ++ni) {
      const bf16x8 bk = *(const bf16x8*)&Ks[ni * 16 + fr][k0 + fg * 8];
      sacc[ni] = __builtin_amdgcn_mfma_f32_16x16x32_bf16(aq, bk, sacc[ni], 0, 0, 0);
    }
  }
  float inv[4];
#pragma unroll
  for (int r = 0; r < 4; ++r) {
    float mx = kNegInf;
#pragma unroll
    for (int ni = 0; ni < 4; ++ni) {
      const float s = (ni * 16 + fr < T) ? sacc[ni][r] * kScale : kNegInf;
      sacc[ni][r] = s;
      mx = fmaxf(mx, s);
    }
#pragma unroll
    for (int off = 1; off < 16; off <<= 1) mx = fmaxf(mx, __shfl_xor(mx, off));
    float sum = 0.f;
#pragma unroll
    for (int ni = 0; ni < 4; ++ni) {
      const float p = __expf(sacc[ni][r] - mx);
      sacc[ni][r] = p;
      sum += p;
    }
#pragma unroll
    for (int off = 1; off < 16; off <<= 1) sum += __shfl_xor(sum, off);
    inv[r] = 1.f / sum;
  }
#pragma unroll
  for (int ni = 0; ni < 4; ++ni)
#pragma unroll
    for (int r = 0; r < 4; ++r)
      Ps[r0 + fg * 4 + r][ni * 16 + fr] = (bf16)sacc[ni][r];
  f32x4 oacc[4] = {};
#pragma unroll
  for (int k0 = 0; k0 < 64; k0 += 32) {
    const bf16x8 ap = *(const bf16x8*)&Ps[r0 + fr][k0 + fg * 8];
#pragma unroll
    for (int ni = 0; ni < 4; ++ni) {
      const bf16x8 bv = *(const bf16x8*)&Vt[ni * 16 + fr][k0 + fg * 8];
      oacc[ni] = __builtin_amdgcn_mfma_f32_16x16x32_bf16(ap, bv, oacc[ni], 0, 0, 0);
    }
  }
#pragma unroll
  for (int r = 0; r < 4; ++r) {
    const int i = r0 + fg * 4 + r;
    if (i < T) {
      const size_t orow = ((size_t)(b * kN + start + i)) * kD + h * kDH;
      const float iv = inv[r];
#pragma unroll
      for (int ni = 0; ni < 4; ++ni)
        o[orow + ni * 16 + fr] = (bf16)(oacc[ni][r] * iv);
    }
  }
}

// ============================================================
// Attention pooling: one wave per (b,m,h). kv layout [B,N,2048]. bf16 out.
// ============================================================
__global__ __launch_bounds__(64) void poolattn_kernel(
    const float* __restrict__ qp, const float* __restrict__ kv,
    const int* __restrict__ ids, bf16* __restrict__ o) {
  const int blk = blockIdx.x;
  const int h = blk % kH;
  const int bm = blk / kH;
  const int m = bm % kM, b = bm / kM;
  const int lane = threadIdx.x;
  __shared__ float sc[kN];
  __shared__ float qs[kDH];
  qs[lane] = qp[h * kDH + lane];
  __syncthreads();
  float mymax = kNegInf;
  int jmn = kN, jmx = -1;
  for (int j = lane; j < kN; j += 64) {
    const int idj = ids[b * kN + j];
    float s;
    if (idj == m) {
      const float* krow = kv + ((size_t)(b * kN + j)) * (2 * kD) + h * kDH;
      float dot = 0.f;
#pragma unroll
      for (int d = 0; d < kDH; ++d) dot += qs[d] * krow[d];
      s = dot * kScale;
      jmn = min(jmn, j); jmx = max(jmx, j);
    } else {
      s = kNegInf;
    }
    sc[j] = s;
    mymax = fmaxf(mymax, s);
  }
#pragma unroll
  for (int off = 32; off; off >>= 1) {
    mymax = fmaxf(mymax, __shfl_xor(mymax, off));
    jmn = min(jmn, __shfl_xor(jmn, off));
    jmx = max(jmx, __shfl_xor(jmx, off));
  }
  const int jlo = jmn, jhi = jmx + 1;
  float mysum = 0.f;
  for (int j = jlo + lane; j < jhi; j += 64) {
    const float p = __expf(sc[j] - mymax);
    sc[j] = p;
    mysum += p;
  }
#pragma unroll
  for (int off = 32; off; off >>= 1) mysum += __shfl_xor(mysum, off);
  const float inv = 1.f / mysum;
  __syncthreads();
  float acc = 0.f;
  const float* vptr = kv + ((size_t)(b * kN + jlo)) * (2 * kD) + kD + h * kDH + lane;
  for (int j = jlo; j < jhi; ++j, vptr += 2 * kD) acc += sc[j] * vptr[0];
  o[((size_t)(b * kM + m)) * kD + h * kDH + lane] = (bf16)(acc * inv);
}

// ============================================================
// driver
// ============================================================
extern "C" void kernel_launch(void* const* d_in, const int* in_sizes, int n_in,
                              void* d_out, int out_size, void* d_ws, size_t ws_size,
                              hipStream_t stream) {
  const float* patches  = (const float*)d_in[0];
  const float* pe_ln1_g = (const float*)d_in[1];
  const float* pe_ln1_b = (const float*)d_in[2];
  const float* W_pe     = (const float*)d_in[3];
  const float* b_pe     = (const float*)d_in[4];
  const float* pe_ln2_g = (const float*)d_in[5];
  const float* pe_ln2_b = (const float*)d_in[6];
  const float* pos_h    = (const float*)d_in[7];
  const float* pos_w    = (const float*)d_in[8];
  const float* ln1_g    = (const float*)d_in[9];
  const float* ln1_b    = (const float*)d_in[10];
  const float* qn_g     = (const float*)d_in[11];
  const float* qn_b     = (const float*)d_in[12];
  const float* kn_g     = (const float*)d_in[13];
  const float* kn_b     = (const float*)d_in[14];
  const float* Wq       = (const float*)d_in[15];
  const float* Wkv      = (const float*)d_in[16];
  const float* Wo       = (const float*)d_in[17];
  const float* ln2_g    = (const float*)d_in[18];
  const float* ln2_b    = (const float*)d_in[19];
  const float* W1       = (const float*)d_in[20];
  const float* b1       = (const float*)d_in[21];
  const float* W2       = (const float*)d_in[22];
  const float* b2       = (const float*)d_in[23];
  const float* fin_g    = (const float*)d_in[24];
  const float* fin_b    = (const float*)d_in[25];
  const float* pool_q   = (const float*)d_in[26];
  const float* pl_ln_g  = (const float*)d_in[27];
  const float* pl_ln_b  = (const float*)d_in[28];
  const float* pl_qn_g  = (const float*)d_in[29];
  const float* pl_qn_b  = (const float*)d_in[30];
  const float* pl_kn_g  = (const float*)d_in[31];
  const float* pl_kn_b  = (const float*)d_in[32];
  const float* pl_Wq    = (const float*)d_in[33];
  const float* pl_Wkv   = (const float*)d_in[34];
  const float* pl_Wo    = (const float*)d_in[35];
  const float* head_g   = (const float*)d_in[36];
  const float* head_b   = (const float*)d_in[37];
  const float* W_head   = (const float*)d_in[38];
  const float* b_head   = (const float*)d_in[39];
  const int* h_idx      = (const int*)d_in[40];
  const int* w_idx      = (const int*)d_in[41];
  const int* image_ids  = (const int*)d_in[42];
  float* out = (float*)d_out;

  // ---- workspace layout ----
  const size_t SZ = (size_t)kB * kN * kD;        // 2,621,440
  char* p = (char*)d_ws;
  float* x    = (float*)p;           p += SZ * 4;
  bf16*  xnb  = (bf16*)p;            p += SZ * 2;
  char*  scratch = p;                p += (SZ * 14);
  bf16*  wtbuf = (bf16*)p;           p += (size_t)kPD * kD * 2;
  char*  smalls = p;
  float* qkvb  = (float*)scratch;                          // [BN][3072] f32
  bf16*  attno = (bf16*)(scratch + SZ * 12);               // [BN][1024] bf16
  bf16*  plnb  = (bf16*)scratch;                           // [BN][3072] bf16 (embed)
  float* emb   = (float*)(scratch + SZ * 8);               // [BN][1024] f32 (embed)
  bf16*  h1b   = (bf16*)scratch;                           // [BN][2048] bf16 (mlp)
  float* kvpool = (float*)scratch;                         // [BN][2048] f32 (pool)
  bf16*  qn_vecb = (bf16*)smalls;                          // 1024 bf16
  float* qpool   = (float*)(smalls + 4096);                // 1024 f32
  bf16*  opoolb  = (bf16*)(smalls + 4096 + 4096);          // 72*1024 bf16
  float* pooled  = (float*)(smalls + 4096 + 4096 + 147456 + 8192);  // 72*1024 f32
  bf16*  pooledn = (bf16*)((char*)pooled + 72 * 1024 * 4 + 8192);   // 72*1024 bf16

  const int BN = kB * kN;

  auto wt = [&](const float* W, bf16* WT, int K, int Ncol, int Npad) {
    wt_kernel<<<dim3(Npad / 32, K / 32), 256, 0, stream>>>(W, WT, K, Ncol);
  };

  // ---- patch embedding ----
  ln_kernel<bf16><<<BN, 256, 0, stream>>>(patches, plnb, pe_ln1_g, pe_ln1_b, kPD);
  wt(W_pe, wtbuf, kPD, kD, kD);
  gemm_mfma_kernel<2, false, false><<<dim3(kD / 64, BN / 128), 256, 0, stream>>>(
      plnb, wtbuf, emb, nullptr, b_pe, nullptr, kPD, kD);
  ln_pos_kernel<<<BN, 256, 0, stream>>>(emb, x, pe_ln2_g, pe_ln2_b, pos_h, pos_w, h_idx, w_idx);

  // ---- transformer layers ----
  for (int l = 0; l < kDepth; ++l) {
    ln_kernel<bf16><<<BN, 256, 0, stream>>>(x, xnb, ln1_g + (size_t)l * kD, ln1_b + (size_t)l * kD, kD);
    wt(Wq + (size_t)l * kD * kD, wtbuf, kD, kD, kD);
    wt(Wkv + (size_t)l * kD * 2 * kD, wtbuf + (size_t)kD * kD, kD, 2 * kD, 2 * kD);
    gemm_mfma_kernel<4, false, false><<<dim3(3 * kD / 128, BN / 128), 256, 0, stream>>>(
        xnb, wtbuf, qkvb, nullptr, nullptr, nullptr, kD, 3 * kD);
    attn_kernel<<<dim3(kH, kM + 1, kB), 256, 0, stream>>>(
        qkvb, image_ids,
        qn_g + (size_t)l * kDH, qn_b + (size_t)l * kDH,
        kn_g + (size_t)l * kDH, kn_b + (size_t)l * kDH, attno);
    wt(Wo + (size_t)l * kD * kD, wtbuf, kD, kD, kD);
    gemm_mfma_kernel<2, false, false><<<dim3(kD / 64, BN / 128), 256, 0, stream>>>(
        attno, wtbuf, x, nullptr, nullptr, x, kD, kD);
    ln_kernel<bf16><<<BN, 256, 0, stream>>>(x, xnb, ln2_g + (size_t)l * kD, ln2_b + (size_t)l * kD, kD);
    wt(W1 + (size_t)l * kD * kMLP, wtbuf, kD, kMLP, kMLP);
    gemm_mfma_kernel<4, true, true><<<dim3(kMLP / 128, BN / 128), 256, 0, stream>>>(
        xnb, wtbuf, nullptr, h1b, b1 + (size_t)l * kMLP, nullptr, kD, kMLP);
    wt(W2 + (size_t)l * kMLP * kD, wtbuf, kMLP, kD, kD);
    gemm_mfma_kernel<2, false, false><<<dim3(kD / 64, BN / 128), 256, 0, stream>>>(
        h1b, wtbuf, x, nullptr, b2 + (size_t)l * kD, x, kMLP, kD);
  }

  // ---- final LN (context for pooling) ----
  ln_kernel<bf16><<<BN, 256, 0, stream>>>(x, xnb, fin_g, fin_b, kD);

  // ---- attention pooling ----
  ln_kernel<bf16><<<1, 256, 0, stream>>>(pool_q, qn_vecb, pl_ln_g, pl_ln_b, kD);
  wt(pl_Wq, wtbuf, kD, kD, kD);
  gemm_tail_kernel<false><<<dim3(8, 1), 256, 0, stream>>>(
      qn_vecb, wtbuf, qpool, nullptr, nullptr, nullptr, 1, kD, kD, kD, 0);
  headln_kernel<<<kH, 64, 0, stream>>>(qpool, kD, pl_qn_g, pl_qn_b);
  wt(pl_Wkv, wtbuf, kD, 2 * kD, 2 * kD);
  gemm_mfma_kernel<4, false, false><<<dim3(2 * kD / 128, BN / 128), 256, 0, stream>>>(
      xnb, wtbuf, kvpool, nullptr, nullptr, nullptr, kD, 2 * kD);
  headln_kernel<<<BN * kH, 64, 0, stream>>>(kvpool, 2 * kD, pl_kn_g, pl_kn_b);
  poolattn_kernel<<<kB * kM * kH, 64, 0, stream>>>(qpool, kvpool, image_ids, opoolb);
  wt(pl_Wo, wtbuf, kD, kD, kD);
  gemm_tail_kernel<false><<<dim3(8, 2), 256, 0, stream>>>(
      opoolb, wtbuf, pooled, nullptr, nullptr, pool_q, kB * kM, kD, kD, kD, 2);

  // ---- classifier head ----
  ln_kernel<bf16><<<kB * kM, 256, 0, stream>>>(pooled, pooledn, head_g, head_b, kD);
  wt(W_head, wtbuf, kD, kNC, 1024);
  gemm_tail_kernel<false><<<dim3(8, 2), 256, 0, stream>>>(
      pooledn, wtbuf, out, nullptr, b_head, nullptr, kB * kM, kD, kNC, kNC, 0);
}

// Round 5
// 1224.598 us; speedup vs baseline: 6.7287x; 1.1675x over previous
//
#include <hip/hip_runtime.h>
#include <cmath>

// ---- model constants ----
constexpr int kB = 4, kN = 640, kD = 1024, kH = 16, kDH = 64;
constexpr int kDepth = 6, kMLP = 2048, kPD = 3072, kNC = 1000, kM = 18;
constexpr float kScale = 0.125f;        // DH^-0.5
constexpr float kNegInf = -3.4028235e38f;

typedef __bf16 bf16;
typedef __attribute__((ext_vector_type(8))) __bf16 bf16x8;
typedef __attribute__((ext_vector_type(4))) __bf16 bf16x4;
typedef __attribute__((ext_vector_type(4))) float f32x4;

#define AS1 __attribute__((address_space(1)))
#define AS3 __attribute__((address_space(3)))

__device__ __forceinline__ void gload16(const void* g, void* l) {
  __builtin_amdgcn_global_load_lds((AS1 void*)g, (AS3 void*)l, 16, 0, 0);
}

// ============================================================
// LayerNorm over last dim K, one block (256 threads) per row.
// ============================================================
template <typename OT>
__global__ __launch_bounds__(256) void ln_kernel(
    const float* __restrict__ in, OT* __restrict__ out,
    const float* __restrict__ g, const float* __restrict__ b, int K) {
  const int row = blockIdx.x;
  const float* x = in + (size_t)row * K;
  OT* o = out + (size_t)row * K;
  float s = 0.f, s2 = 0.f;
  for (int d = threadIdx.x; d < K; d += 256) { float v = x[d]; s += v; s2 += v * v; }
#pragma unroll
  for (int off = 32; off; off >>= 1) { s += __shfl_down(s, off); s2 += __shfl_down(s2, off); }
  __shared__ float ls[4], ls2[4];
  __shared__ float sm, sr;
  const int wid = threadIdx.x >> 6, lane = threadIdx.x & 63;
  if (lane == 0) { ls[wid] = s; ls2[wid] = s2; }
  __syncthreads();
  if (threadIdx.x == 0) {
    float a = ls[0] + ls[1] + ls[2] + ls[3];
    float a2 = ls2[0] + ls2[1] + ls2[2] + ls2[3];
    float mean = a / K;
    float var = a2 / K - mean * mean;
    sm = mean; sr = rsqrtf(var + 1e-5f);
  }
  __syncthreads();
  const float mean = sm, r = sr;
  for (int d = threadIdx.x; d < K; d += 256)
    o[d] = (OT)((x[d] - mean) * r * g[d] + b[d]);
}

// ============================================================
// Fused pe_ln2 + factorized pos-embed add. f32 out (residual base).
// ============================================================
__global__ __launch_bounds__(256) void ln_pos_kernel(
    const float* __restrict__ in, float* __restrict__ out,
    const float* __restrict__ g, const float* __restrict__ b,
    const float* __restrict__ ph, const float* __restrict__ pw,
    const int* __restrict__ hi, const int* __restrict__ wi) {
  const int row = blockIdx.x;
  const float* x = in + (size_t)row * kD;
  float* o = out + (size_t)row * kD;
  float s = 0.f, s2 = 0.f;
  for (int d = threadIdx.x; d < kD; d += 256) { float v = x[d]; s += v; s2 += v * v; }
#pragma unroll
  for (int off = 32; off; off >>= 1) { s += __shfl_down(s, off); s2 += __shfl_down(s2, off); }
  __shared__ float ls[4], ls2[4];
  __shared__ float sm, sr;
  const int wid = threadIdx.x >> 6, lane = threadIdx.x & 63;
  if (lane == 0) { ls[wid] = s; ls2[wid] = s2; }
  __syncthreads();
  if (threadIdx.x == 0) {
    float a = ls[0] + ls[1] + ls[2] + ls[3];
    float a2 = ls2[0] + ls2[1] + ls2[2] + ls2[3];
    float mean = a / kD;
    float var = a2 / kD - mean * mean;
    sm = mean; sr = rsqrtf(var + 1e-5f);
  }
  __syncthreads();
  const float mean = sm, r = sr;
  const float* phr = ph + (size_t)hi[row] * kD;
  const float* pwr = pw + (size_t)wi[row] * kD;
  for (int d = threadIdx.x; d < kD; d += 256)
    o[d] = (x[d] - mean) * r * g[d] + b[d] + phr[d] + pwr[d];
}

// ============================================================
// Per-head LayerNorm (dim DH=64), in place f32.
// ============================================================
__global__ __launch_bounds__(64) void headln_kernel(
    float* __restrict__ p, int stride,
    const float* __restrict__ g, const float* __restrict__ b) {
  const int blk = blockIdx.x;
  const int outer = blk / kH, h = blk % kH;
  float* x = p + (size_t)outer * stride + h * kDH;
  const int lane = threadIdx.x;
  float v = x[lane];
  float s = v, s2 = v * v;
#pragma unroll
  for (int off = 32; off; off >>= 1) { s += __shfl_xor(s, off); s2 += __shfl_xor(s2, off); }
  const float m = s * (1.f / kDH);
  const float var = s2 * (1.f / kDH) - m * m;
  const float r = rsqrtf(var + 1e-5f);
  x[lane] = (v - m) * r * g[lane] + b[lane];
}

// ============================================================
// Weight transpose: f32 W[K][Ncol] -> bf16 WT[Npad][K], zero-padded
// rows for n >= Ncol. grid = (Npad/32, K/32).
// ============================================================
__global__ __launch_bounds__(256) void wt_kernel(
    const float* __restrict__ W, bf16* __restrict__ WT, int K, int Ncol) {
  __shared__ float s[32][33];
  const int n0 = blockIdx.x * 32, k0 = blockIdx.y * 32;
  const int tx = threadIdx.x & 31, ty = threadIdx.x >> 5;
#pragma unroll
  for (int i = 0; i < 4; ++i) {
    const int k = ty + i * 8;
    s[k][tx] = (n0 + tx < Ncol) ? W[(size_t)(k0 + k) * Ncol + (n0 + tx)] : 0.f;
  }
  __syncthreads();
#pragma unroll
  for (int i = 0; i < 4; ++i) {
    const int n = ty + i * 8;
    WT[(size_t)(n0 + n) * K + (k0 + tx)] = (bf16)s[tx][n];
  }
}

// ============================================================
// 64x(NI*32) MFMA GEMM, BK=64, double-buffered LDS with
// global_load_lds prefetch (2-phase: stage next || compute cur,
// ONE barrier per K-step). 4 waves (2x2); wave = 32 x (NI*16).
// 1D grid (gridDim.x % 8 == 0), XCD-chunked swizzle, col-fast.
// M%64==0, N%(NI*32)==0, K%64==0.
// ============================================================
template <int NI, bool OUT_BF, bool GELU>
__global__ __launch_bounds__(256) void gemm64_kernel(
    const bf16* __restrict__ A, const bf16* __restrict__ WT,
    float* __restrict__ Cf, bf16* __restrict__ Cb,
    const float* __restrict__ bias, const float* __restrict__ res,
    int K, int Ncol, int nbx) {
  constexpr int BN = NI * 32;
  __shared__ __align__(16) bf16 As[2][64 * 64];
  __shared__ __align__(16) bf16 Bs[2][BN * 64];
  const int tid = threadIdx.x, lane = tid & 63, wid = tid >> 6;
  const int wr = wid >> 1, wc = wid & 1;
  // XCD-chunked bijective swizzle (gridDim.x % 8 == 0 by construction)
  const int cpx = gridDim.x >> 3;
  const int swz = (blockIdx.x & 7) * cpx + (blockIdx.x >> 3);
  const int row0 = (swz / nbx) * 64, col0 = (swz % nbx) * BN;
  const int fr = lane & 15, fg = lane >> 4;
  f32x4 acc[2][NI] = {};
  bf16* sA = As[0]; bf16* sB = Bs[0];
  bf16* dA = As[1]; bf16* dB = Bs[1];

  auto stage = [&](bf16* tA, bf16* tB, int kt) {
#pragma unroll
    for (int i = 0; i < 2; ++i) {
      const int c = i * 256 + tid;
      gload16(A + (size_t)(row0 + (c >> 3)) * K + kt + (c & 7) * 8,
              tA + (i * 256 + wid * 64) * 8);
    }
#pragma unroll
    for (int i = 0; i < NI; ++i) {
      const int c = i * 256 + tid;
      gload16(WT + (size_t)(col0 + (c >> 3)) * K + kt + (c & 7) * 8,
              tB + (i * 256 + wid * 64) * 8);
    }
  };
  auto compute = [&](const bf16* tA, const bf16* tB) {
#pragma unroll
    for (int kk = 0; kk < 2; ++kk) {
      bf16x8 af[2], bfr[NI];
#pragma unroll
      for (int mi = 0; mi < 2; ++mi)
        af[mi] = *(const bf16x8*)(tA + (wr * 32 + mi * 16 + fr) * 64 + kk * 32 + fg * 8);
#pragma unroll
      for (int ni = 0; ni < NI; ++ni)
        bfr[ni] = *(const bf16x8*)(tB + (wc * (NI * 16) + ni * 16 + fr) * 64 + kk * 32 + fg * 8);
#pragma unroll
      for (int mi = 0; mi < 2; ++mi)
#pragma unroll
        for (int ni = 0; ni < NI; ++ni)
          acc[mi][ni] = __builtin_amdgcn_mfma_f32_16x16x32_bf16(af[mi], bfr[ni], acc[mi][ni], 0, 0, 0);
    }
  };

  const int NT = K >> 6;
  stage(sA, sB, 0);
  __syncthreads();
  for (int t = 1; t < NT; ++t) {
    stage(dA, dB, t * 64);     // prefetch next tile (drained by next barrier)
    compute(sA, sB);
    __syncthreads();
    bf16* u;
    u = sA; sA = dA; dA = u;
    u = sB; sB = dB; dB = u;
  }
  compute(sA, sB);

  // epilogue: row = row0 + wr*32 + mi*16 + fg*4 + r; col = col0 + wc*NI*16 + ni*16 + fr
  const int rb = row0 + wr * 32 + fg * 4;
  const int cb = col0 + wc * (NI * 16) + fr;
#pragma unroll
  for (int mi = 0; mi < 2; ++mi) {
#pragma unroll
    for (int ni = 0; ni < NI; ++ni) {
      const int cc = cb + ni * 16;
      const float bb = bias ? bias[cc] : 0.f;
#pragma unroll
      for (int r = 0; r < 4; ++r) {
        const int rr = rb + mi * 16 + r;
        float v = acc[mi][ni][r] + bb;
        if (res) v += res[(size_t)rr * Ncol + cc];
        if (GELU) v = 0.5f * v * (1.f + erff(v * 0.70710678118654752f));
        if (OUT_BF) Cb[(size_t)rr * Ncol + cc] = (bf16)v;
        else        Cf[(size_t)rr * Ncol + cc] = v;
      }
    }
  }
}

// ============================================================
// Guarded tail GEMM (reg-staged 64x128): small M.
// resmode: 0 none, 1 full, 2 broadcast vector.
// ============================================================
template <bool OUT_BF>
__global__ __launch_bounds__(256) void gemm_tail_kernel(
    const bf16* __restrict__ A, const bf16* __restrict__ WT,
    float* __restrict__ Cf, bf16* __restrict__ Cb,
    const float* __restrict__ bias, const float* __restrict__ resv,
    int Mr, int K, int Nc, int ldc, int resmode) {
  __shared__ __align__(16) bf16 As[64][40];
  __shared__ __align__(16) bf16 Bs[128][40];
  const int tid = threadIdx.x;
  const int lane = tid & 63, wid = tid >> 6;
  const int row0 = blockIdx.y * 64, col0 = blockIdx.x * 128;
  f32x4 acc[4][2] = {};
  const int am = tid >> 2, ako = (tid & 3) * 8;
  const int fr = lane & 15, fg = (lane >> 4) * 8;
  for (int k0 = 0; k0 < K; k0 += 32) {
    if (row0 + am < Mr)
      *(bf16x8*)&As[am][ako] = *(const bf16x8*)(A + (size_t)(row0 + am) * K + k0 + ako);
    else {
      bf16x8 z = {};
      *(bf16x8*)&As[am][ako] = z;
    }
#pragma unroll
    for (int it = 0; it < 2; ++it) {
      const int c = it * 256 + tid;
      const int n = c >> 2, ko = (c & 3) * 8;
      *(bf16x8*)&Bs[n][ko] = *(const bf16x8*)(WT + (size_t)(col0 + n) * K + k0 + ko);
    }
    __syncthreads();
    bf16x8 af[4], bfr[2];
#pragma unroll
    for (int mi = 0; mi < 4; ++mi) af[mi] = *(const bf16x8*)&As[mi * 16 + fr][fg];
#pragma unroll
    for (int ni = 0; ni < 2; ++ni) bfr[ni] = *(const bf16x8*)&Bs[wid * 32 + ni * 16 + fr][fg];
#pragma unroll
    for (int mi = 0; mi < 4; ++mi)
#pragma unroll
      for (int ni = 0; ni < 2; ++ni)
        acc[mi][ni] = __builtin_amdgcn_mfma_f32_16x16x32_bf16(af[mi], bfr[ni], acc[mi][ni], 0, 0, 0);
    __syncthreads();
  }
  const int r4 = (lane >> 4) * 4;
  const int cc0 = col0 + wid * 32 + (lane & 15);
#pragma unroll
  for (int mi = 0; mi < 4; ++mi) {
#pragma unroll
    for (int ni = 0; ni < 2; ++ni) {
      const int cc = cc0 + ni * 16;
      if (cc >= Nc) continue;
#pragma unroll
      for (int r = 0; r < 4; ++r) {
        const int rr = row0 + mi * 16 + r4 + r;
        if (rr >= Mr) continue;
        float v = acc[mi][ni][r];
        if (bias) v += bias[cc];
        if (resmode == 1) v += resv[(size_t)rr * ldc + cc];
        else if (resmode == 2) v += resv[cc];
        if (OUT_BF) Cb[(size_t)rr * ldc + cc] = (bf16)v;
        else        Cf[(size_t)rr * ldc + cc] = v;
      }
    }
  }
}

// ============================================================
// Block-diagonal MFMA attention (one block per head/image/batch).
// ============================================================
__global__ __launch_bounds__(256) void attn_kernel(
    const float* __restrict__ qkv, const int* __restrict__ ids,
    const float* __restrict__ qg, const float* __restrict__ qb,
    const float* __restrict__ kg, const float* __restrict__ kb,
    bf16* __restrict__ o) {
  const int h = blockIdx.x, img = blockIdx.y, b = blockIdx.z;
  const int tid = threadIdx.x, lane = tid & 63, wid = tid >> 6;
  __shared__ __align__(16) bf16 Qs[64][72];
  __shared__ __align__(16) bf16 Ks[64][72];
  __shared__ __align__(16) bf16 Vt[64][72];
  __shared__ __align__(16) bf16 Ps[64][72];
  __shared__ int wlo[4], whi[4];
  __shared__ int sLo, sHi;
  {
    const int want = (img < kM) ? img : -1;
    int lo = kN, hi = -1;
    for (int j = tid; j < kN; j += 256) {
      if (ids[b * kN + j] == want) { lo = min(lo, j); hi = max(hi, j); }
    }
#pragma unroll
    for (int off = 32; off; off >>= 1) {
      lo = min(lo, __shfl_xor(lo, off));
      hi = max(hi, __shfl_xor(hi, off));
    }
    if (lane == 0) { wlo[wid] = lo; whi[wid] = hi; }
    __syncthreads();
    if (tid == 0) {
      sLo = min(min(wlo[0], wlo[1]), min(wlo[2], wlo[3]));
      sHi = max(max(whi[0], whi[1]), max(whi[2], whi[3]));
    }
    __syncthreads();
  }
  if (sHi < 0) return;
  const int start = sLo, T = sHi - sLo + 1;
  if (img == kM) {
    for (int j = start + wid; j <= sHi; j += 4)
      o[((size_t)(b * kN + j)) * kD + h * kDH + lane] = (bf16)0.f;
    return;
  }
  for (int ch = tid; ch < 1024; ch += 256) {
    const int r = ch >> 4, d0 = (ch & 15) * 4;
    if (r < T) {
      const float* base = qkv + ((size_t)(b * kN + start + r)) * 3072 + h * kDH + d0;
      const float4 qv = *(const float4*)(base);
      const float4 kv = *(const float4*)(base + 1024);
      const float4 vv = *(const float4*)(base + 2048);
      float sq = qv.x + qv.y + qv.z + qv.w;
      float sq2 = qv.x * qv.x + qv.y * qv.y + qv.z * qv.z + qv.w * qv.w;
      float sk = kv.x + kv.y + kv.z + kv.w;
      float sk2 = kv.x * kv.x + kv.y * kv.y + kv.z * kv.z + kv.w * kv.w;
#pragma unroll
      for (int off = 1; off < 16; off <<= 1) {
        sq += __shfl_xor(sq, off); sq2 += __shfl_xor(sq2, off);
        sk += __shfl_xor(sk, off); sk2 += __shfl_xor(sk2, off);
      }
      const float qm = sq * (1.f / 64);
      const float qr = rsqrtf(sq2 * (1.f / 64) - qm * qm + 1e-5f);
      const float km = sk * (1.f / 64);
      const float kr = rsqrtf(sk2 * (1.f / 64) - km * km + 1e-5f);
      const float qe[4] = {qv.x, qv.y, qv.z, qv.w};
      const float ke[4] = {kv.x, kv.y, kv.z, kv.w};
      bf16x4 qw, kw;
#pragma unroll
      for (int e = 0; e < 4; ++e) {
        qw[e] = (bf16)((qe[e] - qm) * qr * qg[d0 + e] + qb[d0 + e]);
        kw[e] = (bf16)((ke[e] - km) * kr * kg[d0 + e] + kb[d0 + e]);
      }
      *(bf16x4*)&Qs[r][d0] = qw;
      *(bf16x4*)&Ks[r][d0] = kw;
      Vt[d0 + 0][r] = (bf16)vv.x;
      Vt[d0 + 1][r] = (bf16)vv.y;
      Vt[d0 + 2][r] = (bf16)vv.z;
      Vt[d0 + 3][r] = (bf16)vv.w;
    } else {
      const bf16x4 z = {};
      *(bf16x4*)&Qs[r][d0] = z;
      *(bf16x4*)&Ks[r][d0] = z;
      Vt[d0 + 0][r] = (bf16)0.f;
      Vt[d0 + 1][r] = (bf16)0.f;
      Vt[d0 + 2][r] = (bf16)0.f;
      Vt[d0 + 3][r] = (bf16)0.f;
    }
  }
  __syncthreads();
  const int fr = lane & 15, fg = lane >> 4;
  const int r0 = wid * 16;
  f32x4 sacc[4] = {};
#pragma unroll
  for (int k0 = 0; k0 < 64; k0 += 32) {
    const bf16x8 aq = *(const bf16x8*)&Qs[r0 + fr][k0 + fg * 8];
#pragma unroll
    for (int ni = 0; ni < 4; ++ni) {
      const bf16x8 bk = *(const bf16x8*)&Ks[ni * 16 + fr][k0 + fg * 8];
      sacc[ni] = __builtin_amdgcn_mfma_f32_16x16x32_bf16(aq, bk, sacc[ni], 0, 0, 0);
    }
  }
  float inv[4];
#pragma unroll
  for (int r = 0; r < 4; ++r) {
    float mx = kNegInf;
#pragma unroll
    for (int ni = 0; ni < 4; ++ni) {
      const float s = (ni * 16 + fr < T) ? sacc[ni][r] * kScale : kNegInf;
      sacc[ni][r] = s;
      mx = fmaxf(mx, s);
    }
#pragma unroll
    for (int off = 1; off < 16; off <<= 1) mx = fmaxf(mx, __shfl_xor(mx, off));
    float sum = 0.f;
#pragma unroll
    for (int ni = 0; ni < 4; ++ni) {
      const float p = __expf(sacc[ni][r] - mx);
      sacc[ni][r] = p;
      sum += p;
    }
#pragma unroll
    for (int off = 1; off < 16; off <<= 1) sum += __shfl_xor(sum, off);
    inv[r] = 1.f / sum;
  }
#pragma unroll
  for (int ni = 0; ni < 4; ++ni)
#pragma unroll
    for (int r = 0; r < 4; ++r)
      Ps[r0 + fg * 4 + r][ni * 16 + fr] = (bf16)sacc[ni][r];
  f32x4 oacc[4] = {};
#pragma unroll
  for (int k0 = 0; k0 < 64; k0 += 32) {
    const bf16x8 ap = *(const bf16x8*)&Ps[r0 + fr][k0 + fg * 8];
#pragma unroll
    for (int ni = 0; ni < 4; ++ni) {
      const bf16x8 bv = *(const bf16x8*)&Vt[ni * 16 + fr][k0 + fg * 8];
      oacc[ni] = __builtin_amdgcn_mfma_f32_16x16x32_bf16(ap, bv, oacc[ni], 0, 0, 0);
    }
  }
#pragma unroll
  for (int r = 0; r < 4; ++r) {
    const int i = r0 + fg * 4 + r;
    if (i < T) {
      const size_t orow = ((size_t)(b * kN + start + i)) * kD + h * kDH;
      const float iv = inv[r];
#pragma unroll
      for (int ni = 0; ni < 4; ++ni)
        o[orow + ni * 16 + fr] = (bf16)(oacc[ni][r] * iv);
    }
  }
}

// ============================================================
// Attention pooling: one wave per (b,m,h). kv layout [B,N,2048]. bf16 out.
// ============================================================
__global__ __launch_bounds__(64) void poolattn_kernel(
    const float* __restrict__ qp, const float* __restrict__ kv,
    const int* __restrict__ ids, bf16* __restrict__ o) {
  const int blk = blockIdx.x;
  const int h = blk % kH;
  const int bm = blk / kH;
  const int m = bm % kM, b = bm / kM;
  const int lane = threadIdx.x;
  __shared__ float sc[kN];
  __shared__ float qs[kDH];
  qs[lane] = qp[h * kDH + lane];
  __syncthreads();
  float mymax = kNegInf;
  int jmn = kN, jmx = -1;
  for (int j = lane; j < kN; j += 64) {
    const int idj = ids[b * kN + j];
    float s;
    if (idj == m) {
      const float* krow = kv + ((size_t)(b * kN + j)) * (2 * kD) + h * kDH;
      float dot = 0.f;
#pragma unroll
      for (int d = 0; d < kDH; ++d) dot += qs[d] * krow[d];
      s = dot * kScale;
      jmn = min(jmn, j); jmx = max(jmx, j);
    } else {
      s = kNegInf;
    }
    sc[j] = s;
    mymax = fmaxf(mymax, s);
  }
#pragma unroll
  for (int off = 32; off; off >>= 1) {
    mymax = fmaxf(mymax, __shfl_xor(mymax, off));
    jmn = min(jmn, __shfl_xor(jmn, off));
    jmx = max(jmx, __shfl_xor(jmx, off));
  }
  const int jlo = jmn, jhi = jmx + 1;
  float mysum = 0.f;
  for (int j = jlo + lane; j < jhi; j += 64) {
    const float p = __expf(sc[j] - mymax);
    sc[j] = p;
    mysum += p;
  }
#pragma unroll
  for (int off = 32; off; off >>= 1) mysum += __shfl_xor(mysum, off);
  const float inv = 1.f / mysum;
  __syncthreads();
  float acc = 0.f;
  const float* vptr = kv + ((size_t)(b * kN + jlo)) * (2 * kD) + kD + h * kDH + lane;
  for (int j = jlo; j < jhi; ++j, vptr += 2 * kD) acc += sc[j] * vptr[0];
  o[((size_t)(b * kM + m)) * kD + h * kDH + lane] = (bf16)(acc * inv);
}

// ============================================================
// driver
// ============================================================
extern "C" void kernel_launch(void* const* d_in, const int* in_sizes, int n_in,
                              void* d_out, int out_size, void* d_ws, size_t ws_size,
                              hipStream_t stream) {
  const float* patches  = (const float*)d_in[0];
  const float* pe_ln1_g = (const float*)d_in[1];
  const float* pe_ln1_b = (const float*)d_in[2];
  const float* W_pe     = (const float*)d_in[3];
  const float* b_pe     = (const float*)d_in[4];
  const float* pe_ln2_g = (const float*)d_in[5];
  const float* pe_ln2_b = (const float*)d_in[6];
  const float* pos_h    = (const float*)d_in[7];
  const float* pos_w    = (const float*)d_in[8];
  const float* ln1_g    = (const float*)d_in[9];
  const float* ln1_b    = (const float*)d_in[10];
  const float* qn_g     = (const float*)d_in[11];
  const float* qn_b     = (const float*)d_in[12];
  const float* kn_g     = (const float*)d_in[13];
  const float* kn_b     = (const float*)d_in[14];
  const float* Wq       = (const float*)d_in[15];
  const float* Wkv      = (const float*)d_in[16];
  const float* Wo       = (const float*)d_in[17];
  const float* ln2_g    = (const float*)d_in[18];
  const float* ln2_b    = (const float*)d_in[19];
  const float* W1       = (const float*)d_in[20];
  const float* b1       = (const float*)d_in[21];
  const float* W2       = (const float*)d_in[22];
  const float* b2       = (const float*)d_in[23];
  const float* fin_g    = (const float*)d_in[24];
  const float* fin_b    = (const float*)d_in[25];
  const float* pool_q   = (const float*)d_in[26];
  const float* pl_ln_g  = (const float*)d_in[27];
  const float* pl_ln_b  = (const float*)d_in[28];
  const float* pl_qn_g  = (const float*)d_in[29];
  const float* pl_qn_b  = (const float*)d_in[30];
  const float* pl_kn_g  = (const float*)d_in[31];
  const float* pl_kn_b  = (const float*)d_in[32];
  const float* pl_Wq    = (const float*)d_in[33];
  const float* pl_Wkv   = (const float*)d_in[34];
  const float* pl_Wo    = (const float*)d_in[35];
  const float* head_g   = (const float*)d_in[36];
  const float* head_b   = (const float*)d_in[37];
  const float* W_head   = (const float*)d_in[38];
  const float* b_head   = (const float*)d_in[39];
  const int* h_idx      = (const int*)d_in[40];
  const int* w_idx      = (const int*)d_in[41];
  const int* image_ids  = (const int*)d_in[42];
  float* out = (float*)d_out;

  // ---- workspace layout ----
  const size_t SZ = (size_t)kB * kN * kD;        // 2,621,440
  char* p = (char*)d_ws;
  float* x    = (float*)p;           p += SZ * 4;
  bf16*  xnb  = (bf16*)p;            p += SZ * 2;
  char*  scratch = p;                p += (SZ * 14);
  bf16*  wtbuf = (bf16*)p;           p += (size_t)kPD * kD * 2;
  char*  smalls = p;
  float* qkvb  = (float*)scratch;                          // [BN][3072] f32
  bf16*  attno = (bf16*)(scratch + SZ * 12);               // [BN][1024] bf16
  bf16*  plnb  = (bf16*)scratch;                           // [BN][3072] bf16 (embed)
  float* emb   = (float*)(scratch + SZ * 8);               // [BN][1024] f32 (embed)
  bf16*  h1b   = (bf16*)scratch;                           // [BN][2048] bf16 (mlp)
  float* kvpool = (float*)scratch;                         // [BN][2048] f32 (pool)
  bf16*  qn_vecb = (bf16*)smalls;                          // 1024 bf16
  float* qpool   = (float*)(smalls + 4096);                // 1024 f32
  bf16*  opoolb  = (bf16*)(smalls + 4096 + 4096);          // 72*1024 bf16
  float* pooled  = (float*)(smalls + 4096 + 4096 + 147456 + 8192);  // 72*1024 f32
  bf16*  pooledn = (bf16*)((char*)pooled + 72 * 1024 * 4 + 8192);   // 72*1024 bf16

  const int BN = kB * kN;          // 2560 rows
  const int nbyM = BN / 64;        // 40 row-blocks

  auto wt = [&](const float* W, bf16* WT, int K, int Ncol, int Npad) {
    wt_kernel<<<dim3(Npad / 32, K / 32), 256, 0, stream>>>(W, WT, K, Ncol);
  };

  // ---- patch embedding ----
  ln_kernel<bf16><<<BN, 256, 0, stream>>>(patches, plnb, pe_ln1_g, pe_ln1_b, kPD);
  wt(W_pe, wtbuf, kPD, kD, kD);
  gemm64_kernel<2, false, false><<<(kD / 64) * nbyM, 256, 0, stream>>>(
      plnb, wtbuf, emb, nullptr, b_pe, nullptr, kPD, kD, kD / 64);
  ln_pos_kernel<<<BN, 256, 0, stream>>>(emb, x, pe_ln2_g, pe_ln2_b, pos_h, pos_w, h_idx, w_idx);

  // ---- transformer layers ----
  for (int l = 0; l < kDepth; ++l) {
    ln_kernel<bf16><<<BN, 256, 0, stream>>>(x, xnb, ln1_g + (size_t)l * kD, ln1_b + (size_t)l * kD, kD);
    wt(Wq + (size_t)l * kD * kD, wtbuf, kD, kD, kD);
    wt(Wkv + (size_t)l * kD * 2 * kD, wtbuf + (size_t)kD * kD, kD, 2 * kD, 2 * kD);
    gemm64_kernel<4, false, false><<<(3 * kD / 128) * nbyM, 256, 0, stream>>>(
        xnb, wtbuf, qkvb, nullptr, nullptr, nullptr, kD, 3 * kD, 3 * kD / 128);
    attn_kernel<<<dim3(kH, kM + 1, kB), 256, 0, stream>>>(
        qkvb, image_ids,
        qn_g + (size_t)l * kDH, qn_b + (size_t)l * kDH,
        kn_g + (size_t)l * kDH, kn_b + (size_t)l * kDH, attno);
    wt(Wo + (size_t)l * kD * kD, wtbuf, kD, kD, kD);
    gemm64_kernel<2, false, false><<<(kD / 64) * nbyM, 256, 0, stream>>>(
        attno, wtbuf, x, nullptr, nullptr, x, kD, kD, kD / 64);
    ln_kernel<bf16><<<BN, 256, 0, stream>>>(x, xnb, ln2_g + (size_t)l * kD, ln2_b + (size_t)l * kD, kD);
    wt(W1 + (size_t)l * kD * kMLP, wtbuf, kD, kMLP, kMLP);
    gemm64_kernel<4, true, true><<<(kMLP / 128) * nbyM, 256, 0, stream>>>(
        xnb, wtbuf, nullptr, h1b, b1 + (size_t)l * kMLP, nullptr, kD, kMLP, kMLP / 128);
    wt(W2 + (size_t)l * kMLP * kD, wtbuf, kMLP, kD, kD);
    gemm64_kernel<2, false, false><<<(kD / 64) * nbyM, 256, 0, stream>>>(
        h1b, wtbuf, x, nullptr, b2 + (size_t)l * kD, x, kMLP, kD, kD / 64);
  }

  // ---- final LN (context for pooling) ----
  ln_kernel<bf16><<<BN, 256, 0, stream>>>(x, xnb, fin_g, fin_b, kD);

  // ---- attention pooling ----
  ln_kernel<bf16><<<1, 256, 0, stream>>>(pool_q, qn_vecb, pl_ln_g, pl_ln_b, kD);
  wt(pl_Wq, wtbuf, kD, kD, kD);
  gemm_tail_kernel<false><<<dim3(8, 1), 256, 0, stream>>>(
      qn_vecb, wtbuf, qpool, nullptr, nullptr, nullptr, 1, kD, kD, kD, 0);
  headln_kernel<<<kH, 64, 0, stream>>>(qpool, kD, pl_qn_g, pl_qn_b);
  wt(pl_Wkv, wtbuf, kD, 2 * kD, 2 * kD);
  gemm64_kernel<4, false, false><<<(2 * kD / 128) * nbyM, 256, 0, stream>>>(
      xnb, wtbuf, kvpool, nullptr, nullptr, nullptr, kD, 2 * kD, 2 * kD / 128);
  headln_kernel<<<BN * kH, 64, 0, stream>>>(kvpool, 2 * kD, pl_kn_g, pl_kn_b);
  poolattn_kernel<<<kB * kM * kH, 64, 0, stream>>>(qpool, kvpool, image_ids, opoolb);
  wt(pl_Wo, wtbuf, kD, kD, kD);
  gemm_tail_kernel<false><<<dim3(8, 2), 256, 0, stream>>>(
      opoolb, wtbuf, pooled, nullptr, nullptr, pool_q, kB * kM, kD, kD, kD, 2);

  // ---- classifier head ----
  ln_kernel<bf16><<<kB * kM, 256, 0, stream>>>(pooled, pooledn, head_g, head_b, kD);
  wt(W_head, wtbuf, kD, kNC, 1024);
  gemm_tail_kernel<false><<<dim3(8, 2), 256, 0, stream>>>(
      pooledn, wtbuf, out, nullptr, b_head, nullptr, kB * kM, kD, kNC, kNC, 0);
}

// Round 6
// 1117.569 us; speedup vs baseline: 7.3731x; 1.0958x over previous
//
#include <hip/hip_runtime.h>
#include <cmath>

// ---- model constants ----
constexpr int kB = 4, kN = 640, kD = 1024, kH = 16, kDH = 64;
constexpr int kDepth = 6, kMLP = 2048, kPD = 3072, kNC = 1000, kM = 18;
constexpr float kScale = 0.125f;        // DH^-0.5
constexpr float kNegInf = -3.4028235e38f;

typedef __bf16 bf16;
typedef __attribute__((ext_vector_type(8))) __bf16 bf16x8;
typedef __attribute__((ext_vector_type(4))) __bf16 bf16x4;
typedef __attribute__((ext_vector_type(4))) float f32x4;

#define AS1 __attribute__((address_space(1)))
#define AS3 __attribute__((address_space(3)))

__device__ __forceinline__ void gload16(const void* g, void* l) {
  __builtin_amdgcn_global_load_lds((AS1 void*)g, (AS3 void*)l, 16, 0, 0);
}

// ============================================================
// LayerNorm over last dim K, one block (256 threads) per row.
// ============================================================
template <typename OT>
__global__ __launch_bounds__(256) void ln_kernel(
    const float* __restrict__ in, OT* __restrict__ out,
    const float* __restrict__ g, const float* __restrict__ b, int K) {
  const int row = blockIdx.x;
  const float* x = in + (size_t)row * K;
  OT* o = out + (size_t)row * K;
  float s = 0.f, s2 = 0.f;
  for (int d = threadIdx.x; d < K; d += 256) { float v = x[d]; s += v; s2 += v * v; }
#pragma unroll
  for (int off = 32; off; off >>= 1) { s += __shfl_down(s, off); s2 += __shfl_down(s2, off); }
  __shared__ float ls[4], ls2[4];
  __shared__ float sm, sr;
  const int wid = threadIdx.x >> 6, lane = threadIdx.x & 63;
  if (lane == 0) { ls[wid] = s; ls2[wid] = s2; }
  __syncthreads();
  if (threadIdx.x == 0) {
    float a = ls[0] + ls[1] + ls[2] + ls[3];
    float a2 = ls2[0] + ls2[1] + ls2[2] + ls2[3];
    float mean = a / K;
    float var = a2 / K - mean * mean;
    sm = mean; sr = rsqrtf(var + 1e-5f);
  }
  __syncthreads();
  const float mean = sm, r = sr;
  for (int d = threadIdx.x; d < K; d += 256)
    o[d] = (OT)((x[d] - mean) * r * g[d] + b[d]);
}

// ============================================================
// Fused pe_ln2 + factorized pos-embed add. f32 out (residual base).
// ============================================================
__global__ __launch_bounds__(256) void ln_pos_kernel(
    const float* __restrict__ in, float* __restrict__ out,
    const float* __restrict__ g, const float* __restrict__ b,
    const float* __restrict__ ph, const float* __restrict__ pw,
    const int* __restrict__ hi, const int* __restrict__ wi) {
  const int row = blockIdx.x;
  const float* x = in + (size_t)row * kD;
  float* o = out + (size_t)row * kD;
  float s = 0.f, s2 = 0.f;
  for (int d = threadIdx.x; d < kD; d += 256) { float v = x[d]; s += v; s2 += v * v; }
#pragma unroll
  for (int off = 32; off; off >>= 1) { s += __shfl_down(s, off); s2 += __shfl_down(s2, off); }
  __shared__ float ls[4], ls2[4];
  __shared__ float sm, sr;
  const int wid = threadIdx.x >> 6, lane = threadIdx.x & 63;
  if (lane == 0) { ls[wid] = s; ls2[wid] = s2; }
  __syncthreads();
  if (threadIdx.x == 0) {
    float a = ls[0] + ls[1] + ls[2] + ls[3];
    float a2 = ls2[0] + ls2[1] + ls2[2] + ls2[3];
    float mean = a / kD;
    float var = a2 / kD - mean * mean;
    sm = mean; sr = rsqrtf(var + 1e-5f);
  }
  __syncthreads();
  const float mean = sm, r = sr;
  const float* phr = ph + (size_t)hi[row] * kD;
  const float* pwr = pw + (size_t)wi[row] * kD;
  for (int d = threadIdx.x; d < kD; d += 256)
    o[d] = (x[d] - mean) * r * g[d] + b[d] + phr[d] + pwr[d];
}

// ============================================================
// Per-head LayerNorm (dim DH=64), in place f32.
// ============================================================
__global__ __launch_bounds__(64) void headln_kernel(
    float* __restrict__ p, int stride,
    const float* __restrict__ g, const float* __restrict__ b) {
  const int blk = blockIdx.x;
  const int outer = blk / kH, h = blk % kH;
  float* x = p + (size_t)outer * stride + h * kDH;
  const int lane = threadIdx.x;
  float v = x[lane];
  float s = v, s2 = v * v;
#pragma unroll
  for (int off = 32; off; off >>= 1) { s += __shfl_xor(s, off); s2 += __shfl_xor(s2, off); }
  const float m = s * (1.f / kDH);
  const float var = s2 * (1.f / kDH) - m * m;
  const float r = rsqrtf(var + 1e-5f);
  x[lane] = (v - m) * r * g[lane] + b[lane];
}

// ============================================================
// Weight transpose: f32 W[K][Ncol] -> bf16 WT[Npad][K], zero-padded
// rows for n >= Ncol. grid = (Npad/32, K/32).
// ============================================================
__global__ __launch_bounds__(256) void wt_kernel(
    const float* __restrict__ W, bf16* __restrict__ WT, int K, int Ncol) {
  __shared__ float s[32][33];
  const int n0 = blockIdx.x * 32, k0 = blockIdx.y * 32;
  const int tx = threadIdx.x & 31, ty = threadIdx.x >> 5;
#pragma unroll
  for (int i = 0; i < 4; ++i) {
    const int k = ty + i * 8;
    s[k][tx] = (n0 + tx < Ncol) ? W[(size_t)(k0 + k) * Ncol + (n0 + tx)] : 0.f;
  }
  __syncthreads();
#pragma unroll
  for (int i = 0; i < 4; ++i) {
    const int n = ty + i * 8;
    WT[(size_t)(n0 + n) * K + (k0 + tx)] = (bf16)s[tx][n];
  }
}

// ============================================================
// 64x(NI*32) MFMA GEMM, BK=64, double-buffered LDS, global_load_lds
// prefetch (stage next || compute cur, ONE barrier per K-step).
// T2 XOR-swizzle: LDS row = 8 chunks of 16B; chunk ci of row r holds
// logical k-chunk (ci ^ (r&7)); source pre-swizzled, read swizzled.
// 4 waves (2x2); wave = 32 x (NI*16). XCD-chunked blockIdx swizzle.
// M%64==0, N%(NI*32)==0, K%64==0.
// ============================================================
template <int NI, bool OUT_BF, bool GELU>
__global__ __launch_bounds__(256) void gemm64_kernel(
    const bf16* __restrict__ A, const bf16* __restrict__ WT,
    float* __restrict__ Cf, bf16* __restrict__ Cb,
    const float* __restrict__ bias, const float* __restrict__ res,
    int K, int Ncol, int nbx) {
  constexpr int BN = NI * 32;
  __shared__ __align__(16) bf16 As[2][64 * 64];
  __shared__ __align__(16) bf16 Bs[2][BN * 64];
  const int tid = threadIdx.x, lane = tid & 63, wid = tid >> 6;
  const int wr = wid >> 1, wc = wid & 1;
  // XCD-chunked bijective swizzle (gridDim.x % 8 == 0 by construction)
  const int cpx = gridDim.x >> 3;
  const int swz = (blockIdx.x & 7) * cpx + (blockIdx.x >> 3);
  const int row0 = (swz / nbx) * 64, col0 = (swz % nbx) * BN;
  const int fr = lane & 15, fg = lane >> 4;
  f32x4 acc[2][NI] = {};
  bf16* sA = As[0]; bf16* sB = Bs[0];
  bf16* dA = As[1]; bf16* dB = Bs[1];

  auto stage = [&](bf16* tA, bf16* tB, int kt) {
#pragma unroll
    for (int i = 0; i < 2; ++i) {
      const int c = i * 256 + tid;
      const int r = c >> 3, ci = c & 7;
      gload16(A + (size_t)(row0 + r) * K + kt + ((ci ^ (r & 7)) * 8),
              tA + (i * 256 + wid * 64) * 8);
    }
#pragma unroll
    for (int i = 0; i < NI; ++i) {
      const int c = i * 256 + tid;
      const int r = c >> 3, ci = c & 7;
      gload16(WT + (size_t)(col0 + r) * K + kt + ((ci ^ (r & 7)) * 8),
              tB + (i * 256 + wid * 64) * 8);
    }
  };
  auto compute = [&](const bf16* tA, const bf16* tB) {
#pragma unroll
    for (int kk = 0; kk < 2; ++kk) {
      bf16x8 af[2], bfr[NI];
#pragma unroll
      for (int mi = 0; mi < 2; ++mi) {
        const int r = wr * 32 + mi * 16 + fr;
        af[mi] = *(const bf16x8*)(tA + r * 64 + (((kk * 4 + fg) ^ (r & 7)) * 8));
      }
#pragma unroll
      for (int ni = 0; ni < NI; ++ni) {
        const int r = wc * (NI * 16) + ni * 16 + fr;
        bfr[ni] = *(const bf16x8*)(tB + r * 64 + (((kk * 4 + fg) ^ (r & 7)) * 8));
      }
#pragma unroll
      for (int mi = 0; mi < 2; ++mi)
#pragma unroll
        for (int ni = 0; ni < NI; ++ni)
          acc[mi][ni] = __builtin_amdgcn_mfma_f32_16x16x32_bf16(af[mi], bfr[ni], acc[mi][ni], 0, 0, 0);
    }
  };

  const int NT = K >> 6;
  stage(sA, sB, 0);
  __syncthreads();
  for (int t = 1; t < NT; ++t) {
    stage(dA, dB, t * 64);     // prefetch next tile (drained by next barrier)
    compute(sA, sB);
    __syncthreads();
    bf16* u;
    u = sA; sA = dA; dA = u;
    u = sB; sB = dB; dB = u;
  }
  compute(sA, sB);

  // epilogue: row = row0 + wr*32 + mi*16 + fg*4 + r; col = col0 + wc*NI*16 + ni*16 + fr
  const int rb = row0 + wr * 32 + fg * 4;
  const int cb = col0 + wc * (NI * 16) + fr;
#pragma unroll
  for (int mi = 0; mi < 2; ++mi) {
#pragma unroll
    for (int ni = 0; ni < NI; ++ni) {
      const int cc = cb + ni * 16;
      const float bb = bias ? bias[cc] : 0.f;
#pragma unroll
      for (int r = 0; r < 4; ++r) {
        const int rr = rb + mi * 16 + r;
        float v = acc[mi][ni][r] + bb;
        if (res) v += res[(size_t)rr * Ncol + cc];
        if (GELU) v = 0.5f * v * (1.f + erff(v * 0.70710678118654752f));
        if (OUT_BF) Cb[(size_t)rr * Ncol + cc] = (bf16)v;
        else        Cf[(size_t)rr * Ncol + cc] = v;
      }
    }
  }
}

// ============================================================
// Guarded tail GEMM (reg-staged 64x128): small M.
// resmode: 0 none, 1 full, 2 broadcast vector.
// ============================================================
template <bool OUT_BF>
__global__ __launch_bounds__(256) void gemm_tail_kernel(
    const bf16* __restrict__ A, const bf16* __restrict__ WT,
    float* __restrict__ Cf, bf16* __restrict__ Cb,
    const float* __restrict__ bias, const float* __restrict__ resv,
    int Mr, int K, int Nc, int ldc, int resmode) {
  __shared__ __align__(16) bf16 As[64][40];
  __shared__ __align__(16) bf16 Bs[128][40];
  const int tid = threadIdx.x;
  const int lane = tid & 63, wid = tid >> 6;
  const int row0 = blockIdx.y * 64, col0 = blockIdx.x * 128;
  f32x4 acc[4][2] = {};
  const int am = tid >> 2, ako = (tid & 3) * 8;
  const int fr = lane & 15, fg = (lane >> 4) * 8;
  for (int k0 = 0; k0 < K; k0 += 32) {
    if (row0 + am < Mr)
      *(bf16x8*)&As[am][ako] = *(const bf16x8*)(A + (size_t)(row0 + am) * K + k0 + ako);
    else {
      bf16x8 z = {};
      *(bf16x8*)&As[am][ako] = z;
    }
#pragma unroll
    for (int it = 0; it < 2; ++it) {
      const int c = it * 256 + tid;
      const int n = c >> 2, ko = (c & 3) * 8;
      *(bf16x8*)&Bs[n][ko] = *(const bf16x8*)(WT + (size_t)(col0 + n) * K + k0 + ko);
    }
    __syncthreads();
    bf16x8 af[4], bfr[2];
#pragma unroll
    for (int mi = 0; mi < 4; ++mi) af[mi] = *(const bf16x8*)&As[mi * 16 + fr][fg];
#pragma unroll
    for (int ni = 0; ni < 2; ++ni) bfr[ni] = *(const bf16x8*)&Bs[wid * 32 + ni * 16 + fr][fg];
#pragma unroll
    for (int mi = 0; mi < 4; ++mi)
#pragma unroll
      for (int ni = 0; ni < 2; ++ni)
        acc[mi][ni] = __builtin_amdgcn_mfma_f32_16x16x32_bf16(af[mi], bfr[ni], acc[mi][ni], 0, 0, 0);
    __syncthreads();
  }
  const int r4 = (lane >> 4) * 4;
  const int cc0 = col0 + wid * 32 + (lane & 15);
#pragma unroll
  for (int mi = 0; mi < 4; ++mi) {
#pragma unroll
    for (int ni = 0; ni < 2; ++ni) {
      const int cc = cc0 + ni * 16;
      if (cc >= Nc) continue;
#pragma unroll
      for (int r = 0; r < 4; ++r) {
        const int rr = row0 + mi * 16 + r4 + r;
        if (rr >= Mr) continue;
        float v = acc[mi][ni][r];
        if (bias) v += bias[cc];
        if (resmode == 1) v += resv[(size_t)rr * ldc + cc];
        else if (resmode == 2) v += resv[cc];
        if (OUT_BF) Cb[(size_t)rr * ldc + cc] = (bf16)v;
        else        Cf[(size_t)rr * ldc + cc] = v;
      }
    }
  }
}

// ============================================================
// Block-diagonal MFMA attention (one block per head/image/batch).
// ============================================================
__global__ __launch_bounds__(256) void attn_kernel(
    const float* __restrict__ qkv, const int* __restrict__ ids,
    const float* __restrict__ qg, const float* __restrict__ qb,
    const float* __restrict__ kg, const float* __restrict__ kb,
    bf16* __restrict__ o) {
  const int h = blockIdx.x, img = blockIdx.y, b = blockIdx.z;
  const int tid = threadIdx.x, lane = tid & 63, wid = tid >> 6;
  __shared__ __align__(16) bf16 Qs[64][72];
  __shared__ __align__(16) bf16 Ks[64][72];
  __shared__ __align__(16) bf16 Vt[64][72];
  __shared__ __align__(16) bf16 Ps[64][72];
  __shared__ int wlo[4], whi[4];
  __shared__ int sLo, sHi;
  {
    const int want = (img < kM) ? img : -1;
    int lo = kN, hi = -1;
    for (int j = tid; j < kN; j += 256) {
      if (ids[b * kN + j] == want) { lo = min(lo, j); hi = max(hi, j); }
    }
#pragma unroll
    for (int off = 32; off; off >>= 1) {
      lo = min(lo, __shfl_xor(lo, off));
      hi = max(hi, __shfl_xor(hi, off));
    }
    if (lane == 0) { wlo[wid] = lo; whi[wid] = hi; }
    __syncthreads();
    if (tid == 0) {
      sLo = min(min(wlo[0], wlo[1]), min(wlo[2], wlo[3]));
      sHi = max(max(whi[0], whi[1]), max(whi[2], whi[3]));
    }
    __syncthreads();
  }
  if (sHi < 0) return;
  const int start = sLo, T = sHi - sLo + 1;
  if (img == kM) {
    for (int j = start + wid; j <= sHi; j += 4)
      o[((size_t)(b * kN + j)) * kD + h * kDH + lane] = (bf16)0.f;
    return;
  }
  for (int ch = tid; ch < 1024; ch += 256) {
    const int r = ch >> 4, d0 = (ch & 15) * 4;
    if (r < T) {
      const float* base = qkv + ((size_t)(b * kN + start + r)) * 3072 + h * kDH + d0;
      const float4 qv = *(const float4*)(base);
      const float4 kv = *(const float4*)(base + 1024);
      const float4 vv = *(const float4*)(base + 2048);
      float sq = qv.x + qv.y + qv.z + qv.w;
      float sq2 = qv.x * qv.x + qv.y * qv.y + qv.z * qv.z + qv.w * qv.w;
      float sk = kv.x + kv.y + kv.z + kv.w;
      float sk2 = kv.x * kv.x + kv.y * kv.y + kv.z * kv.z + kv.w * kv.w;
#pragma unroll
      for (int off = 1; off < 16; off <<= 1) {
        sq += __shfl_xor(sq, off); sq2 += __shfl_xor(sq2, off);
        sk += __shfl_xor(sk, off); sk2 += __shfl_xor(sk2, off);
      }
      const float qm = sq * (1.f / 64);
      const float qr = rsqrtf(sq2 * (1.f / 64) - qm * qm + 1e-5f);
      const float km = sk * (1.f / 64);
      const float kr = rsqrtf(sk2 * (1.f / 64) - km * km + 1e-5f);
      const float qe[4] = {qv.x, qv.y, qv.z, qv.w};
      const float ke[4] = {kv.x, kv.y, kv.z, kv.w};
      bf16x4 qw, kw;
#pragma unroll
      for (int e = 0; e < 4; ++e) {
        qw[e] = (bf16)((qe[e] - qm) * qr * qg[d0 + e] + qb[d0 + e]);
        kw[e] = (bf16)((ke[e] - km) * kr * kg[d0 + e] + kb[d0 + e]);
      }
      *(bf16x4*)&Qs[r][d0] = qw;
      *(bf16x4*)&Ks[r][d0] = kw;
      Vt[d0 + 0][r] = (bf16)vv.x;
      Vt[d0 + 1][r] = (bf16)vv.y;
      Vt[d0 + 2][r] = (bf16)vv.z;
      Vt[d0 + 3][r] = (bf16)vv.w;
    } else {
      const bf16x4 z = {};
      *(bf16x4*)&Qs[r][d0] = z;
      *(bf16x4*)&Ks[r][d0] = z;
      Vt[d0 + 0][r] = (bf16)0.f;
      Vt[d0 + 1][r] = (bf16)0.f;
      Vt[d0 + 2][r] = (bf16)0.f;
      Vt[d0 + 3][r] = (bf16)0.f;
    }
  }
  __syncthreads();
  const int fr = lane & 15, fg = lane >> 4;
  const int r0 = wid * 16;
  f32x4 sacc[4] = {};
#pragma unroll
  for (int k0 = 0; k0 < 64; k0 += 32) {
    const bf16x8 aq = *(const bf16x8*)&Qs[r0 + fr][k0 + fg * 8];
#pragma unroll
    for (int ni = 0; ni < 4; ++ni) {
      const bf16x8 bk = *(const bf16x8*)&Ks[ni * 16 + fr][k0 + fg * 8];
      sacc[ni] = __builtin_amdgcn_mfma_f32_16x16x32_bf16(aq, bk, sacc[ni], 0, 0, 0);
    }
  }
  float inv[4];
#pragma unroll
  for (int r = 0; r < 4; ++r) {
    float mx = kNegInf;
#pragma unroll
    for (int ni = 0; ni < 4; ++ni) {
      const float s = (ni * 16 + fr < T) ? sacc[ni][r] * kScale : kNegInf;
      sacc[ni][r] = s;
      mx = fmaxf(mx, s);
    }
#pragma unroll
    for (int off = 1; off < 16; off <<= 1) mx = fmaxf(mx, __shfl_xor(mx, off));
    float sum = 0.f;
#pragma unroll
    for (int ni = 0; ni < 4; ++ni) {
      const float p = __expf(sacc[ni][r] - mx);
      sacc[ni][r] = p;
      sum += p;
    }
#pragma unroll
    for (int off = 1; off < 16; off <<= 1) sum += __shfl_xor(sum, off);
    inv[r] = 1.f / sum;
  }
#pragma unroll
  for (int ni = 0; ni < 4; ++ni)
#pragma unroll
    for (int r = 0; r < 4; ++r)
      Ps[r0 + fg * 4 + r][ni * 16 + fr] = (bf16)sacc[ni][r];
  f32x4 oacc[4] = {};
#pragma unroll
  for (int k0 = 0; k0 < 64; k0 += 32) {
    const bf16x8 ap = *(const bf16x8*)&Ps[r0 + fr][k0 + fg * 8];
#pragma unroll
    for (int ni = 0; ni < 4; ++ni) {
      const bf16x8 bv = *(const bf16x8*)&Vt[ni * 16 + fr][k0 + fg * 8];
      oacc[ni] = __builtin_amdgcn_mfma_f32_16x16x32_bf16(ap, bv, oacc[ni], 0, 0, 0);
    }
  }
#pragma unroll
  for (int r = 0; r < 4; ++r) {
    const int i = r0 + fg * 4 + r;
    if (i < T) {
      const size_t orow = ((size_t)(b * kN + start + i)) * kD + h * kDH;
      const float iv = inv[r];
#pragma unroll
      for (int ni = 0; ni < 4; ++ni)
        o[orow + ni * 16 + fr] = (bf16)(oacc[ni][r] * iv);
    }
  }
}

// ============================================================
// Attention pooling: one wave per (b,m,h). kv layout [B,N,2048]. bf16 out.
// ============================================================
__global__ __launch_bounds__(64) void poolattn_kernel(
    const float* __restrict__ qp, const float* __restrict__ kv,
    const int* __restrict__ ids, bf16* __restrict__ o) {
  const int blk = blockIdx.x;
  const int h = blk % kH;
  const int bm = blk / kH;
  const int m = bm % kM, b = bm / kM;
  const int lane = threadIdx.x;
  __shared__ float sc[kN];
  __shared__ float qs[kDH];
  qs[lane] = qp[h * kDH + lane];
  __syncthreads();
  float mymax = kNegInf;
  int jmn = kN, jmx = -1;
  for (int j = lane; j < kN; j += 64) {
    const int idj = ids[b * kN + j];
    float s;
    if (idj == m) {
      const float* krow = kv + ((size_t)(b * kN + j)) * (2 * kD) + h * kDH;
      float dot = 0.f;
#pragma unroll
      for (int d = 0; d < kDH; ++d) dot += qs[d] * krow[d];
      s = dot * kScale;
      jmn = min(jmn, j); jmx = max(jmx, j);
    } else {
      s = kNegInf;
    }
    sc[j] = s;
    mymax = fmaxf(mymax, s);
  }
#pragma unroll
  for (int off = 32; off; off >>= 1) {
    mymax = fmaxf(mymax, __shfl_xor(mymax, off));
    jmn = min(jmn, __shfl_xor(jmn, off));
    jmx = max(jmx, __shfl_xor(jmx, off));
  }
  const int jlo = jmn, jhi = jmx + 1;
  float mysum = 0.f;
  for (int j = jlo + lane; j < jhi; j += 64) {
    const float p = __expf(sc[j] - mymax);
    sc[j] = p;
    mysum += p;
  }
#pragma unroll
  for (int off = 32; off; off >>= 1) mysum += __shfl_xor(mysum, off);
  const float inv = 1.f / mysum;
  __syncthreads();
  float acc = 0.f;
  const float* vptr = kv + ((size_t)(b * kN + jlo)) * (2 * kD) + kD + h * kDH + lane;
  for (int j = jlo; j < jhi; ++j, vptr += 2 * kD) acc += sc[j] * vptr[0];
  o[((size_t)(b * kM + m)) * kD + h * kDH + lane] = (bf16)(acc * inv);
}

// ============================================================
// driver
// ============================================================
extern "C" void kernel_launch(void* const* d_in, const int* in_sizes, int n_in,
                              void* d_out, int out_size, void* d_ws, size_t ws_size,
                              hipStream_t stream) {
  const float* patches  = (const float*)d_in[0];
  const float* pe_ln1_g = (const float*)d_in[1];
  const float* pe_ln1_b = (const float*)d_in[2];
  const float* W_pe     = (const float*)d_in[3];
  const float* b_pe     = (const float*)d_in[4];
  const float* pe_ln2_g = (const float*)d_in[5];
  const float* pe_ln2_b = (const float*)d_in[6];
  const float* pos_h    = (const float*)d_in[7];
  const float* pos_w    = (const float*)d_in[8];
  const float* ln1_g    = (const float*)d_in[9];
  const float* ln1_b    = (const float*)d_in[10];
  const float* qn_g     = (const float*)d_in[11];
  const float* qn_b     = (const float*)d_in[12];
  const float* kn_g     = (const float*)d_in[13];
  const float* kn_b     = (const float*)d_in[14];
  const float* Wq       = (const float*)d_in[15];
  const float* Wkv      = (const float*)d_in[16];
  const float* Wo       = (const float*)d_in[17];
  const float* ln2_g    = (const float*)d_in[18];
  const float* ln2_b    = (const float*)d_in[19];
  const float* W1       = (const float*)d_in[20];
  const float* b1       = (const float*)d_in[21];
  const float* W2       = (const float*)d_in[22];
  const float* b2       = (const float*)d_in[23];
  const float* fin_g    = (const float*)d_in[24];
  const float* fin_b    = (const float*)d_in[25];
  const float* pool_q   = (const float*)d_in[26];
  const float* pl_ln_g  = (const float*)d_in[27];
  const float* pl_ln_b  = (const float*)d_in[28];
  const float* pl_qn_g  = (const float*)d_in[29];
  const float* pl_qn_b  = (const float*)d_in[30];
  const float* pl_kn_g  = (const float*)d_in[31];
  const float* pl_kn_b  = (const float*)d_in[32];
  const float* pl_Wq    = (const float*)d_in[33];
  const float* pl_Wkv   = (const float*)d_in[34];
  const float* pl_Wo    = (const float*)d_in[35];
  const float* head_g   = (const float*)d_in[36];
  const float* head_b   = (const float*)d_in[37];
  const float* W_head   = (const float*)d_in[38];
  const float* b_head   = (const float*)d_in[39];
  const int* h_idx      = (const int*)d_in[40];
  const int* w_idx      = (const int*)d_in[41];
  const int* image_ids  = (const int*)d_in[42];
  float* out = (float*)d_out;

  // ---- workspace layout ----
  const size_t SZ = (size_t)kB * kN * kD;        // 2,621,440
  char* p = (char*)d_ws;
  float* x    = (float*)p;           p += SZ * 4;
  bf16*  xnb  = (bf16*)p;            p += SZ * 2;
  char*  scratch = p;                p += (SZ * 14);
  bf16*  wtbuf = (bf16*)p;           p += (size_t)kPD * kD * 2;
  char*  smalls = p;
  float* qkvb  = (float*)scratch;                          // [BN][3072] f32
  bf16*  attno = (bf16*)(scratch + SZ * 12);               // [BN][1024] bf16
  bf16*  plnb  = (bf16*)scratch;                           // [BN][3072] bf16 (embed)
  float* emb   = (float*)(scratch + SZ * 8);               // [BN][1024] f32 (embed)
  bf16*  h1b   = (bf16*)scratch;                           // [BN][2048] bf16 (mlp)
  float* kvpool = (float*)scratch;                         // [BN][2048] f32 (pool)
  bf16*  qn_vecb = (bf16*)smalls;                          // 1024 bf16
  float* qpool   = (float*)(smalls + 4096);                // 1024 f32
  bf16*  opoolb  = (bf16*)(smalls + 4096 + 4096);          // 72*1024 bf16
  float* pooled  = (float*)(smalls + 4096 + 4096 + 147456 + 8192);  // 72*1024 f32
  bf16*  pooledn = (bf16*)((char*)pooled + 72 * 1024 * 4 + 8192);   // 72*1024 bf16

  const int BN = kB * kN;          // 2560 rows
  const int nbyM = BN / 64;        // 40 row-blocks

  auto wt = [&](const float* W, bf16* WT, int K, int Ncol, int Npad) {
    wt_kernel<<<dim3(Npad / 32, K / 32), 256, 0, stream>>>(W, WT, K, Ncol);
  };

  // ---- patch embedding ----
  ln_kernel<bf16><<<BN, 256, 0, stream>>>(patches, plnb, pe_ln1_g, pe_ln1_b, kPD);
  wt(W_pe, wtbuf, kPD, kD, kD);
  gemm64_kernel<2, false, false><<<(kD / 64) * nbyM, 256, 0, stream>>>(
      plnb, wtbuf, emb, nullptr, b_pe, nullptr, kPD, kD, kD / 64);
  ln_pos_kernel<<<BN, 256, 0, stream>>>(emb, x, pe_ln2_g, pe_ln2_b, pos_h, pos_w, h_idx, w_idx);

  // ---- transformer layers ----
  for (int l = 0; l < kDepth; ++l) {
    ln_kernel<bf16><<<BN, 256, 0, stream>>>(x, xnb, ln1_g + (size_t)l * kD, ln1_b + (size_t)l * kD, kD);
    wt(Wq + (size_t)l * kD * kD, wtbuf, kD, kD, kD);
    wt(Wkv + (size_t)l * kD * 2 * kD, wtbuf + (size_t)kD * kD, kD, 2 * kD, 2 * kD);
    gemm64_kernel<4, false, false><<<(3 * kD / 128) * nbyM, 256, 0, stream>>>(
        xnb, wtbuf, qkvb, nullptr, nullptr, nullptr, kD, 3 * kD, 3 * kD / 128);
    attn_kernel<<<dim3(kH, kM + 1, kB), 256, 0, stream>>>(
        qkvb, image_ids,
        qn_g + (size_t)l * kDH, qn_b + (size_t)l * kDH,
        kn_g + (size_t)l * kDH, kn_b + (size_t)l * kDH, attno);
    wt(Wo + (size_t)l * kD * kD, wtbuf, kD, kD, kD);
    gemm64_kernel<2, false, false><<<(kD / 64) * nbyM, 256, 0, stream>>>(
        attno, wtbuf, x, nullptr, nullptr, x, kD, kD, kD / 64);
    ln_kernel<bf16><<<BN, 256, 0, stream>>>(x, xnb, ln2_g + (size_t)l * kD, ln2_b + (size_t)l * kD, kD);
    wt(W1 + (size_t)l * kD * kMLP, wtbuf, kD, kMLP, kMLP);
    gemm64_kernel<4, true, true><<<(kMLP / 128) * nbyM, 256, 0, stream>>>(
        xnb, wtbuf, nullptr, h1b, b1 + (size_t)l * kMLP, nullptr, kD, kMLP, kMLP / 128);
    wt(W2 + (size_t)l * kMLP * kD, wtbuf, kMLP, kD, kD);
    gemm64_kernel<2, false, false><<<(kD / 64) * nbyM, 256, 0, stream>>>(
        h1b, wtbuf, x, nullptr, b2 + (size_t)l * kD, x, kMLP, kD, kD / 64);
  }

  // ---- final LN (context for pooling) ----
  ln_kernel<bf16><<<BN, 256, 0, stream>>>(x, xnb, fin_g, fin_b, kD);

  // ---- attention pooling ----
  ln_kernel<bf16><<<1, 256, 0, stream>>>(pool_q, qn_vecb, pl_ln_g, pl_ln_b, kD);
  wt(pl_Wq, wtbuf, kD, kD, kD);
  gemm_tail_kernel<false><<<dim3(8, 1), 256, 0, stream>>>(
      qn_vecb, wtbuf, qpool, nullptr, nullptr, nullptr, 1, kD, kD, kD, 0);
  headln_kernel<<<kH, 64, 0, stream>>>(qpool, kD, pl_qn_g, pl_qn_b);
  wt(pl_Wkv, wtbuf, kD, 2 * kD, 2 * kD);
  gemm64_kernel<4, false, false><<<(2 * kD / 128) * nbyM, 256, 0, stream>>>(
      xnb, wtbuf, kvpool, nullptr, nullptr, nullptr, kD, 2 * kD, 2 * kD / 128);
  headln_kernel<<<BN * kH, 64, 0, stream>>>(kvpool, 2 * kD, pl_kn_g, pl_kn_b);
  poolattn_kernel<<<kB * kM * kH, 64, 0, stream>>>(qpool, kvpool, image_ids, opoolb);
  wt(pl_Wo, wtbuf, kD, kD, kD);
  gemm_tail_kernel<false><<<dim3(8, 2), 256, 0, stream>>>(
      opoolb, wtbuf, pooled, nullptr, nullptr, pool_q, kB * kM, kD, kD, kD, 2);

  // ---- classifier head ----
  ln_kernel<bf16><<<kB * kM, 256, 0, stream>>>(pooled, pooledn, head_g, head_b, kD);
  wt(W_head, wtbuf, kD, kNC, 1024);
  gemm_tail_kernel<false><<<dim3(8, 2), 256, 0, stream>>>(
      pooledn, wtbuf, out, nullptr, b_head, nullptr, kB * kM, kD, kNC, kNC, 0);
}

// Round 7
// 1018.166 us; speedup vs baseline: 8.0930x; 1.0976x over previous
//
#include <hip/hip_runtime.h>
#include <cmath>

// ---- model constants ----
constexpr int kB = 4, kN = 640, kD = 1024, kH = 16, kDH = 64;
constexpr int kDepth = 6, kMLP = 2048, kPD = 3072, kNC = 1000, kM = 18;
constexpr float kScale = 0.125f;        // DH^-0.5
constexpr float kNegInf = -3.4028235e38f;

typedef __bf16 bf16;
typedef __attribute__((ext_vector_type(8))) __bf16 bf16x8;
typedef __attribute__((ext_vector_type(4))) __bf16 bf16x4;
typedef __attribute__((ext_vector_type(4))) float f32x4;

#define AS1 __attribute__((address_space(1)))
#define AS3 __attribute__((address_space(3)))

__device__ __forceinline__ void gload16(const void* g, void* l) {
  __builtin_amdgcn_global_load_lds((AS1 void*)g, (AS3 void*)l, 16, 0, 0);
}

// ---- wtbuf element offsets (bf16 elems) ----
constexpr size_t kMEG = 1048576;
constexpr size_t kOffPe = 0;                              // 3072x1024
constexpr size_t kLayer0 = 3 * kMEG;                      // after W_pe^T
constexpr size_t kLayerSz = 8 * kMEG;                     // WqT 1M | WkvT 2M | WoT 1M | W1T 2M | W2T 2M
constexpr size_t kOffPool = kLayer0 + 6 * kLayerSz;       // 51M
constexpr size_t kOffPlWq = kOffPool;
constexpr size_t kOffPlWkv = kOffPool + 1 * kMEG;
constexpr size_t kOffPlWo = kOffPool + 3 * kMEG;
constexpr size_t kOffHead = kOffPool + 4 * kMEG;
constexpr size_t kWtTotal = kOffHead + 1 * kMEG;          // 56M elems = 112 MB

// ============================================================
// Batched weight transpose: 35 jobs, f32 W[K][Nc] -> bf16 WT[Np][K]
// grid = (3072, 35); early-exit when tile >= job tiles.
// ============================================================
__global__ __launch_bounds__(256) void wt_all_kernel(
    const float* __restrict__ pe, const float* __restrict__ wq,
    const float* __restrict__ wkv, const float* __restrict__ wo,
    const float* __restrict__ w1, const float* __restrict__ w2,
    const float* __restrict__ plq, const float* __restrict__ plkv,
    const float* __restrict__ plo, const float* __restrict__ whead,
    bf16* __restrict__ WTB) {
  const int j = blockIdx.y;
  const float* W;
  size_t doff;
  int K, Nc, Np;
  if (j == 0) {
    W = pe; K = 3072; Nc = 1024; Np = 1024; doff = kOffPe;
  } else if (j < 31) {
    const int l = (j - 1) / 5, w = (j - 1) % 5;
    const size_t lbase = kLayer0 + (size_t)l * kLayerSz;
    switch (w) {
      case 0:  W = wq  + (size_t)l * kMEG;     K = 1024; Nc = 1024; doff = lbase;            break;
      case 1:  W = wkv + (size_t)l * 2 * kMEG; K = 1024; Nc = 2048; doff = lbase + kMEG;     break;
      case 2:  W = wo  + (size_t)l * kMEG;     K = 1024; Nc = 1024; doff = lbase + 3 * kMEG; break;
      case 3:  W = w1  + (size_t)l * 2 * kMEG; K = 1024; Nc = 2048; doff = lbase + 4 * kMEG; break;
      default: W = w2  + (size_t)l * 2 * kMEG; K = 2048; Nc = 1024; doff = lbase + 6 * kMEG; break;
    }
    Np = Nc;
  } else if (j == 31) { W = plq;  K = 1024; Nc = 1024; Np = 1024; doff = kOffPlWq; }
  else if (j == 32)   { W = plkv; K = 1024; Nc = 2048; Np = 2048; doff = kOffPlWkv; }
  else if (j == 33)   { W = plo;  K = 1024; Nc = 1024; Np = 1024; doff = kOffPlWo; }
  else                { W = whead; K = 1024; Nc = 1000; Np = 1024; doff = kOffHead; }
  const int nbx = Np >> 5;
  const int ntiles = nbx * (K >> 5);
  const int tile = blockIdx.x;
  if (tile >= ntiles) return;
  const int n0 = (tile % nbx) * 32, k0 = (tile / nbx) * 32;
  bf16* WT = WTB + doff;
  __shared__ float s[32][33];
  const int tx = threadIdx.x & 31, ty = threadIdx.x >> 5;
#pragma unroll
  for (int i = 0; i < 4; ++i) {
    const int k = ty + i * 8;
    s[k][tx] = (n0 + tx < Nc) ? W[(size_t)(k0 + k) * Nc + (n0 + tx)] : 0.f;
  }
  __syncthreads();
#pragma unroll
  for (int i = 0; i < 4; ++i) {
    const int n = ty + i * 8;
    WT[(size_t)(n0 + n) * K + (k0 + tx)] = (bf16)s[tx][n];
  }
}

// ============================================================
// LayerNorm over last dim K (K%1024==0), float4 loads.
// ============================================================
template <typename OT>
__global__ __launch_bounds__(256) void ln_kernel(
    const float* __restrict__ in, OT* __restrict__ out,
    const float* __restrict__ g, const float* __restrict__ b, int K) {
  const int row = blockIdx.x;
  const float* x = in + (size_t)row * K;
  OT* o = out + (size_t)row * K;
  const int K4 = K >> 2;
  float s = 0.f, s2 = 0.f;
  for (int c = threadIdx.x; c < K4; c += 256) {
    const float4 v = ((const float4*)x)[c];
    s += v.x + v.y + v.z + v.w;
    s2 += v.x * v.x + v.y * v.y + v.z * v.z + v.w * v.w;
  }
#pragma unroll
  for (int off = 32; off; off >>= 1) { s += __shfl_down(s, off); s2 += __shfl_down(s2, off); }
  __shared__ float ls[4], ls2[4];
  __shared__ float sm, sr;
  const int wid = threadIdx.x >> 6, lane = threadIdx.x & 63;
  if (lane == 0) { ls[wid] = s; ls2[wid] = s2; }
  __syncthreads();
  if (threadIdx.x == 0) {
    float a = ls[0] + ls[1] + ls[2] + ls[3];
    float a2 = ls2[0] + ls2[1] + ls2[2] + ls2[3];
    float mean = a / K;
    float var = a2 / K - mean * mean;
    sm = mean; sr = rsqrtf(var + 1e-5f);
  }
  __syncthreads();
  const float mean = sm, r = sr;
  for (int c = threadIdx.x; c < K4; c += 256) {
    const float4 v = ((const float4*)x)[c];
    const float4 gv = ((const float4*)g)[c];
    const float4 bv = ((const float4*)b)[c];
    const int d = c * 4;
    o[d + 0] = (OT)((v.x - mean) * r * gv.x + bv.x);
    o[d + 1] = (OT)((v.y - mean) * r * gv.y + bv.y);
    o[d + 2] = (OT)((v.z - mean) * r * gv.z + bv.z);
    o[d + 3] = (OT)((v.w - mean) * r * gv.w + bv.w);
  }
}

// ============================================================
// Fused pe_ln2 + factorized pos-embed add (f32 out).
// ============================================================
__global__ __launch_bounds__(256) void ln_pos_kernel(
    const float* __restrict__ in, float* __restrict__ out,
    const float* __restrict__ g, const float* __restrict__ b,
    const float* __restrict__ ph, const float* __restrict__ pw,
    const int* __restrict__ hi, const int* __restrict__ wi) {
  const int row = blockIdx.x;
  const float* x = in + (size_t)row * kD;
  float* o = out + (size_t)row * kD;
  float s = 0.f, s2 = 0.f;
  for (int c = threadIdx.x; c < 256; c += 256) {
    const float4 v = ((const float4*)x)[c];
    s += v.x + v.y + v.z + v.w;
    s2 += v.x * v.x + v.y * v.y + v.z * v.z + v.w * v.w;
  }
#pragma unroll
  for (int off = 32; off; off >>= 1) { s += __shfl_down(s, off); s2 += __shfl_down(s2, off); }
  __shared__ float ls[4], ls2[4];
  __shared__ float sm, sr;
  const int wid = threadIdx.x >> 6, lane = threadIdx.x & 63;
  if (lane == 0) { ls[wid] = s; ls2[wid] = s2; }
  __syncthreads();
  if (threadIdx.x == 0) {
    float a = ls[0] + ls[1] + ls[2] + ls[3];
    float a2 = ls2[0] + ls2[1] + ls2[2] + ls2[3];
    float mean = a / kD;
    float var = a2 / kD - mean * mean;
    sm = mean; sr = rsqrtf(var + 1e-5f);
  }
  __syncthreads();
  const float mean = sm, r = sr;
  const float4* phr = (const float4*)(ph + (size_t)hi[row] * kD);
  const float4* pwr = (const float4*)(pw + (size_t)wi[row] * kD);
  const int c = threadIdx.x;
  const float4 v = ((const float4*)x)[c];
  const float4 gv = ((const float4*)g)[c];
  const float4 bv = ((const float4*)b)[c];
  const float4 hv = phr[c], wv = pwr[c];
  float4 ov;
  ov.x = (v.x - mean) * r * gv.x + bv.x + hv.x + wv.x;
  ov.y = (v.y - mean) * r * gv.y + bv.y + hv.y + wv.y;
  ov.z = (v.z - mean) * r * gv.z + bv.z + hv.z + wv.z;
  ov.w = (v.w - mean) * r * gv.w + bv.w + hv.w + wv.w;
  ((float4*)o)[c] = ov;
}

// ============================================================
// Per-head LayerNorm (dim DH=64), in place f32 (pool kv path).
// ============================================================
__global__ __launch_bounds__(64) void headln_kernel(
    float* __restrict__ p, int stride,
    const float* __restrict__ g, const float* __restrict__ b) {
  const int blk = blockIdx.x;
  const int outer = blk / kH, h = blk % kH;
  float* x = p + (size_t)outer * stride + h * kDH;
  const int lane = threadIdx.x;
  float v = x[lane];
  float s = v, s2 = v * v;
#pragma unroll
  for (int off = 32; off; off >>= 1) { s += __shfl_xor(s, off); s2 += __shfl_xor(s2, off); }
  const float m = s * (1.f / kDH);
  const float var = s2 * (1.f / kDH) - m * m;
  const float r = rsqrtf(var + 1e-5f);
  x[lane] = (v - m) * r * g[lane] + b[lane];
}

// ============================================================
// Fused pool-query chain: LN(pool_q) -> @pl_Wq^T(bf16) -> head LN.
// 16 blocks (one per head) x 256 threads. qpool: [1024] f32.
// ============================================================
__global__ __launch_bounds__(256) void poolq_kernel(
    const float* __restrict__ pq, const float* __restrict__ lg,
    const float* __restrict__ lb, const bf16* __restrict__ WqT,
    const float* __restrict__ qg, const float* __restrict__ qb,
    float* __restrict__ qpool) {
  const int h = blockIdx.x, tid = threadIdx.x;
  __shared__ float qs[1024];
  __shared__ float red[256];
  __shared__ float ls[4], ls2[4];
  __shared__ float sm, sr;
  // LN of pool_q (redundant per block; tiny)
  const float4 v = ((const float4*)pq)[tid];
  float s = v.x + v.y + v.z + v.w;
  float s2 = v.x * v.x + v.y * v.y + v.z * v.z + v.w * v.w;
#pragma unroll
  for (int off = 32; off; off >>= 1) { s += __shfl_down(s, off); s2 += __shfl_down(s2, off); }
  const int wid = tid >> 6, lane = tid & 63;
  if (lane == 0) { ls[wid] = s; ls2[wid] = s2; }
  __syncthreads();
  if (tid == 0) {
    float a = ls[0] + ls[1] + ls[2] + ls[3];
    float a2 = ls2[0] + ls2[1] + ls2[2] + ls2[3];
    float mean = a / kD;
    sm = mean; sr = rsqrtf(a2 / kD - mean * mean + 1e-5f);
  }
  __syncthreads();
  {
    const float mean = sm, r = sr;
    const float4 gv = ((const float4*)lg)[tid];
    const float4 bv = ((const float4*)lb)[tid];
    qs[tid * 4 + 0] = (v.x - mean) * r * gv.x + bv.x;
    qs[tid * 4 + 1] = (v.y - mean) * r * gv.y + bv.y;
    qs[tid * 4 + 2] = (v.z - mean) * r * gv.z + bv.z;
    qs[tid * 4 + 3] = (v.w - mean) * r * gv.w + bv.w;
  }
  __syncthreads();
  // dot: output d = tid&63, quarter = tid>>6
  const int d = tid & 63, qq = tid >> 6;
  const bf16* wrow = WqT + (size_t)(h * 64 + d) * 1024 + qq * 256;
  const float* qp = qs + qq * 256;
  float part = 0.f;
  for (int k = 0; k < 256; k += 8) {
    const bf16x8 w8 = *(const bf16x8*)(wrow + k);
#pragma unroll
    for (int e = 0; e < 8; ++e) part += qp[k + e] * (float)w8[e];
  }
  red[tid] = part;
  __syncthreads();
  if (tid < 64) {
    const float dot = red[tid] + red[tid + 64] + red[tid + 128] + red[tid + 192];
    float hs = dot, hs2 = dot * dot;
#pragma unroll
    for (int off = 32; off; off >>= 1) { hs += __shfl_xor(hs, off); hs2 += __shfl_xor(hs2, off); }
    const float m = hs * (1.f / kDH);
    const float r = rsqrtf(hs2 * (1.f / kDH) - m * m + 1e-5f);
    qpool[h * 64 + tid] = (dot - m) * r * qg[tid] + qb[tid];
  }
}

// ============================================================
// 64x(NI*32) MFMA GEMM, BK=64, dbuf LDS + global_load_lds prefetch,
// T2 XOR-swizzle (source pre-swizzled, read swizzled), XCD swizzle.
// ============================================================
template <int NI, bool OUT_BF, bool GELU>
__global__ __launch_bounds__(256) void gemm64_kernel(
    const bf16* __restrict__ A, const bf16* __restrict__ WT,
    float* __restrict__ Cf, bf16* __restrict__ Cb,
    const float* __restrict__ bias, const float* __restrict__ res,
    int K, int Ncol, int nbx) {
  constexpr int BN = NI * 32;
  __shared__ __align__(16) bf16 As[2][64 * 64];
  __shared__ __align__(16) bf16 Bs[2][BN * 64];
  const int tid = threadIdx.x, lane = tid & 63, wid = tid >> 6;
  const int wr = wid >> 1, wc = wid & 1;
  const int cpx = gridDim.x >> 3;
  const int swz = (blockIdx.x & 7) * cpx + (blockIdx.x >> 3);
  const int row0 = (swz / nbx) * 64, col0 = (swz % nbx) * BN;
  const int fr = lane & 15, fg = lane >> 4;
  f32x4 acc[2][NI] = {};
  bf16* sA = As[0]; bf16* sB = Bs[0];
  bf16* dA = As[1]; bf16* dB = Bs[1];

  auto stage = [&](bf16* tA, bf16* tB, int kt) {
#pragma unroll
    for (int i = 0; i < 2; ++i) {
      const int c = i * 256 + tid;
      const int r = c >> 3, ci = c & 7;
      gload16(A + (size_t)(row0 + r) * K + kt + ((ci ^ (r & 7)) * 8),
              tA + (i * 256 + wid * 64) * 8);
    }
#pragma unroll
    for (int i = 0; i < NI; ++i) {
      const int c = i * 256 + tid;
      const int r = c >> 3, ci = c & 7;
      gload16(WT + (size_t)(col0 + r) * K + kt + ((ci ^ (r & 7)) * 8),
              tB + (i * 256 + wid * 64) * 8);
    }
  };
  auto compute = [&](const bf16* tA, const bf16* tB) {
#pragma unroll
    for (int kk = 0; kk < 2; ++kk) {
      bf16x8 af[2], bfr[NI];
#pragma unroll
      for (int mi = 0; mi < 2; ++mi) {
        const int r = wr * 32 + mi * 16 + fr;
        af[mi] = *(const bf16x8*)(tA + r * 64 + (((kk * 4 + fg) ^ (r & 7)) * 8));
      }
#pragma unroll
      for (int ni = 0; ni < NI; ++ni) {
        const int r = wc * (NI * 16) + ni * 16 + fr;
        bfr[ni] = *(const bf16x8*)(tB + r * 64 + (((kk * 4 + fg) ^ (r & 7)) * 8));
      }
#pragma unroll
      for (int mi = 0; mi < 2; ++mi)
#pragma unroll
        for (int ni = 0; ni < NI; ++ni)
          acc[mi][ni] = __builtin_amdgcn_mfma_f32_16x16x32_bf16(af[mi], bfr[ni], acc[mi][ni], 0, 0, 0);
    }
  };

  const int NT = K >> 6;
  stage(sA, sB, 0);
  __syncthreads();
  for (int t = 1; t < NT; ++t) {
    stage(dA, dB, t * 64);
    compute(sA, sB);
    __syncthreads();
    bf16* u;
    u = sA; sA = dA; dA = u;
    u = sB; sB = dB; dB = u;
  }
  compute(sA, sB);

  const int rb = row0 + wr * 32 + fg * 4;
  const int cb = col0 + wc * (NI * 16) + fr;
#pragma unroll
  for (int mi = 0; mi < 2; ++mi) {
#pragma unroll
    for (int ni = 0; ni < NI; ++ni) {
      const int cc = cb + ni * 16;
      const float bb = bias ? bias[cc] : 0.f;
#pragma unroll
      for (int r = 0; r < 4; ++r) {
        const int rr = rb + mi * 16 + r;
        float v = acc[mi][ni][r] + bb;
        if (res) v += res[(size_t)rr * Ncol + cc];
        if (GELU) v = 0.5f * v * (1.f + erff(v * 0.70710678118654752f));
        if (OUT_BF) Cb[(size_t)rr * Ncol + cc] = (bf16)v;
        else        Cf[(size_t)rr * Ncol + cc] = v;
      }
    }
  }
}

// ============================================================
// Guarded tail GEMM (reg-staged 64x128): small M.
// ============================================================
template <bool OUT_BF>
__global__ __launch_bounds__(256) void gemm_tail_kernel(
    const bf16* __restrict__ A, const bf16* __restrict__ WT,
    float* __restrict__ Cf, bf16* __restrict__ Cb,
    const float* __restrict__ bias, const float* __restrict__ resv,
    int Mr, int K, int Nc, int ldc, int resmode) {
  __shared__ __align__(16) bf16 As[64][40];
  __shared__ __align__(16) bf16 Bs[128][40];
  const int tid = threadIdx.x;
  const int lane = tid & 63, wid = tid >> 6;
  const int row0 = blockIdx.y * 64, col0 = blockIdx.x * 128;
  f32x4 acc[4][2] = {};
  const int am = tid >> 2, ako = (tid & 3) * 8;
  const int fr = lane & 15, fg = (lane >> 4) * 8;
  for (int k0 = 0; k0 < K; k0 += 32) {
    if (row0 + am < Mr)
      *(bf16x8*)&As[am][ako] = *(const bf16x8*)(A + (size_t)(row0 + am) * K + k0 + ako);
    else {
      bf16x8 z = {};
      *(bf16x8*)&As[am][ako] = z;
    }
#pragma unroll
    for (int it = 0; it < 2; ++it) {
      const int c = it * 256 + tid;
      const int n = c >> 2, ko = (c & 3) * 8;
      *(bf16x8*)&Bs[n][ko] = *(const bf16x8*)(WT + (size_t)(col0 + n) * K + k0 + ko);
    }
    __syncthreads();
    bf16x8 af[4], bfr[2];
#pragma unroll
    for (int mi = 0; mi < 4; ++mi) af[mi] = *(const bf16x8*)&As[mi * 16 + fr][fg];
#pragma unroll
    for (int ni = 0; ni < 2; ++ni) bfr[ni] = *(const bf16x8*)&Bs[wid * 32 + ni * 16 + fr][fg];
#pragma unroll
    for (int mi = 0; mi < 4; ++mi)
#pragma unroll
      for (int ni = 0; ni < 2; ++ni)
        acc[mi][ni] = __builtin_amdgcn_mfma_f32_16x16x32_bf16(af[mi], bfr[ni], acc[mi][ni], 0, 0, 0);
    __syncthreads();
  }
  const int r4 = (lane >> 4) * 4;
  const int cc0 = col0 + wid * 32 + (lane & 15);
#pragma unroll
  for (int mi = 0; mi < 4; ++mi) {
#pragma unroll
    for (int ni = 0; ni < 2; ++ni) {
      const int cc = cc0 + ni * 16;
      if (cc >= Nc) continue;
#pragma unroll
      for (int r = 0; r < 4; ++r) {
        const int rr = row0 + mi * 16 + r4 + r;
        if (rr >= Mr) continue;
        float v = acc[mi][ni][r];
        if (bias) v += bias[cc];
        if (resmode == 1) v += resv[(size_t)rr * ldc + cc];
        else if (resmode == 2) v += resv[cc];
        if (OUT_BF) Cb[(size_t)rr * ldc + cc] = (bf16)v;
        else        Cf[(size_t)rr * ldc + cc] = v;
      }
    }
  }
}

// ============================================================
// Block-diagonal MFMA attention, bf16 qkv input [B,N,3072].
// ============================================================
__global__ __launch_bounds__(256) void attn_kernel(
    const bf16* __restrict__ qkv, const int* __restrict__ ids,
    const float* __restrict__ qg, const float* __restrict__ qb,
    const float* __restrict__ kg, const float* __restrict__ kb,
    bf16* __restrict__ o) {
  const int h = blockIdx.x, img = blockIdx.y, b = blockIdx.z;
  const int tid = threadIdx.x, lane = tid & 63, wid = tid >> 6;
  __shared__ __align__(16) bf16 Qs[64][72];
  __shared__ __align__(16) bf16 Ks[64][72];
  __shared__ __align__(16) bf16 Vt[64][72];
  __shared__ __align__(16) bf16 Ps[64][72];
  __shared__ int wlo[4], whi[4];
  __shared__ int sLo, sHi;
  {
    const int want = (img < kM) ? img : -1;
    int lo = kN, hi = -1;
    for (int j = tid; j < kN; j += 256) {
      if (ids[b * kN + j] == want) { lo = min(lo, j); hi = max(hi, j); }
    }
#pragma unroll
    for (int off = 32; off; off >>= 1) {
      lo = min(lo, __shfl_xor(lo, off));
      hi = max(hi, __shfl_xor(hi, off));
    }
    if (lane == 0) { wlo[wid] = lo; whi[wid] = hi; }
    __syncthreads();
    if (tid == 0) {
      sLo = min(min(wlo[0], wlo[1]), min(wlo[2], wlo[3]));
      sHi = max(max(whi[0], whi[1]), max(whi[2], whi[3]));
    }
    __syncthreads();
  }
  if (sHi < 0) return;
  const int start = sLo, T = sHi - sLo + 1;
  if (img == kM) {
    for (int j = start + wid; j <= sHi; j += 4)
      o[((size_t)(b * kN + j)) * kD + h * kDH + lane] = (bf16)0.f;
    return;
  }
  // stage: chunk = 8 bf16; row = ch>>3 (8 lanes per row)
#pragma unroll
  for (int it = 0; it < 2; ++it) {
    const int ch = it * 256 + tid;
    const int r = ch >> 3, d0 = (ch & 7) * 8;
    if (r < T) {
      const bf16* base = qkv + ((size_t)(b * kN + start + r)) * 3072 + h * kDH + d0;
      const bf16x8 qv = *(const bf16x8*)(base);
      const bf16x8 kv = *(const bf16x8*)(base + 1024);
      const bf16x8 vv = *(const bf16x8*)(base + 2048);
      float qf[8], kf[8];
      float sq = 0.f, sq2 = 0.f, sk = 0.f, sk2 = 0.f;
#pragma unroll
      for (int e = 0; e < 8; ++e) {
        qf[e] = (float)qv[e]; kf[e] = (float)kv[e];
        sq += qf[e]; sq2 += qf[e] * qf[e];
        sk += kf[e]; sk2 += kf[e] * kf[e];
      }
#pragma unroll
      for (int off = 1; off < 8; off <<= 1) {
        sq += __shfl_xor(sq, off); sq2 += __shfl_xor(sq2, off);
        sk += __shfl_xor(sk, off); sk2 += __shfl_xor(sk2, off);
      }
      const float qm = sq * (1.f / 64);
      const float qr = rsqrtf(sq2 * (1.f / 64) - qm * qm + 1e-5f);
      const float km = sk * (1.f / 64);
      const float kr = rsqrtf(sk2 * (1.f / 64) - km * km + 1e-5f);
      bf16x8 qw, kw;
#pragma unroll
      for (int e = 0; e < 8; ++e) {
        qw[e] = (bf16)((qf[e] - qm) * qr * qg[d0 + e] + qb[d0 + e]);
        kw[e] = (bf16)((kf[e] - km) * kr * kg[d0 + e] + kb[d0 + e]);
      }
      *(bf16x8*)&Qs[r][d0] = qw;
      *(bf16x8*)&Ks[r][d0] = kw;
#pragma unroll
      for (int e = 0; e < 8; ++e) Vt[d0 + e][r] = vv[e];
    } else {
      const bf16x8 z = {};
      *(bf16x8*)&Qs[r][d0] = z;
      *(bf16x8*)&Ks[r][d0] = z;
#pragma unroll
      for (int e = 0; e < 8; ++e) Vt[d0 + e][r] = (bf16)0.f;
    }
  }
  __syncthreads();
  const int fr = lane & 15, fg = lane >> 4;
  const int r0 = wid * 16;
  f32x4 sacc[4] = {};
#pragma unroll
  for (int k0 = 0; k0 < 64; k0 += 32) {
    const bf16x8 aq = *(const bf16x8*)&Qs[r0 + fr][k0 + fg * 8];
#pragma unroll
    for (int ni = 0; ni < 4; ++ni) {
      const bf16x8 bk = *(const bf16x8*)&Ks[ni * 16 + fr][k0 + fg * 8];
      sacc[ni] = __builtin_amdgcn_mfma_f32_16x16x32_bf16(aq, bk, sacc[ni], 0, 0, 0);
    }
  }
  float inv[4];
#pragma unroll
  for (int r = 0; r < 4; ++r) {
    float mx = kNegInf;
#pragma unroll
    for (int ni = 0; ni < 4; ++ni) {
      const float s = (ni * 16 + fr < T) ? sacc[ni][r] * kScale : kNegInf;
      sacc[ni][r] = s;
      mx = fmaxf(mx, s);
    }
#pragma unroll
    for (int off = 1; off < 16; off <<= 1) mx = fmaxf(mx, __shfl_xor(mx, off));
    float sum = 0.f;
#pragma unroll
    for (int ni = 0; ni < 4; ++ni) {
      const float p = __expf(sacc[ni][r] - mx);
      sacc[ni][r] = p;
      sum += p;
    }
#pragma unroll
    for (int off = 1; off < 16; off <<= 1) sum += __shfl_xor(sum, off);
    inv[r] = 1.f / sum;
  }
#pragma unroll
  for (int ni = 0; ni < 4; ++ni)
#pragma unroll
    for (int r = 0; r < 4; ++r)
      Ps[r0 + fg * 4 + r][ni * 16 + fr] = (bf16)sacc[ni][r];
  f32x4 oacc[4] = {};
#pragma unroll
  for (int k0 = 0; k0 < 64; k0 += 32) {
    const bf16x8 ap = *(const bf16x8*)&Ps[r0 + fr][k0 + fg * 8];
#pragma unroll
    for (int ni = 0; ni < 4; ++ni) {
      const bf16x8 bv = *(const bf16x8*)&Vt[ni * 16 + fr][k0 + fg * 8];
      oacc[ni] = __builtin_amdgcn_mfma_f32_16x16x32_bf16(ap, bv, oacc[ni], 0, 0, 0);
    }
  }
#pragma unroll
  for (int r = 0; r < 4; ++r) {
    const int i = r0 + fg * 4 + r;
    if (i < T) {
      const size_t orow = ((size_t)(b * kN + start + i)) * kD + h * kDH;
      const float iv = inv[r];
#pragma unroll
      for (int ni = 0; ni < 4; ++ni)
        o[orow + ni * 16 + fr] = (bf16)(oacc[ni][r] * iv);
    }
  }
}

// ============================================================
// Attention pooling: one wave per (b,m,h). kv layout [B,N,2048]. bf16 out.
// ============================================================
__global__ __launch_bounds__(64) void poolattn_kernel(
    const float* __restrict__ qp, const float* __restrict__ kv,
    const int* __restrict__ ids, bf16* __restrict__ o) {
  const int blk = blockIdx.x;
  const int h = blk % kH;
  const int bm = blk / kH;
  const int m = bm % kM, b = bm / kM;
  const int lane = threadIdx.x;
  __shared__ float sc[kN];
  __shared__ float qs[kDH];
  qs[lane] = qp[h * kDH + lane];
  __syncthreads();
  float mymax = kNegInf;
  int jmn = kN, jmx = -1;
  for (int j = lane; j < kN; j += 64) {
    const int idj = ids[b * kN + j];
    float s;
    if (idj == m) {
      const float* krow = kv + ((size_t)(b * kN + j)) * (2 * kD) + h * kDH;
      float dot = 0.f;
#pragma unroll
      for (int d = 0; d < kDH; ++d) dot += qs[d] * krow[d];
      s = dot * kScale;
      jmn = min(jmn, j); jmx = max(jmx, j);
    } else {
      s = kNegInf;
    }
    sc[j] = s;
    mymax = fmaxf(mymax, s);
  }
#pragma unroll
  for (int off = 32; off; off >>= 1) {
    mymax = fmaxf(mymax, __shfl_xor(mymax, off));
    jmn = min(jmn, __shfl_xor(jmn, off));
    jmx = max(jmx, __shfl_xor(jmx, off));
  }
  const int jlo = jmn, jhi = jmx + 1;
  float mysum = 0.f;
  for (int j = jlo + lane; j < jhi; j += 64) {
    const float p = __expf(sc[j] - mymax);
    sc[j] = p;
    mysum += p;
  }
#pragma unroll
  for (int off = 32; off; off >>= 1) mysum += __shfl_xor(mysum, off);
  const float inv = 1.f / mysum;
  __syncthreads();
  float acc = 0.f;
  const float* vptr = kv + ((size_t)(b * kN + jlo)) * (2 * kD) + kD + h * kDH + lane;
  for (int j = jlo; j < jhi; ++j, vptr += 2 * kD) acc += sc[j] * vptr[0];
  o[((size_t)(b * kM + m)) * kD + h * kDH + lane] = (bf16)(acc * inv);
}

// ============================================================
// driver
// ============================================================
extern "C" void kernel_launch(void* const* d_in, const int* in_sizes, int n_in,
                              void* d_out, int out_size, void* d_ws, size_t ws_size,
                              hipStream_t stream) {
  const float* patches  = (const float*)d_in[0];
  const float* pe_ln1_g = (const float*)d_in[1];
  const float* pe_ln1_b = (const float*)d_in[2];
  const float* W_pe     = (const float*)d_in[3];
  const float* b_pe     = (const float*)d_in[4];
  const float* pe_ln2_g = (const float*)d_in[5];
  const float* pe_ln2_b = (const float*)d_in[6];
  const float* pos_h    = (const float*)d_in[7];
  const float* pos_w    = (const float*)d_in[8];
  const float* ln1_g    = (const float*)d_in[9];
  const float* ln1_b    = (const float*)d_in[10];
  const float* qn_g     = (const float*)d_in[11];
  const float* qn_b     = (const float*)d_in[12];
  const float* kn_g     = (const float*)d_in[13];
  const float* kn_b     = (const float*)d_in[14];
  const float* Wq       = (const float*)d_in[15];
  const float* Wkv      = (const float*)d_in[16];
  const float* Wo       = (const float*)d_in[17];
  const float* ln2_g    = (const float*)d_in[18];
  const float* ln2_b    = (const float*)d_in[19];
  const float* W1       = (const float*)d_in[20];
  const float* b1       = (const float*)d_in[21];
  const float* W2       = (const float*)d_in[22];
  const float* b2       = (const float*)d_in[23];
  const float* fin_g    = (const float*)d_in[24];
  const float* fin_b    = (const float*)d_in[25];
  const float* pool_q   = (const float*)d_in[26];
  const float* pl_ln_g  = (const float*)d_in[27];
  const float* pl_ln_b  = (const float*)d_in[28];
  const float* pl_qn_g  = (const float*)d_in[29];
  const float* pl_qn_b  = (const float*)d_in[30];
  const float* pl_kn_g  = (const float*)d_in[31];
  const float* pl_kn_b  = (const float*)d_in[32];
  const float* pl_Wq    = (const float*)d_in[33];
  const float* pl_Wkv   = (const float*)d_in[34];
  const float* pl_Wo    = (const float*)d_in[35];
  const float* head_g   = (const float*)d_in[36];
  const float* head_b   = (const float*)d_in[37];
  const float* W_head   = (const float*)d_in[38];
  const float* b_head   = (const float*)d_in[39];
  const int* h_idx      = (const int*)d_in[40];
  const int* w_idx      = (const int*)d_in[41];
  const int* image_ids  = (const int*)d_in[42];
  float* out = (float*)d_out;

  // ---- workspace layout ----
  const size_t SZ = (size_t)kB * kN * kD;        // 2,621,440
  char* p = (char*)d_ws;
  float* x    = (float*)p;           p += SZ * 4;                 // 10.5 MB
  bf16*  xnb  = (bf16*)p;            p += SZ * 2;                 // 5.2 MB
  char*  scratch = p;                p += 32u * 1024 * 1024;      // 32 MB
  char*  smalls = p;                 p += 1u * 1024 * 1024;       // 1 MB
  bf16*  wtbuf = (bf16*)p;                                        // 112 MB
  // scratch overlays
  bf16*  qkvbb = (bf16*)scratch;                         // [BN][3072] bf16
  bf16*  attno = (bf16*)(scratch + 16u * 1024 * 1024);   // [BN][1024] bf16
  bf16*  plnb  = (bf16*)scratch;                         // [BN][3072] bf16 (embed)
  float* emb   = (float*)(scratch + 16u * 1024 * 1024);  // [BN][1024] f32 (embed)
  bf16*  h1b   = (bf16*)scratch;                         // [BN][2048] bf16 (mlp)
  float* kvpool = (float*)scratch;                       // [BN][2048] f32 (pool)
  float* qpool   = (float*)smalls;                                    // 1024 f32
  bf16*  opoolb  = (bf16*)(smalls + 8192);                            // 72*1024 bf16
  float* pooled  = (float*)(smalls + 8192 + 163840);                  // 72*1024 f32
  bf16*  pooledn = (bf16*)(smalls + 8192 + 163840 + 327680);          // 72*1024 bf16

  const int BN = kB * kN;          // 2560 rows
  const int nbyM = BN / 64;        // 40 row-blocks

  // ---- all weight transposes, one launch, off the critical path ----
  wt_all_kernel<<<dim3(3072, 35), 256, 0, stream>>>(
      W_pe, Wq, Wkv, Wo, W1, W2, pl_Wq, pl_Wkv, pl_Wo, W_head, wtbuf);

  // ---- patch embedding ----
  ln_kernel<bf16><<<BN, 256, 0, stream>>>(patches, plnb, pe_ln1_g, pe_ln1_b, kPD);
  gemm64_kernel<2, false, false><<<(kD / 64) * nbyM, 256, 0, stream>>>(
      plnb, wtbuf + kOffPe, emb, nullptr, b_pe, nullptr, kPD, kD, kD / 64);
  ln_pos_kernel<<<BN, 256, 0, stream>>>(emb, x, pe_ln2_g, pe_ln2_b, pos_h, pos_w, h_idx, w_idx);

  // ---- transformer layers ----
  for (int l = 0; l < kDepth; ++l) {
    const bf16* lw = wtbuf + kLayer0 + (size_t)l * kLayerSz;
    ln_kernel<bf16><<<BN, 256, 0, stream>>>(x, xnb, ln1_g + (size_t)l * kD, ln1_b + (size_t)l * kD, kD);
    gemm64_kernel<4, true, false><<<(3 * kD / 128) * nbyM, 256, 0, stream>>>(
        xnb, lw, nullptr, qkvbb, nullptr, nullptr, kD, 3 * kD, 3 * kD / 128);
    attn_kernel<<<dim3(kH, kM + 1, kB), 256, 0, stream>>>(
        qkvbb, image_ids,
        qn_g + (size_t)l * kDH, qn_b + (size_t)l * kDH,
        kn_g + (size_t)l * kDH, kn_b + (size_t)l * kDH, attno);
    gemm64_kernel<2, false, false><<<(kD / 64) * nbyM, 256, 0, stream>>>(
        attno, lw + 3 * kMEG, x, nullptr, nullptr, x, kD, kD, kD / 64);
    ln_kernel<bf16><<<BN, 256, 0, stream>>>(x, xnb, ln2_g + (size_t)l * kD, ln2_b + (size_t)l * kD, kD);
    gemm64_kernel<4, true, true><<<(kMLP / 128) * nbyM, 256, 0, stream>>>(
        xnb, lw + 4 * kMEG, nullptr, h1b, b1 + (size_t)l * kMLP, nullptr, kD, kMLP, kMLP / 128);
    gemm64_kernel<2, false, false><<<(kD / 64) * nbyM, 256, 0, stream>>>(
        h1b, lw + 6 * kMEG, x, nullptr, b2 + (size_t)l * kD, x, kMLP, kD, kD / 64);
  }

  // ---- final LN (context for pooling) ----
  ln_kernel<bf16><<<BN, 256, 0, stream>>>(x, xnb, fin_g, fin_b, kD);

  // ---- attention pooling ----
  poolq_kernel<<<kH, 256, 0, stream>>>(
      pool_q, pl_ln_g, pl_ln_b, wtbuf + kOffPlWq, pl_qn_g, pl_qn_b, qpool);
  gemm64_kernel<4, false, false><<<(2 * kD / 128) * nbyM, 256, 0, stream>>>(
      xnb, wtbuf + kOffPlWkv, kvpool, nullptr, nullptr, nullptr, kD, 2 * kD, 2 * kD / 128);
  headln_kernel<<<BN * kH, 64, 0, stream>>>(kvpool, 2 * kD, pl_kn_g, pl_kn_b);
  poolattn_kernel<<<kB * kM * kH, 64, 0, stream>>>(qpool, kvpool, image_ids, opoolb);
  gemm_tail_kernel<false><<<dim3(8, 2), 256, 0, stream>>>(
      opoolb, wtbuf + kOffPlWo, pooled, nullptr, nullptr, pool_q, kB * kM, kD, kD, kD, 2);

  // ---- classifier head ----
  ln_kernel<bf16><<<kB * kM, 256, 0, stream>>>(pooled, pooledn, head_g, head_b, kD);
  gemm_tail_kernel<false><<<dim3(8, 2), 256, 0, stream>>>(
      pooledn, wtbuf + kOffHead, out, nullptr, b_head, nullptr, kB * kM, kD, kNC, kNC, 0);
}

// Round 8
// 971.047 us; speedup vs baseline: 8.4857x; 1.0485x over previous
//
#include <hip/hip_runtime.h>
#include <cmath>

// ---- model constants ----
constexpr int kB = 4, kN = 640, kD = 1024, kH = 16, kDH = 64;
constexpr int kDepth = 6, kMLP = 2048, kPD = 3072, kNC = 1000, kM = 18;
constexpr float kScale = 0.125f;        // DH^-0.5
constexpr float kNegInf = -3.4028235e38f;

typedef __bf16 bf16;
typedef __attribute__((ext_vector_type(8))) __bf16 bf16x8;
typedef __attribute__((ext_vector_type(4))) __bf16 bf16x4;
typedef __attribute__((ext_vector_type(4))) float f32x4;

#define AS1 __attribute__((address_space(1)))
#define AS3 __attribute__((address_space(3)))

__device__ __forceinline__ void gload16(const void* g, void* l) {
  __builtin_amdgcn_global_load_lds((AS1 void*)g, (AS3 void*)l, 16, 0, 0);
}

// ---- wtbuf element offsets (bf16 elems) ----
constexpr size_t kMEG = 1048576;
constexpr size_t kOffPe = 0;                              // 3072x1024
constexpr size_t kLayer0 = 3 * kMEG;
constexpr size_t kLayerSz = 8 * kMEG;                     // WqT 1M | WkvT 2M | WoT 1M | W1T 2M | W2T 2M
constexpr size_t kOffPool = kLayer0 + 6 * kLayerSz;
constexpr size_t kOffPlWq = kOffPool;
constexpr size_t kOffPlWkv = kOffPool + 1 * kMEG;
constexpr size_t kOffPlWo = kOffPool + 3 * kMEG;
constexpr size_t kOffHead = kOffPool + 4 * kMEG;

// ============================================================
// Batched weight transpose, 64x64 tiles: f32 W[K][Nc] -> bf16 WT[Np][K].
// float4 reads, LDS [64][65], bf16x8 writes. grid = (768, 35).
// ============================================================
__global__ __launch_bounds__(256) void wt_all_kernel(
    const float* __restrict__ pe, const float* __restrict__ wq,
    const float* __restrict__ wkv, const float* __restrict__ wo,
    const float* __restrict__ w1, const float* __restrict__ w2,
    const float* __restrict__ plq, const float* __restrict__ plkv,
    const float* __restrict__ plo, const float* __restrict__ whead,
    bf16* __restrict__ WTB) {
  const int j = blockIdx.y;
  const float* W;
  size_t doff;
  int K, Nc, Np;
  if (j == 0) {
    W = pe; K = 3072; Nc = 1024; Np = 1024; doff = kOffPe;
  } else if (j < 31) {
    const int l = (j - 1) / 5, w = (j - 1) % 5;
    const size_t lbase = kLayer0 + (size_t)l * kLayerSz;
    switch (w) {
      case 0:  W = wq  + (size_t)l * kMEG;     K = 1024; Nc = 1024; doff = lbase;            break;
      case 1:  W = wkv + (size_t)l * 2 * kMEG; K = 1024; Nc = 2048; doff = lbase + kMEG;     break;
      case 2:  W = wo  + (size_t)l * kMEG;     K = 1024; Nc = 1024; doff = lbase + 3 * kMEG; break;
      case 3:  W = w1  + (size_t)l * 2 * kMEG; K = 1024; Nc = 2048; doff = lbase + 4 * kMEG; break;
      default: W = w2  + (size_t)l * 2 * kMEG; K = 2048; Nc = 1024; doff = lbase + 6 * kMEG; break;
    }
    Np = Nc;
  } else if (j == 31) { W = plq;  K = 1024; Nc = 1024; Np = 1024; doff = kOffPlWq; }
  else if (j == 32)   { W = plkv; K = 1024; Nc = 2048; Np = 2048; doff = kOffPlWkv; }
  else if (j == 33)   { W = plo;  K = 1024; Nc = 1024; Np = 1024; doff = kOffPlWo; }
  else                { W = whead; K = 1024; Nc = 1000; Np = 1024; doff = kOffHead; }
  const int nbx = Np >> 6;
  const int ntiles = nbx * (K >> 6);
  const int tile = blockIdx.x;
  if (tile >= ntiles) return;
  const int n0 = (tile % nbx) * 64, k0 = (tile / nbx) * 64;
  bf16* WT = WTB + doff;
  __shared__ float s[64][65];
  const int tid = threadIdx.x;
  if (n0 + 64 <= Nc) {
#pragma unroll
    for (int i = 0; i < 4; ++i) {
      const int c = i * 256 + tid;
      const int r = c >> 4, cq = c & 15;
      const float4 v = *(const float4*)(W + (size_t)(k0 + r) * Nc + n0 + cq * 4);
      s[r][cq * 4 + 0] = v.x; s[r][cq * 4 + 1] = v.y;
      s[r][cq * 4 + 2] = v.z; s[r][cq * 4 + 3] = v.w;
    }
  } else {
#pragma unroll
    for (int i = 0; i < 4; ++i) {
      const int c = i * 256 + tid;
      const int r = c >> 4, cq = c & 15;
#pragma unroll
      for (int e = 0; e < 4; ++e) {
        const int n = n0 + cq * 4 + e;
        s[r][cq * 4 + e] = (n < Nc) ? W[(size_t)(k0 + r) * Nc + n] : 0.f;
      }
    }
  }
  __syncthreads();
#pragma unroll
  for (int i = 0; i < 2; ++i) {
    const int c = i * 256 + tid;
    const int n = c >> 3, kq = c & 7;
    bf16x8 w;
#pragma unroll
    for (int e = 0; e < 8; ++e) w[e] = (bf16)s[kq * 8 + e][n];
    *(bf16x8*)(WT + (size_t)(n0 + n) * K + k0 + kq * 8) = w;
  }
}

// ============================================================
// LayerNorm over last dim K (K%1024==0), float4 loads.
// ============================================================
template <typename OT>
__global__ __launch_bounds__(256) void ln_kernel(
    const float* __restrict__ in, OT* __restrict__ out,
    const float* __restrict__ g, const float* __restrict__ b, int K) {
  const int row = blockIdx.x;
  const float* x = in + (size_t)row * K;
  OT* o = out + (size_t)row * K;
  const int K4 = K >> 2;
  float s = 0.f, s2 = 0.f;
  for (int c = threadIdx.x; c < K4; c += 256) {
    const float4 v = ((const float4*)x)[c];
    s += v.x + v.y + v.z + v.w;
    s2 += v.x * v.x + v.y * v.y + v.z * v.z + v.w * v.w;
  }
#pragma unroll
  for (int off = 32; off; off >>= 1) { s += __shfl_down(s, off); s2 += __shfl_down(s2, off); }
  __shared__ float ls[4], ls2[4];
  __shared__ float sm, sr;
  const int wid = threadIdx.x >> 6, lane = threadIdx.x & 63;
  if (lane == 0) { ls[wid] = s; ls2[wid] = s2; }
  __syncthreads();
  if (threadIdx.x == 0) {
    float a = ls[0] + ls[1] + ls[2] + ls[3];
    float a2 = ls2[0] + ls2[1] + ls2[2] + ls2[3];
    float mean = a / K;
    float var = a2 / K - mean * mean;
    sm = mean; sr = rsqrtf(var + 1e-5f);
  }
  __syncthreads();
  const float mean = sm, r = sr;
  for (int c = threadIdx.x; c < K4; c += 256) {
    const float4 v = ((const float4*)x)[c];
    const float4 gv = ((const float4*)g)[c];
    const float4 bv = ((const float4*)b)[c];
    const int d = c * 4;
    o[d + 0] = (OT)((v.x - mean) * r * gv.x + bv.x);
    o[d + 1] = (OT)((v.y - mean) * r * gv.y + bv.y);
    o[d + 2] = (OT)((v.z - mean) * r * gv.z + bv.z);
    o[d + 3] = (OT)((v.w - mean) * r * gv.w + bv.w);
  }
}

// ============================================================
// Fused pe_ln2 + factorized pos-embed add (f32 out).
// ============================================================
__global__ __launch_bounds__(256) void ln_pos_kernel(
    const float* __restrict__ in, float* __restrict__ out,
    const float* __restrict__ g, const float* __restrict__ b,
    const float* __restrict__ ph, const float* __restrict__ pw,
    const int* __restrict__ hi, const int* __restrict__ wi) {
  const int row = blockIdx.x;
  const float* x = in + (size_t)row * kD;
  float* o = out + (size_t)row * kD;
  const int c = threadIdx.x;
  const float4 v = ((const float4*)x)[c];
  float s = v.x + v.y + v.z + v.w;
  float s2 = v.x * v.x + v.y * v.y + v.z * v.z + v.w * v.w;
#pragma unroll
  for (int off = 32; off; off >>= 1) { s += __shfl_down(s, off); s2 += __shfl_down(s2, off); }
  __shared__ float ls[4], ls2[4];
  __shared__ float sm, sr;
  const int wid = threadIdx.x >> 6, lane = threadIdx.x & 63;
  if (lane == 0) { ls[wid] = s; ls2[wid] = s2; }
  __syncthreads();
  if (threadIdx.x == 0) {
    float a = ls[0] + ls[1] + ls[2] + ls[3];
    float a2 = ls2[0] + ls2[1] + ls2[2] + ls2[3];
    float mean = a / kD;
    float var = a2 / kD - mean * mean;
    sm = mean; sr = rsqrtf(var + 1e-5f);
  }
  __syncthreads();
  const float mean = sm, r = sr;
  const float4* phr = (const float4*)(ph + (size_t)hi[row] * kD);
  const float4* pwr = (const float4*)(pw + (size_t)wi[row] * kD);
  const float4 gv = ((const float4*)g)[c];
  const float4 bv = ((const float4*)b)[c];
  const float4 hv = phr[c], wv = pwr[c];
  float4 ov;
  ov.x = (v.x - mean) * r * gv.x + bv.x + hv.x + wv.x;
  ov.y = (v.y - mean) * r * gv.y + bv.y + hv.y + wv.y;
  ov.z = (v.z - mean) * r * gv.z + bv.z + hv.z + wv.z;
  ov.w = (v.w - mean) * r * gv.w + bv.w + hv.w + wv.w;
  ((float4*)o)[c] = ov;
}

// ============================================================
// Fused pool-query chain: LN(pool_q) -> @pl_Wq^T(bf16) -> head LN.
// ============================================================
__global__ __launch_bounds__(256) void poolq_kernel(
    const float* __restrict__ pq, const float* __restrict__ lg,
    const float* __restrict__ lb, const bf16* __restrict__ WqT,
    const float* __restrict__ qg, const float* __restrict__ qb,
    float* __restrict__ qpool) {
  const int h = blockIdx.x, tid = threadIdx.x;
  __shared__ float qs[1024];
  __shared__ float red[256];
  __shared__ float ls[4], ls2[4];
  __shared__ float sm, sr;
  const float4 v = ((const float4*)pq)[tid];
  float s = v.x + v.y + v.z + v.w;
  float s2 = v.x * v.x + v.y * v.y + v.z * v.z + v.w * v.w;
#pragma unroll
  for (int off = 32; off; off >>= 1) { s += __shfl_down(s, off); s2 += __shfl_down(s2, off); }
  const int wid = tid >> 6, lane = tid & 63;
  if (lane == 0) { ls[wid] = s; ls2[wid] = s2; }
  __syncthreads();
  if (tid == 0) {
    float a = ls[0] + ls[1] + ls[2] + ls[3];
    float a2 = ls2[0] + ls2[1] + ls2[2] + ls2[3];
    float mean = a / kD;
    sm = mean; sr = rsqrtf(a2 / kD - mean * mean + 1e-5f);
  }
  __syncthreads();
  {
    const float mean = sm, r = sr;
    const float4 gv = ((const float4*)lg)[tid];
    const float4 bv = ((const float4*)lb)[tid];
    qs[tid * 4 + 0] = (v.x - mean) * r * gv.x + bv.x;
    qs[tid * 4 + 1] = (v.y - mean) * r * gv.y + bv.y;
    qs[tid * 4 + 2] = (v.z - mean) * r * gv.z + bv.z;
    qs[tid * 4 + 3] = (v.w - mean) * r * gv.w + bv.w;
  }
  __syncthreads();
  const int d = tid & 63, qq = tid >> 6;
  const bf16* wrow = WqT + (size_t)(h * 64 + d) * 1024 + qq * 256;
  const float* qp = qs + qq * 256;
  float part = 0.f;
  for (int k = 0; k < 256; k += 8) {
    const bf16x8 w8 = *(const bf16x8*)(wrow + k);
#pragma unroll
    for (int e = 0; e < 8; ++e) part += qp[k + e] * (float)w8[e];
  }
  red[tid] = part;
  __syncthreads();
  if (tid < 64) {
    const float dot = red[tid] + red[tid + 64] + red[tid + 128] + red[tid + 192];
    float hs = dot, hs2 = dot * dot;
#pragma unroll
    for (int off = 32; off; off >>= 1) { hs += __shfl_xor(hs, off); hs2 += __shfl_xor(hs2, off); }
    const float m = hs * (1.f / kDH);
    const float r = rsqrtf(hs2 * (1.f / kDH) - m * m + 1e-5f);
    qpool[h * 64 + tid] = (dot - m) * r * qg[tid] + qb[tid];
  }
}

// ============================================================
// 64x(NI*32) MFMA GEMM, BK=64, dbuf LDS + global_load_lds prefetch,
// T2 XOR-swizzle, XCD-chunked blockIdx swizzle. HLN: fused per-head
// LayerNorm on the k-half columns (pool kv; requires NI=4 so each
// wave holds a full 64-col head per row).
// ============================================================
template <int NI, bool OUT_BF, bool GELU, bool HLN>
__global__ __launch_bounds__(256) void gemm64_kernel(
    const bf16* __restrict__ A, const bf16* __restrict__ WT,
    float* __restrict__ Cf, bf16* __restrict__ Cb,
    const float* __restrict__ bias, const float* __restrict__ res,
    const float* __restrict__ hg, const float* __restrict__ hb,
    int K, int Ncol, int nbx) {
  constexpr int BN = NI * 32;
  __shared__ __align__(16) bf16 As[2][64 * 64];
  __shared__ __align__(16) bf16 Bs[2][BN * 64];
  const int tid = threadIdx.x, lane = tid & 63, wid = tid >> 6;
  const int wr = wid >> 1, wc = wid & 1;
  const int cpx = gridDim.x >> 3;
  const int swz = (blockIdx.x & 7) * cpx + (blockIdx.x >> 3);
  const int row0 = (swz / nbx) * 64, col0 = (swz % nbx) * BN;
  const int fr = lane & 15, fg = lane >> 4;
  f32x4 acc[2][NI] = {};
  bf16* sA = As[0]; bf16* sB = Bs[0];
  bf16* dA = As[1]; bf16* dB = Bs[1];

  auto stage = [&](bf16* tA, bf16* tB, int kt) {
#pragma unroll
    for (int i = 0; i < 2; ++i) {
      const int c = i * 256 + tid;
      const int r = c >> 3, ci = c & 7;
      gload16(A + (size_t)(row0 + r) * K + kt + ((ci ^ (r & 7)) * 8),
              tA + (i * 256 + wid * 64) * 8);
    }
#pragma unroll
    for (int i = 0; i < NI; ++i) {
      const int c = i * 256 + tid;
      const int r = c >> 3, ci = c & 7;
      gload16(WT + (size_t)(col0 + r) * K + kt + ((ci ^ (r & 7)) * 8),
              tB + (i * 256 + wid * 64) * 8);
    }
  };
  auto compute = [&](const bf16* tA, const bf16* tB) {
#pragma unroll
    for (int kk = 0; kk < 2; ++kk) {
      bf16x8 af[2], bfr[NI];
#pragma unroll
      for (int mi = 0; mi < 2; ++mi) {
        const int r = wr * 32 + mi * 16 + fr;
        af[mi] = *(const bf16x8*)(tA + r * 64 + (((kk * 4 + fg) ^ (r & 7)) * 8));
      }
#pragma unroll
      for (int ni = 0; ni < NI; ++ni) {
        const int r = wc * (NI * 16) + ni * 16 + fr;
        bfr[ni] = *(const bf16x8*)(tB + r * 64 + (((kk * 4 + fg) ^ (r & 7)) * 8));
      }
#pragma unroll
      for (int mi = 0; mi < 2; ++mi)
#pragma unroll
        for (int ni = 0; ni < NI; ++ni)
          acc[mi][ni] = __builtin_amdgcn_mfma_f32_16x16x32_bf16(af[mi], bfr[ni], acc[mi][ni], 0, 0, 0);
    }
  };

  const int NT = K >> 6;
  stage(sA, sB, 0);
  __syncthreads();
  for (int t = 1; t < NT; ++t) {
    stage(dA, dB, t * 64);
    compute(sA, sB);
    __syncthreads();
    bf16* u;
    u = sA; sA = dA; dA = u;
    u = sB; sB = dB; dB = u;
  }
  compute(sA, sB);

  const int rb = row0 + wr * 32 + fg * 4;
  const int cb = col0 + wc * (NI * 16) + fr;
  // optional fused head-LN stats (per (mi,r) row over the wave's 64 cols)
  float hm[2][4], hr[2][4];
  if (HLN) {
#pragma unroll
    for (int mi = 0; mi < 2; ++mi)
#pragma unroll
      for (int r = 0; r < 4; ++r) {
        float s = 0.f, s2 = 0.f;
#pragma unroll
        for (int ni = 0; ni < NI; ++ni) {
          const float v = acc[mi][ni][r];
          s += v; s2 += v * v;
        }
#pragma unroll
        for (int off = 1; off < 16; off <<= 1) {
          s += __shfl_xor(s, off); s2 += __shfl_xor(s2, off);
        }
        const float m = s * (1.f / kDH);
        hm[mi][r] = m;
        hr[mi][r] = rsqrtf(s2 * (1.f / kDH) - m * m + 1e-5f);
      }
  }
  const bool kHalf = HLN && (cb < kD);
#pragma unroll
  for (int mi = 0; mi < 2; ++mi) {
#pragma unroll
    for (int ni = 0; ni < NI; ++ni) {
      const int cc = cb + ni * 16;
      const float bb = bias ? bias[cc] : 0.f;
      const float hgv = HLN ? hg[ni * 16 + fr] : 0.f;
      const float hbv = HLN ? hb[ni * 16 + fr] : 0.f;
#pragma unroll
      for (int r = 0; r < 4; ++r) {
        const int rr = rb + mi * 16 + r;
        float v = acc[mi][ni][r] + bb;
        if (res) v += res[(size_t)rr * Ncol + cc];
        if (GELU) v = 0.5f * v * (1.f + erff(v * 0.70710678118654752f));
        if (HLN && kHalf) v = (v - hm[mi][r]) * hr[mi][r] * hgv + hbv;
        if (OUT_BF) Cb[(size_t)rr * Ncol + cc] = (bf16)v;
        else        Cf[(size_t)rr * Ncol + cc] = v;
      }
    }
  }
}

// ============================================================
// Guarded tail GEMM (reg-staged 64x128): small M.
// ============================================================
template <bool OUT_BF>
__global__ __launch_bounds__(256) void gemm_tail_kernel(
    const bf16* __restrict__ A, const bf16* __restrict__ WT,
    float* __restrict__ Cf, bf16* __restrict__ Cb,
    const float* __restrict__ bias, const float* __restrict__ resv,
    int Mr, int K, int Nc, int ldc, int resmode) {
  __shared__ __align__(16) bf16 As[64][40];
  __shared__ __align__(16) bf16 Bs[128][40];
  const int tid = threadIdx.x;
  const int lane = tid & 63, wid = tid >> 6;
  const int row0 = blockIdx.y * 64, col0 = blockIdx.x * 128;
  f32x4 acc[4][2] = {};
  const int am = tid >> 2, ako = (tid & 3) * 8;
  const int fr = lane & 15, fg = (lane >> 4) * 8;
  for (int k0 = 0; k0 < K; k0 += 32) {
    if (row0 + am < Mr)
      *(bf16x8*)&As[am][ako] = *(const bf16x8*)(A + (size_t)(row0 + am) * K + k0 + ako);
    else {
      bf16x8 z = {};
      *(bf16x8*)&As[am][ako] = z;
    }
#pragma unroll
    for (int it = 0; it < 2; ++it) {
      const int c = it * 256 + tid;
      const int n = c >> 2, ko = (c & 3) * 8;
      *(bf16x8*)&Bs[n][ko] = *(const bf16x8*)(WT + (size_t)(col0 + n) * K + k0 + ko);
    }
    __syncthreads();
    bf16x8 af[4], bfr[2];
#pragma unroll
    for (int mi = 0; mi < 4; ++mi) af[mi] = *(const bf16x8*)&As[mi * 16 + fr][fg];
#pragma unroll
    for (int ni = 0; ni < 2; ++ni) bfr[ni] = *(const bf16x8*)&Bs[wid * 32 + ni * 16 + fr][fg];
#pragma unroll
    for (int mi = 0; mi < 4; ++mi)
#pragma unroll
      for (int ni = 0; ni < 2; ++ni)
        acc[mi][ni] = __builtin_amdgcn_mfma_f32_16x16x32_bf16(af[mi], bfr[ni], acc[mi][ni], 0, 0, 0);
    __syncthreads();
  }
  const int r4 = (lane >> 4) * 4;
  const int cc0 = col0 + wid * 32 + (lane & 15);
#pragma unroll
  for (int mi = 0; mi < 4; ++mi) {
#pragma unroll
    for (int ni = 0; ni < 2; ++ni) {
      const int cc = cc0 + ni * 16;
      if (cc >= Nc) continue;
#pragma unroll
      for (int r = 0; r < 4; ++r) {
        const int rr = row0 + mi * 16 + r4 + r;
        if (rr >= Mr) continue;
        float v = acc[mi][ni][r];
        if (bias) v += bias[cc];
        if (resmode == 1) v += resv[(size_t)rr * ldc + cc];
        else if (resmode == 2) v += resv[cc];
        if (OUT_BF) Cb[(size_t)rr * ldc + cc] = (bf16)v;
        else        Cf[(size_t)rr * ldc + cc] = v;
      }
    }
  }
}

// ============================================================
// Block-diagonal MFMA attention, bf16 qkv input [B,N,3072].
// ============================================================
__global__ __launch_bounds__(256) void attn_kernel(
    const bf16* __restrict__ qkv, const int* __restrict__ ids,
    const float* __restrict__ qg, const float* __restrict__ qb,
    const float* __restrict__ kg, const float* __restrict__ kb,
    bf16* __restrict__ o) {
  const int h = blockIdx.x, img = blockIdx.y, b = blockIdx.z;
  const int tid = threadIdx.x, lane = tid & 63, wid = tid >> 6;
  __shared__ __align__(16) bf16 Qs[64][72];
  __shared__ __align__(16) bf16 Ks[64][72];
  __shared__ __align__(16) bf16 Vt[64][72];
  __shared__ __align__(16) bf16 Ps[64][72];
  __shared__ int wlo[4], whi[4];
  __shared__ int sLo, sHi;
  {
    const int want = (img < kM) ? img : -1;
    int lo = kN, hi = -1;
    for (int j = tid; j < kN; j += 256) {
      if (ids[b * kN + j] == want) { lo = min(lo, j); hi = max(hi, j); }
    }
#pragma unroll
    for (int off = 32; off; off >>= 1) {
      lo = min(lo, __shfl_xor(lo, off));
      hi = max(hi, __shfl_xor(hi, off));
    }
    if (lane == 0) { wlo[wid] = lo; whi[wid] = hi; }
    __syncthreads();
    if (tid == 0) {
      sLo = min(min(wlo[0], wlo[1]), min(wlo[2], wlo[3]));
      sHi = max(max(whi[0], whi[1]), max(whi[2], whi[3]));
    }
    __syncthreads();
  }
  if (sHi < 0) return;
  const int start = sLo, T = sHi - sLo + 1;
  if (img == kM) {
    for (int j = start + wid; j <= sHi; j += 4)
      o[((size_t)(b * kN + j)) * kD + h * kDH + lane] = (bf16)0.f;
    return;
  }
#pragma unroll
  for (int it = 0; it < 2; ++it) {
    const int ch = it * 256 + tid;
    const int r = ch >> 3, d0 = (ch & 7) * 8;
    if (r < T) {
      const bf16* base = qkv + ((size_t)(b * kN + start + r)) * 3072 + h * kDH + d0;
      const bf16x8 qv = *(const bf16x8*)(base);
      const bf16x8 kv = *(const bf16x8*)(base + 1024);
      const bf16x8 vv = *(const bf16x8*)(base + 2048);
      float qf[8], kf[8];
      float sq = 0.f, sq2 = 0.f, sk = 0.f, sk2 = 0.f;
#pragma unroll
      for (int e = 0; e < 8; ++e) {
        qf[e] = (float)qv[e]; kf[e] = (float)kv[e];
        sq += qf[e]; sq2 += qf[e] * qf[e];
        sk += kf[e]; sk2 += kf[e] * kf[e];
      }
#pragma unroll
      for (int off = 1; off < 8; off <<= 1) {
        sq += __shfl_xor(sq, off); sq2 += __shfl_xor(sq2, off);
        sk += __shfl_xor(sk, off); sk2 += __shfl_xor(sk2, off);
      }
      const float qm = sq * (1.f / 64);
      const float qr = rsqrtf(sq2 * (1.f / 64) - qm * qm + 1e-5f);
      const float km = sk * (1.f / 64);
      const float kr = rsqrtf(sk2 * (1.f / 64) - km * km + 1e-5f);
      bf16x8 qw, kw;
#pragma unroll
      for (int e = 0; e < 8; ++e) {
        qw[e] = (bf16)((qf[e] - qm) * qr * qg[d0 + e] + qb[d0 + e]);
        kw[e] = (bf16)((kf[e] - km) * kr * kg[d0 + e] + kb[d0 + e]);
      }
      *(bf16x8*)&Qs[r][d0] = qw;
      *(bf16x8*)&Ks[r][d0] = kw;
#pragma unroll
      for (int e = 0; e < 8; ++e) Vt[d0 + e][r] = vv[e];
    } else {
      const bf16x8 z = {};
      *(bf16x8*)&Qs[r][d0] = z;
      *(bf16x8*)&Ks[r][d0] = z;
#pragma unroll
      for (int e = 0; e < 8; ++e) Vt[d0 + e][r] = (bf16)0.f;
    }
  }
  __syncthreads();
  const int fr = lane & 15, fg = lane >> 4;
  const int r0 = wid * 16;
  f32x4 sacc[4] = {};
#pragma unroll
  for (int k0 = 0; k0 < 64; k0 += 32) {
    const bf16x8 aq = *(const bf16x8*)&Qs[r0 + fr][k0 + fg * 8];
#pragma unroll
    for (int ni = 0; ni < 4; ++ni) {
      const bf16x8 bk = *(const bf16x8*)&Ks[ni * 16 + fr][k0 + fg * 8];
      sacc[ni] = __builtin_amdgcn_mfma_f32_16x16x32_bf16(aq, bk, sacc[ni], 0, 0, 0);
    }
  }
  float inv[4];
#pragma unroll
  for (int r = 0; r < 4; ++r) {
    float mx = kNegInf;
#pragma unroll
    for (int ni = 0; ni < 4; ++ni) {
      const float s = (ni * 16 + fr < T) ? sacc[ni][r] * kScale : kNegInf;
      sacc[ni][r] = s;
      mx = fmaxf(mx, s);
    }
#pragma unroll
    for (int off = 1; off < 16; off <<= 1) mx = fmaxf(mx, __shfl_xor(mx, off));
    float sum = 0.f;
#pragma unroll
    for (int ni = 0; ni < 4; ++ni) {
      const float p = __expf(sacc[ni][r] - mx);
      sacc[ni][r] = p;
      sum += p;
    }
#pragma unroll
    for (int off = 1; off < 16; off <<= 1) sum += __shfl_xor(sum, off);
    inv[r] = 1.f / sum;
  }
#pragma unroll
  for (int ni = 0; ni < 4; ++ni)
#pragma unroll
    for (int r = 0; r < 4; ++r)
      Ps[r0 + fg * 4 + r][ni * 16 + fr] = (bf16)sacc[ni][r];
  f32x4 oacc[4] = {};
#pragma unroll
  for (int k0 = 0; k0 < 64; k0 += 32) {
    const bf16x8 ap = *(const bf16x8*)&Ps[r0 + fr][k0 + fg * 8];
#pragma unroll
    for (int ni = 0; ni < 4; ++ni) {
      const bf16x8 bv = *(const bf16x8*)&Vt[ni * 16 + fr][k0 + fg * 8];
      oacc[ni] = __builtin_amdgcn_mfma_f32_16x16x32_bf16(ap, bv, oacc[ni], 0, 0, 0);
    }
  }
#pragma unroll
  for (int r = 0; r < 4; ++r) {
    const int i = r0 + fg * 4 + r;
    if (i < T) {
      const size_t orow = ((size_t)(b * kN + start + i)) * kD + h * kDH;
      const float iv = inv[r];
#pragma unroll
      for (int ni = 0; ni < 4; ++ni)
        o[orow + ni * 16 + fr] = (bf16)(oacc[ni][r] * iv);
    }
  }
}

// ============================================================
// Attention pooling: one wave per (b,m,h). kv bf16 [B,N,2048]. bf16 out.
// ============================================================
__global__ __launch_bounds__(64) void poolattn_kernel(
    const float* __restrict__ qp, const bf16* __restrict__ kv,
    const int* __restrict__ ids, bf16* __restrict__ o) {
  const int blk = blockIdx.x;
  const int h = blk % kH;
  const int bm = blk / kH;
  const int m = bm % kM, b = bm / kM;
  const int lane = threadIdx.x;
  __shared__ float sc[kN];
  __shared__ float qs[kDH];
  qs[lane] = qp[h * kDH + lane];
  __syncthreads();
  float mymax = kNegInf;
  int jmn = kN, jmx = -1;
  for (int j = lane; j < kN; j += 64) {
    const int idj = ids[b * kN + j];
    float s;
    if (idj == m) {
      const bf16* krow = kv + ((size_t)(b * kN + j)) * (2 * kD) + h * kDH;
      float dot = 0.f;
#pragma unroll
      for (int d = 0; d < kDH; ++d) dot += qs[d] * (float)krow[d];
      s = dot * kScale;
      jmn = min(jmn, j); jmx = max(jmx, j);
    } else {
      s = kNegInf;
    }
    sc[j] = s;
    mymax = fmaxf(mymax, s);
  }
#pragma unroll
  for (int off = 32; off; off >>= 1) {
    mymax = fmaxf(mymax, __shfl_xor(mymax, off));
    jmn = min(jmn, __shfl_xor(jmn, off));
    jmx = max(jmx, __shfl_xor(jmx, off));
  }
  const int jlo = jmn, jhi = jmx + 1;
  float mysum = 0.f;
  for (int j = jlo + lane; j < jhi; j += 64) {
    const float p = __expf(sc[j] - mymax);
    sc[j] = p;
    mysum += p;
  }
#pragma unroll
  for (int off = 32; off; off >>= 1) mysum += __shfl_xor(mysum, off);
  const float inv = 1.f / mysum;
  __syncthreads();
  float acc = 0.f;
  const bf16* vptr = kv + ((size_t)(b * kN + jlo)) * (2 * kD) + kD + h * kDH + lane;
  for (int j = jlo; j < jhi; ++j, vptr += 2 * kD) acc += sc[j] * (float)vptr[0];
  o[((size_t)(b * kM + m)) * kD + h * kDH + lane] = (bf16)(acc * inv);
}

// ============================================================
// driver
// ============================================================
extern "C" void kernel_launch(void* const* d_in, const int* in_sizes, int n_in,
                              void* d_out, int out_size, void* d_ws, size_t ws_size,
                              hipStream_t stream) {
  const float* patches  = (const float*)d_in[0];
  const float* pe_ln1_g = (const float*)d_in[1];
  const float* pe_ln1_b = (const float*)d_in[2];
  const float* W_pe     = (const float*)d_in[3];
  const float* b_pe     = (const float*)d_in[4];
  const float* pe_ln2_g = (const float*)d_in[5];
  const float* pe_ln2_b = (const float*)d_in[6];
  const float* pos_h    = (const float*)d_in[7];
  const float* pos_w    = (const float*)d_in[8];
  const float* ln1_g    = (const float*)d_in[9];
  const float* ln1_b    = (const float*)d_in[10];
  const float* qn_g     = (const float*)d_in[11];
  const float* qn_b     = (const float*)d_in[12];
  const float* kn_g     = (const float*)d_in[13];
  const float* kn_b     = (const float*)d_in[14];
  const float* Wq       = (const float*)d_in[15];
  const float* Wkv      = (const float*)d_in[16];
  const float* Wo       = (const float*)d_in[17];
  const float* ln2_g    = (const float*)d_in[18];
  const float* ln2_b    = (const float*)d_in[19];
  const float* W1       = (const float*)d_in[20];
  const float* b1       = (const float*)d_in[21];
  const float* W2       = (const float*)d_in[22];
  const float* b2       = (const float*)d_in[23];
  const float* fin_g    = (const float*)d_in[24];
  const float* fin_b    = (const float*)d_in[25];
  const float* pool_q   = (const float*)d_in[26];
  const float* pl_ln_g  = (const float*)d_in[27];
  const float* pl_ln_b  = (const float*)d_in[28];
  const float* pl_qn_g  = (const float*)d_in[29];
  const float* pl_qn_b  = (const float*)d_in[30];
  const float* pl_kn_g  = (const float*)d_in[31];
  const float* pl_kn_b  = (const float*)d_in[32];
  const float* pl_Wq    = (const float*)d_in[33];
  const float* pl_Wkv   = (const float*)d_in[34];
  const float* pl_Wo    = (const float*)d_in[35];
  const float* head_g   = (const float*)d_in[36];
  const float* head_b   = (const float*)d_in[37];
  const float* W_head   = (const float*)d_in[38];
  const float* b_head   = (const float*)d_in[39];
  const int* h_idx      = (const int*)d_in[40];
  const int* w_idx      = (const int*)d_in[41];
  const int* image_ids  = (const int*)d_in[42];
  float* out = (float*)d_out;

  // ---- workspace layout ----
  const size_t SZ = (size_t)kB * kN * kD;        // 2,621,440
  char* p = (char*)d_ws;
  float* x    = (float*)p;           p += SZ * 4;                 // 10.5 MB
  bf16*  xnb  = (bf16*)p;            p += SZ * 2;                 // 5.2 MB
  char*  scratch = p;                p += 32u * 1024 * 1024;      // 32 MB
  char*  smalls = p;                 p += 1u * 1024 * 1024;       // 1 MB
  bf16*  wtbuf = (bf16*)p;                                        // 112 MB
  // scratch overlays
  bf16*  qkvbb = (bf16*)scratch;                         // [BN][3072] bf16
  bf16*  attno = (bf16*)(scratch + 16u * 1024 * 1024);   // [BN][1024] bf16
  bf16*  plnb  = (bf16*)scratch;                         // [BN][3072] bf16 (embed)
  float* emb   = (float*)(scratch + 16u * 1024 * 1024);  // [BN][1024] f32 (embed)
  bf16*  h1b   = (bf16*)scratch;                         // [BN][2048] bf16 (mlp)
  bf16*  kvpoolb = (bf16*)scratch;                       // [BN][2048] bf16 (pool)
  float* qpool   = (float*)smalls;
  bf16*  opoolb  = (bf16*)(smalls + 8192);
  float* pooled  = (float*)(smalls + 8192 + 163840);
  bf16*  pooledn = (bf16*)(smalls + 8192 + 163840 + 327680);

  const int BN = kB * kN;          // 2560 rows
  const int nbyM = BN / 64;        // 40 row-blocks

  // ---- all weight transposes, one launch ----
  wt_all_kernel<<<dim3(768, 35), 256, 0, stream>>>(
      W_pe, Wq, Wkv, Wo, W1, W2, pl_Wq, pl_Wkv, pl_Wo, W_head, wtbuf);

  // ---- patch embedding ----
  ln_kernel<bf16><<<BN, 256, 0, stream>>>(patches, plnb, pe_ln1_g, pe_ln1_b, kPD);
  gemm64_kernel<2, false, false, false><<<(kD / 64) * nbyM, 256, 0, stream>>>(
      plnb, wtbuf + kOffPe, emb, nullptr, b_pe, nullptr, nullptr, nullptr, kPD, kD, kD / 64);
  ln_pos_kernel<<<BN, 256, 0, stream>>>(emb, x, pe_ln2_g, pe_ln2_b, pos_h, pos_w, h_idx, w_idx);

  // ---- transformer layers ----
  for (int l = 0; l < kDepth; ++l) {
    const bf16* lw = wtbuf + kLayer0 + (size_t)l * kLayerSz;
    ln_kernel<bf16><<<BN, 256, 0, stream>>>(x, xnb, ln1_g + (size_t)l * kD, ln1_b + (size_t)l * kD, kD);
    gemm64_kernel<2, true, false, false><<<(3 * kD / 64) * nbyM, 256, 0, stream>>>(
        xnb, lw, nullptr, qkvbb, nullptr, nullptr, nullptr, nullptr, kD, 3 * kD, 3 * kD / 64);
    attn_kernel<<<dim3(kH, kM + 1, kB), 256, 0, stream>>>(
        qkvbb, image_ids,
        qn_g + (size_t)l * kDH, qn_b + (size_t)l * kDH,
        kn_g + (size_t)l * kDH, kn_b + (size_t)l * kDH, attno);
    gemm64_kernel<2, false, false, false><<<(kD / 64) * nbyM, 256, 0, stream>>>(
        attno, lw + 3 * kMEG, x, nullptr, nullptr, x, nullptr, nullptr, kD, kD, kD / 64);
    ln_kernel<bf16><<<BN, 256, 0, stream>>>(x, xnb, ln2_g + (size_t)l * kD, ln2_b + (size_t)l * kD, kD);
    gemm64_kernel<2, true, true, false><<<(kMLP / 64) * nbyM, 256, 0, stream>>>(
        xnb, lw + 4 * kMEG, nullptr, h1b, b1 + (size_t)l * kMLP, nullptr, nullptr, nullptr, kD, kMLP, kMLP / 64);
    gemm64_kernel<2, false, false, false><<<(kD / 64) * nbyM, 256, 0, stream>>>(
        h1b, lw + 6 * kMEG, x, nullptr, b2 + (size_t)l * kD, x, nullptr, nullptr, kMLP, kD, kD / 64);
  }

  // ---- final LN (context for pooling) ----
  ln_kernel<bf16><<<BN, 256, 0, stream>>>(x, xnb, fin_g, fin_b, kD);

  // ---- attention pooling ----
  poolq_kernel<<<kH, 256, 0, stream>>>(
      pool_q, pl_ln_g, pl_ln_b, wtbuf + kOffPlWq, pl_qn_g, pl_qn_b, qpool);
  // pool kv GEMM with fused per-head LN on k-half (NI=4: head per wave), bf16 out
  gemm64_kernel<4, true, false, true><<<(2 * kD / 128) * nbyM, 256, 0, stream>>>(
      xnb, wtbuf + kOffPlWkv, nullptr, kvpoolb, nullptr, nullptr, pl_kn_g, pl_kn_b, kD, 2 * kD, 2 * kD / 128);
  poolattn_kernel<<<kB * kM * kH, 64, 0, stream>>>(qpool, kvpoolb, image_ids, opoolb);
  gemm_tail_kernel<false><<<dim3(8, 2), 256, 0, stream>>>(
      opoolb, wtbuf + kOffPlWo, pooled, nullptr, nullptr, pool_q, kB * kM, kD, kD, kD, 2);

  // ---- classifier head ----
  ln_kernel<bf16><<<kB * kM, 256, 0, stream>>>(pooled, pooledn, head_g, head_b, kD);
  gemm_tail_kernel<false><<<dim3(8, 2), 256, 0, stream>>>(
      pooledn, wtbuf + kOffHead, out, nullptr, b_head, nullptr, kB * kM, kD, kNC, kNC, 0);
}

// Round 9
// 966.418 us; speedup vs baseline: 8.5263x; 1.0048x over previous
//
#include <hip/hip_runtime.h>
#include <cmath>

// ---- model constants ----
constexpr int kB = 4, kN = 640, kD = 1024, kH = 16, kDH = 64;
constexpr int kDepth = 6, kMLP = 2048, kPD = 3072, kNC = 1000, kM = 18;
constexpr float kScale = 0.125f;        // DH^-0.5
constexpr float kNegInf = -3.4028235e38f;

typedef __bf16 bf16;
typedef __attribute__((ext_vector_type(8))) __bf16 bf16x8;
typedef __attribute__((ext_vector_type(4))) __bf16 bf16x4;
typedef __attribute__((ext_vector_type(4))) float f32x4;

#define AS1 __attribute__((address_space(1)))
#define AS3 __attribute__((address_space(3)))

__device__ __forceinline__ void gload16(const void* g, void* l) {
  __builtin_amdgcn_global_load_lds((AS1 void*)g, (AS3 void*)l, 16, 0, 0);
}

// ---- wtbuf element offsets (bf16 elems) ----
constexpr size_t kMEG = 1048576;
constexpr size_t kOffPe = 0;                              // 3072x1024
constexpr size_t kLayer0 = 3 * kMEG;
constexpr size_t kLayerSz = 8 * kMEG;                     // WqT 1M | WkvT 2M | WoT 1M | W1T 2M | W2T 2M
constexpr size_t kOffPool = kLayer0 + 6 * kLayerSz;
constexpr size_t kOffPlWq = kOffPool;
constexpr size_t kOffPlWkv = kOffPool + 1 * kMEG;
constexpr size_t kOffPlWo = kOffPool + 3 * kMEG;
constexpr size_t kOffHead = kOffPool + 4 * kMEG;

// ============================================================
// Batched weight transpose v3: register transpose, no LDS.
// Tile = 256 n x 64 k per block; lane owns one n-column, reads
// 64 coalesced k-rows, writes 128 B k-contiguous. grid (192, 35).
// ============================================================
__global__ __launch_bounds__(256) void wt_all_kernel(
    const float* __restrict__ pe, const float* __restrict__ wq,
    const float* __restrict__ wkv, const float* __restrict__ wo,
    const float* __restrict__ w1, const float* __restrict__ w2,
    const float* __restrict__ plq, const float* __restrict__ plkv,
    const float* __restrict__ plo, const float* __restrict__ whead,
    bf16* __restrict__ WTB) {
  const int j = blockIdx.y;
  const float* W;
  size_t doff;
  int K, Nc, Np;
  if (j == 0) {
    W = pe; K = 3072; Nc = 1024; Np = 1024; doff = kOffPe;
  } else if (j < 31) {
    const int l = (j - 1) / 5, w = (j - 1) % 5;
    const size_t lbase = kLayer0 + (size_t)l * kLayerSz;
    switch (w) {
      case 0:  W = wq  + (size_t)l * kMEG;     K = 1024; Nc = 1024; doff = lbase;            break;
      case 1:  W = wkv + (size_t)l * 2 * kMEG; K = 1024; Nc = 2048; doff = lbase + kMEG;     break;
      case 2:  W = wo  + (size_t)l * kMEG;     K = 1024; Nc = 1024; doff = lbase + 3 * kMEG; break;
      case 3:  W = w1  + (size_t)l * 2 * kMEG; K = 1024; Nc = 2048; doff = lbase + 4 * kMEG; break;
      default: W = w2  + (size_t)l * 2 * kMEG; K = 2048; Nc = 1024; doff = lbase + 6 * kMEG; break;
    }
    Np = Nc;
  } else if (j == 31) { W = plq;  K = 1024; Nc = 1024; Np = 1024; doff = kOffPlWq; }
  else if (j == 32)   { W = plkv; K = 1024; Nc = 2048; Np = 2048; doff = kOffPlWkv; }
  else if (j == 33)   { W = plo;  K = 1024; Nc = 1024; Np = 1024; doff = kOffPlWo; }
  else                { W = whead; K = 1024; Nc = 1000; Np = 1024; doff = kOffHead; }
  const int nb = Np >> 8;                    // 256-wide n blocks
  const int ntiles = nb * (K >> 6);
  const int tile = blockIdx.x;
  if (tile >= ntiles) return;
  const int n0 = (tile % nb) * 256, k0 = (tile / nb) * 64;
  const int n = n0 + threadIdx.x;
  bf16* WT = WTB + doff;
  bf16x8 ob[8];
  if (n < Nc) {
    const float* src = W + (size_t)k0 * Nc + n;
#pragma unroll
    for (int i = 0; i < 8; ++i) {
#pragma unroll
      for (int e = 0; e < 8; ++e)
        ob[i][e] = (bf16)src[(size_t)(i * 8 + e) * Nc];
    }
  } else {
#pragma unroll
    for (int i = 0; i < 8; ++i) ob[i] = bf16x8{};
  }
  bf16* dst = WT + (size_t)n * K + k0;
#pragma unroll
  for (int i = 0; i < 8; ++i)
    *(bf16x8*)(dst + i * 8) = ob[i];
}

// ============================================================
// Image-span precompute: spans[b][img] = {lo, hi} (hi=-1 if none).
// img == kM is the padding block (id == -1). grid (kM+1, kB), 64 thr.
// ============================================================
__global__ __launch_bounds__(64) void span_kernel(
    const int* __restrict__ ids, int2* __restrict__ spans) {
  const int img = blockIdx.x, b = blockIdx.y;
  const int want = (img < kM) ? img : -1;
  int lo = kN, hi = -1;
  for (int j = threadIdx.x; j < kN; j += 64) {
    if (ids[b * kN + j] == want) { lo = min(lo, j); hi = max(hi, j); }
  }
#pragma unroll
  for (int off = 32; off; off >>= 1) {
    lo = min(lo, __shfl_xor(lo, off));
    hi = max(hi, __shfl_xor(hi, off));
  }
  if (threadIdx.x == 0) spans[b * (kM + 1) + img] = make_int2(lo, hi);
}

// ============================================================
// LayerNorm over last dim K (K%1024==0), float4 loads.
// ============================================================
template <typename OT>
__global__ __launch_bounds__(256) void ln_kernel(
    const float* __restrict__ in, OT* __restrict__ out,
    const float* __restrict__ g, const float* __restrict__ b, int K) {
  const int row = blockIdx.x;
  const float* x = in + (size_t)row * K;
  OT* o = out + (size_t)row * K;
  const int K4 = K >> 2;
  float s = 0.f, s2 = 0.f;
  for (int c = threadIdx.x; c < K4; c += 256) {
    const float4 v = ((const float4*)x)[c];
    s += v.x + v.y + v.z + v.w;
    s2 += v.x * v.x + v.y * v.y + v.z * v.z + v.w * v.w;
  }
#pragma unroll
  for (int off = 32; off; off >>= 1) { s += __shfl_down(s, off); s2 += __shfl_down(s2, off); }
  __shared__ float ls[4], ls2[4];
  __shared__ float sm, sr;
  const int wid = threadIdx.x >> 6, lane = threadIdx.x & 63;
  if (lane == 0) { ls[wid] = s; ls2[wid] = s2; }
  __syncthreads();
  if (threadIdx.x == 0) {
    float a = ls[0] + ls[1] + ls[2] + ls[3];
    float a2 = ls2[0] + ls2[1] + ls2[2] + ls2[3];
    float mean = a / K;
    float var = a2 / K - mean * mean;
    sm = mean; sr = rsqrtf(var + 1e-5f);
  }
  __syncthreads();
  const float mean = sm, r = sr;
  for (int c = threadIdx.x; c < K4; c += 256) {
    const float4 v = ((const float4*)x)[c];
    const float4 gv = ((const float4*)g)[c];
    const float4 bv = ((const float4*)b)[c];
    const int d = c * 4;
    o[d + 0] = (OT)((v.x - mean) * r * gv.x + bv.x);
    o[d + 1] = (OT)((v.y - mean) * r * gv.y + bv.y);
    o[d + 2] = (OT)((v.z - mean) * r * gv.z + bv.z);
    o[d + 3] = (OT)((v.w - mean) * r * gv.w + bv.w);
  }
}

// ============================================================
// Fused pe_ln2 + factorized pos-embed add (f32 out).
// ============================================================
__global__ __launch_bounds__(256) void ln_pos_kernel(
    const float* __restrict__ in, float* __restrict__ out,
    const float* __restrict__ g, const float* __restrict__ b,
    const float* __restrict__ ph, const float* __restrict__ pw,
    const int* __restrict__ hi, const int* __restrict__ wi) {
  const int row = blockIdx.x;
  const float* x = in + (size_t)row * kD;
  float* o = out + (size_t)row * kD;
  const int c = threadIdx.x;
  const float4 v = ((const float4*)x)[c];
  float s = v.x + v.y + v.z + v.w;
  float s2 = v.x * v.x + v.y * v.y + v.z * v.z + v.w * v.w;
#pragma unroll
  for (int off = 32; off; off >>= 1) { s += __shfl_down(s, off); s2 += __shfl_down(s2, off); }
  __shared__ float ls[4], ls2[4];
  __shared__ float sm, sr;
  const int wid = threadIdx.x >> 6, lane = threadIdx.x & 63;
  if (lane == 0) { ls[wid] = s; ls2[wid] = s2; }
  __syncthreads();
  if (threadIdx.x == 0) {
    float a = ls[0] + ls[1] + ls[2] + ls[3];
    float a2 = ls2[0] + ls2[1] + ls2[2] + ls2[3];
    float mean = a / kD;
    float var = a2 / kD - mean * mean;
    sm = mean; sr = rsqrtf(var + 1e-5f);
  }
  __syncthreads();
  const float mean = sm, r = sr;
  const float4* phr = (const float4*)(ph + (size_t)hi[row] * kD);
  const float4* pwr = (const float4*)(pw + (size_t)wi[row] * kD);
  const float4 gv = ((const float4*)g)[c];
  const float4 bv = ((const float4*)b)[c];
  const float4 hv = phr[c], wv = pwr[c];
  float4 ov;
  ov.x = (v.x - mean) * r * gv.x + bv.x + hv.x + wv.x;
  ov.y = (v.y - mean) * r * gv.y + bv.y + hv.y + wv.y;
  ov.z = (v.z - mean) * r * gv.z + bv.z + hv.z + wv.z;
  ov.w = (v.w - mean) * r * gv.w + bv.w + hv.w + wv.w;
  ((float4*)o)[c] = ov;
}

// ============================================================
// Fused pool-query chain: LN(pool_q) -> @pl_Wq^T(bf16) -> head LN.
// ============================================================
__global__ __launch_bounds__(256) void poolq_kernel(
    const float* __restrict__ pq, const float* __restrict__ lg,
    const float* __restrict__ lb, const bf16* __restrict__ WqT,
    const float* __restrict__ qg, const float* __restrict__ qb,
    float* __restrict__ qpool) {
  const int h = blockIdx.x, tid = threadIdx.x;
  __shared__ float qs[1024];
  __shared__ float red[256];
  __shared__ float ls[4], ls2[4];
  __shared__ float sm, sr;
  const float4 v = ((const float4*)pq)[tid];
  float s = v.x + v.y + v.z + v.w;
  float s2 = v.x * v.x + v.y * v.y + v.z * v.z + v.w * v.w;
#pragma unroll
  for (int off = 32; off; off >>= 1) { s += __shfl_down(s, off); s2 += __shfl_down(s2, off); }
  const int wid = tid >> 6, lane = tid & 63;
  if (lane == 0) { ls[wid] = s; ls2[wid] = s2; }
  __syncthreads();
  if (tid == 0) {
    float a = ls[0] + ls[1] + ls[2] + ls[3];
    float a2 = ls2[0] + ls2[1] + ls2[2] + ls2[3];
    float mean = a / kD;
    sm = mean; sr = rsqrtf(a2 / kD - mean * mean + 1e-5f);
  }
  __syncthreads();
  {
    const float mean = sm, r = sr;
    const float4 gv = ((const float4*)lg)[tid];
    const float4 bv = ((const float4*)lb)[tid];
    qs[tid * 4 + 0] = (v.x - mean) * r * gv.x + bv.x;
    qs[tid * 4 + 1] = (v.y - mean) * r * gv.y + bv.y;
    qs[tid * 4 + 2] = (v.z - mean) * r * gv.z + bv.z;
    qs[tid * 4 + 3] = (v.w - mean) * r * gv.w + bv.w;
  }
  __syncthreads();
  const int d = tid & 63, qq = tid >> 6;
  const bf16* wrow = WqT + (size_t)(h * 64 + d) * 1024 + qq * 256;
  const float* qp = qs + qq * 256;
  float part = 0.f;
  for (int k = 0; k < 256; k += 8) {
    const bf16x8 w8 = *(const bf16x8*)(wrow + k);
#pragma unroll
    for (int e = 0; e < 8; ++e) part += qp[k + e] * (float)w8[e];
  }
  red[tid] = part;
  __syncthreads();
  if (tid < 64) {
    const float dot = red[tid] + red[tid + 64] + red[tid + 128] + red[tid + 192];
    float hs = dot, hs2 = dot * dot;
#pragma unroll
    for (int off = 32; off; off >>= 1) { hs += __shfl_xor(hs, off); hs2 += __shfl_xor(hs2, off); }
    const float m = hs * (1.f / kDH);
    const float r = rsqrtf(hs2 * (1.f / kDH) - m * m + 1e-5f);
    qpool[h * 64 + tid] = (dot - m) * r * qg[tid] + qb[tid];
  }
}

// ============================================================
// 64x(NI*32) MFMA GEMM, BK=64, dbuf LDS + global_load_lds prefetch,
// T2 XOR-swizzle, XCD-chunked blockIdx swizzle. HLN: fused per-head
// LayerNorm on the k-half columns (pool kv; NI=4).
// ============================================================
template <int NI, bool OUT_BF, bool GELU, bool HLN>
__global__ __launch_bounds__(256) void gemm64_kernel(
    const bf16* __restrict__ A, const bf16* __restrict__ WT,
    float* __restrict__ Cf, bf16* __restrict__ Cb,
    const float* __restrict__ bias, const float* __restrict__ res,
    const float* __restrict__ hg, const float* __restrict__ hb,
    int K, int Ncol, int nbx) {
  constexpr int BN = NI * 32;
  __shared__ __align__(16) bf16 As[2][64 * 64];
  __shared__ __align__(16) bf16 Bs[2][BN * 64];
  const int tid = threadIdx.x, lane = tid & 63, wid = tid >> 6;
  const int wr = wid >> 1, wc = wid & 1;
  const int cpx = gridDim.x >> 3;
  const int swz = (blockIdx.x & 7) * cpx + (blockIdx.x >> 3);
  const int row0 = (swz / nbx) * 64, col0 = (swz % nbx) * BN;
  const int fr = lane & 15, fg = lane >> 4;
  f32x4 acc[2][NI] = {};
  bf16* sA = As[0]; bf16* sB = Bs[0];
  bf16* dA = As[1]; bf16* dB = Bs[1];

  auto stage = [&](bf16* tA, bf16* tB, int kt) {
#pragma unroll
    for (int i = 0; i < 2; ++i) {
      const int c = i * 256 + tid;
      const int r = c >> 3, ci = c & 7;
      gload16(A + (size_t)(row0 + r) * K + kt + ((ci ^ (r & 7)) * 8),
              tA + (i * 256 + wid * 64) * 8);
    }
#pragma unroll
    for (int i = 0; i < NI; ++i) {
      const int c = i * 256 + tid;
      const int r = c >> 3, ci = c & 7;
      gload16(WT + (size_t)(col0 + r) * K + kt + ((ci ^ (r & 7)) * 8),
              tB + (i * 256 + wid * 64) * 8);
    }
  };
  auto compute = [&](const bf16* tA, const bf16* tB) {
#pragma unroll
    for (int kk = 0; kk < 2; ++kk) {
      bf16x8 af[2], bfr[NI];
#pragma unroll
      for (int mi = 0; mi < 2; ++mi) {
        const int r = wr * 32 + mi * 16 + fr;
        af[mi] = *(const bf16x8*)(tA + r * 64 + (((kk * 4 + fg) ^ (r & 7)) * 8));
      }
#pragma unroll
      for (int ni = 0; ni < NI; ++ni) {
        const int r = wc * (NI * 16) + ni * 16 + fr;
        bfr[ni] = *(const bf16x8*)(tB + r * 64 + (((kk * 4 + fg) ^ (r & 7)) * 8));
      }
#pragma unroll
      for (int mi = 0; mi < 2; ++mi)
#pragma unroll
        for (int ni = 0; ni < NI; ++ni)
          acc[mi][ni] = __builtin_amdgcn_mfma_f32_16x16x32_bf16(af[mi], bfr[ni], acc[mi][ni], 0, 0, 0);
    }
  };

  const int NT = K >> 6;
  stage(sA, sB, 0);
  __syncthreads();
  for (int t = 1; t < NT; ++t) {
    stage(dA, dB, t * 64);
    compute(sA, sB);
    __syncthreads();
    bf16* u;
    u = sA; sA = dA; dA = u;
    u = sB; sB = dB; dB = u;
  }
  compute(sA, sB);

  const int rb = row0 + wr * 32 + fg * 4;
  const int cb = col0 + wc * (NI * 16) + fr;
  float hm[2][4], hr[2][4];
  if (HLN) {
#pragma unroll
    for (int mi = 0; mi < 2; ++mi)
#pragma unroll
      for (int r = 0; r < 4; ++r) {
        float s = 0.f, s2 = 0.f;
#pragma unroll
        for (int ni = 0; ni < NI; ++ni) {
          const float v = acc[mi][ni][r];
          s += v; s2 += v * v;
        }
#pragma unroll
        for (int off = 1; off < 16; off <<= 1) {
          s += __shfl_xor(s, off); s2 += __shfl_xor(s2, off);
        }
        const float m = s * (1.f / kDH);
        hm[mi][r] = m;
        hr[mi][r] = rsqrtf(s2 * (1.f / kDH) - m * m + 1e-5f);
      }
  }
  const bool kHalf = HLN && (cb < kD);
#pragma unroll
  for (int mi = 0; mi < 2; ++mi) {
#pragma unroll
    for (int ni = 0; ni < NI; ++ni) {
      const int cc = cb + ni * 16;
      const float bb = bias ? bias[cc] : 0.f;
      const float hgv = HLN ? hg[ni * 16 + fr] : 0.f;
      const float hbv = HLN ? hb[ni * 16 + fr] : 0.f;
#pragma unroll
      for (int r = 0; r < 4; ++r) {
        const int rr = rb + mi * 16 + r;
        float v = acc[mi][ni][r] + bb;
        if (res) v += res[(size_t)rr * Ncol + cc];
        if (GELU) v = 0.5f * v * (1.f + erff(v * 0.70710678118654752f));
        if (HLN && kHalf) v = (v - hm[mi][r]) * hr[mi][r] * hgv + hbv;
        if (OUT_BF) Cb[(size_t)rr * Ncol + cc] = (bf16)v;
        else        Cf[(size_t)rr * Ncol + cc] = v;
      }
    }
  }
}

// ============================================================
// Guarded tail GEMM (reg-staged 64x128): small M.
// ============================================================
template <bool OUT_BF>
__global__ __launch_bounds__(256) void gemm_tail_kernel(
    const bf16* __restrict__ A, const bf16* __restrict__ WT,
    float* __restrict__ Cf, bf16* __restrict__ Cb,
    const float* __restrict__ bias, const float* __restrict__ resv,
    int Mr, int K, int Nc, int ldc, int resmode) {
  __shared__ __align__(16) bf16 As[64][40];
  __shared__ __align__(16) bf16 Bs[128][40];
  const int tid = threadIdx.x;
  const int lane = tid & 63, wid = tid >> 6;
  const int row0 = blockIdx.y * 64, col0 = blockIdx.x * 128;
  f32x4 acc[4][2] = {};
  const int am = tid >> 2, ako = (tid & 3) * 8;
  const int fr = lane & 15, fg = (lane >> 4) * 8;
  for (int k0 = 0; k0 < K; k0 += 32) {
    if (row0 + am < Mr)
      *(bf16x8*)&As[am][ako] = *(const bf16x8*)(A + (size_t)(row0 + am) * K + k0 + ako);
    else {
      bf16x8 z = {};
      *(bf16x8*)&As[am][ako] = z;
    }
#pragma unroll
    for (int it = 0; it < 2; ++it) {
      const int c = it * 256 + tid;
      const int n = c >> 2, ko = (c & 3) * 8;
      *(bf16x8*)&Bs[n][ko] = *(const bf16x8*)(WT + (size_t)(col0 + n) * K + k0 + ko);
    }
    __syncthreads();
    bf16x8 af[4], bfr[2];
#pragma unroll
    for (int mi = 0; mi < 4; ++mi) af[mi] = *(const bf16x8*)&As[mi * 16 + fr][fg];
#pragma unroll
    for (int ni = 0; ni < 2; ++ni) bfr[ni] = *(const bf16x8*)&Bs[wid * 32 + ni * 16 + fr][fg];
#pragma unroll
    for (int mi = 0; mi < 4; ++mi)
#pragma unroll
      for (int ni = 0; ni < 2; ++ni)
        acc[mi][ni] = __builtin_amdgcn_mfma_f32_16x16x32_bf16(af[mi], bfr[ni], acc[mi][ni], 0, 0, 0);
    __syncthreads();
  }
  const int r4 = (lane >> 4) * 4;
  const int cc0 = col0 + wid * 32 + (lane & 15);
#pragma unroll
  for (int mi = 0; mi < 4; ++mi) {
#pragma unroll
    for (int ni = 0; ni < 2; ++ni) {
      const int cc = cc0 + ni * 16;
      if (cc >= Nc) continue;
#pragma unroll
      for (int r = 0; r < 4; ++r) {
        const int rr = row0 + mi * 16 + r4 + r;
        if (rr >= Mr) continue;
        float v = acc[mi][ni][r];
        if (bias) v += bias[cc];
        if (resmode == 1) v += resv[(size_t)rr * ldc + cc];
        else if (resmode == 2) v += resv[cc];
        if (OUT_BF) Cb[(size_t)rr * ldc + cc] = (bf16)v;
        else        Cf[(size_t)rr * ldc + cc] = v;
      }
    }
  }
}

// ============================================================
// Block-diagonal MFMA attention, bf16 qkv input [B,N,3072].
// Spans precomputed.
// ============================================================
__global__ __launch_bounds__(256) void attn_kernel(
    const bf16* __restrict__ qkv, const int2* __restrict__ spans,
    const float* __restrict__ qg, const float* __restrict__ qb,
    const float* __restrict__ kg, const float* __restrict__ kb,
    bf16* __restrict__ o) {
  const int h = blockIdx.x, img = blockIdx.y, b = blockIdx.z;
  const int tid = threadIdx.x, lane = tid & 63, wid = tid >> 6;
  __shared__ __align__(16) bf16 Qs[64][72];
  __shared__ __align__(16) bf16 Ks[64][72];
  __shared__ __align__(16) bf16 Vt[64][72];
  __shared__ __align__(16) bf16 Ps[64][72];
  const int2 sp = spans[b * (kM + 1) + img];
  if (sp.y < 0) return;
  const int start = sp.x, T = sp.y - sp.x + 1;
  if (img == kM) {
    for (int j = start + wid; j <= sp.y; j += 4)
      o[((size_t)(b * kN + j)) * kD + h * kDH + lane] = (bf16)0.f;
    return;
  }
#pragma unroll
  for (int it = 0; it < 2; ++it) {
    const int ch = it * 256 + tid;
    const int r = ch >> 3, d0 = (ch & 7) * 8;
    if (r < T) {
      const bf16* base = qkv + ((size_t)(b * kN + start + r)) * 3072 + h * kDH + d0;
      const bf16x8 qv = *(const bf16x8*)(base);
      const bf16x8 kv = *(const bf16x8*)(base + 1024);
      const bf16x8 vv = *(const bf16x8*)(base + 2048);
      float qf[8], kf[8];
      float sq = 0.f, sq2 = 0.f, sk = 0.f, sk2 = 0.f;
#pragma unroll
      for (int e = 0; e < 8; ++e) {
        qf[e] = (float)qv[e]; kf[e] = (float)kv[e];
        sq += qf[e]; sq2 += qf[e] * qf[e];
        sk += kf[e]; sk2 += kf[e] * kf[e];
      }
#pragma unroll
      for (int off = 1; off < 8; off <<= 1) {
        sq += __shfl_xor(sq, off); sq2 += __shfl_xor(sq2, off);
        sk += __shfl_xor(sk, off); sk2 += __shfl_xor(sk2, off);
      }
      const float qm = sq * (1.f / 64);
      const float qr = rsqrtf(sq2 * (1.f / 64) - qm * qm + 1e-5f);
      const float km = sk * (1.f / 64);
      const float kr = rsqrtf(sk2 * (1.f / 64) - km * km + 1e-5f);
      bf16x8 qw, kw;
#pragma unroll
      for (int e = 0; e < 8; ++e) {
        qw[e] = (bf16)((qf[e] - qm) * qr * qg[d0 + e] + qb[d0 + e]);
        kw[e] = (bf16)((kf[e] - km) * kr * kg[d0 + e] + kb[d0 + e]);
      }
      *(bf16x8*)&Qs[r][d0] = qw;
      *(bf16x8*)&Ks[r][d0] = kw;
#pragma unroll
      for (int e = 0; e < 8; ++e) Vt[d0 + e][r] = vv[e];
    } else {
      const bf16x8 z = {};
      *(bf16x8*)&Qs[r][d0] = z;
      *(bf16x8*)&Ks[r][d0] = z;
#pragma unroll
      for (int e = 0; e < 8; ++e) Vt[d0 + e][r] = (bf16)0.f;
    }
  }
  __syncthreads();
  const int fr = lane & 15, fg = lane >> 4;
  const int r0 = wid * 16;
  f32x4 sacc[4] = {};
#pragma unroll
  for (int k0 = 0; k0 < 64; k0 += 32) {
    const bf16x8 aq = *(const bf16x8*)&Qs[r0 + fr][k0 + fg * 8];
#pragma unroll
    for (int ni = 0; ni < 4; ++ni) {
      const bf16x8 bk = *(const bf16x8*)&Ks[ni * 16 + fr][k0 + fg * 8];
      sacc[ni] = __builtin_amdgcn_mfma_f32_16x16x32_bf16(aq, bk, sacc[ni], 0, 0, 0);
    }
  }
  float inv[4];
#pragma unroll
  for (int r = 0; r < 4; ++r) {
    float mx = kNegInf;
#pragma unroll
    for (int ni = 0; ni < 4; ++ni) {
      const float s = (ni * 16 + fr < T) ? sacc[ni][r] * kScale : kNegInf;
      sacc[ni][r] = s;
      mx = fmaxf(mx, s);
    }
#pragma unroll
    for (int off = 1; off < 16; off <<= 1) mx = fmaxf(mx, __shfl_xor(mx, off));
    float sum = 0.f;
#pragma unroll
    for (int ni = 0; ni < 4; ++ni) {
      const float p = __expf(sacc[ni][r] - mx);
      sacc[ni][r] = p;
      sum += p;
    }
#pragma unroll
    for (int off = 1; off < 16; off <<= 1) sum += __shfl_xor(sum, off);
    inv[r] = 1.f / sum;
  }
#pragma unroll
  for (int ni = 0; ni < 4; ++ni)
#pragma unroll
    for (int r = 0; r < 4; ++r)
      Ps[r0 + fg * 4 + r][ni * 16 + fr] = (bf16)sacc[ni][r];
  f32x4 oacc[4] = {};
#pragma unroll
  for (int k0 = 0; k0 < 64; k0 += 32) {
    const bf16x8 ap = *(const bf16x8*)&Ps[r0 + fr][k0 + fg * 8];
#pragma unroll
    for (int ni = 0; ni < 4; ++ni) {
      const bf16x8 bv = *(const bf16x8*)&Vt[ni * 16 + fr][k0 + fg * 8];
      oacc[ni] = __builtin_amdgcn_mfma_f32_16x16x32_bf16(ap, bv, oacc[ni], 0, 0, 0);
    }
  }
#pragma unroll
  for (int r = 0; r < 4; ++r) {
    const int i = r0 + fg * 4 + r;
    if (i < T) {
      const size_t orow = ((size_t)(b * kN + start + i)) * kD + h * kDH;
      const float iv = inv[r];
#pragma unroll
      for (int ni = 0; ni < 4; ++ni)
        o[orow + ni * 16 + fr] = (bf16)(oacc[ni][r] * iv);
    }
  }
}

// ============================================================
// Attention pooling: one wave per (b,m,h). kv bf16 [B,N,2048],
// spans precomputed. bf16 out.
// ============================================================
__global__ __launch_bounds__(64) void poolattn_kernel(
    const float* __restrict__ qp, const bf16* __restrict__ kv,
    const int2* __restrict__ spans, bf16* __restrict__ o) {
  const int blk = blockIdx.x;
  const int h = blk % kH;
  const int bm = blk / kH;
  const int m = bm % kM, b = bm / kM;
  const int lane = threadIdx.x;
  __shared__ float sc[kN];
  __shared__ float qs[kDH];
  qs[lane] = qp[h * kDH + lane];
  __syncthreads();
  const int2 sp = spans[b * (kM + 1) + m];
  const int jlo = sp.x, jhi = sp.y + 1;
  float mymax = kNegInf;
  for (int j = jlo + lane; j < jhi; j += 64) {
    const bf16* krow = kv + ((size_t)(b * kN + j)) * (2 * kD) + h * kDH;
    float dot = 0.f;
#pragma unroll
    for (int d = 0; d < kDH; ++d) dot += qs[d] * (float)krow[d];
    const float s = dot * kScale;
    sc[j] = s;
    mymax = fmaxf(mymax, s);
  }
#pragma unroll
  for (int off = 32; off; off >>= 1) mymax = fmaxf(mymax, __shfl_xor(mymax, off));
  float mysum = 0.f;
  for (int j = jlo + lane; j < jhi; j += 64) {
    const float p = __expf(sc[j] - mymax);
    sc[j] = p;
    mysum += p;
  }
#pragma unroll
  for (int off = 32; off; off >>= 1) mysum += __shfl_xor(mysum, off);
  const float inv = 1.f / mysum;
  __syncthreads();
  float acc = 0.f;
  const bf16* vptr = kv + ((size_t)(b * kN + jlo)) * (2 * kD) + kD + h * kDH + lane;
  for (int j = jlo; j < jhi; ++j, vptr += 2 * kD) acc += sc[j] * (float)vptr[0];
  o[((size_t)(b * kM + m)) * kD + h * kDH + lane] = (bf16)(acc * inv);
}

// ============================================================
// driver
// ============================================================
extern "C" void kernel_launch(void* const* d_in, const int* in_sizes, int n_in,
                              void* d_out, int out_size, void* d_ws, size_t ws_size,
                              hipStream_t stream) {
  const float* patches  = (const float*)d_in[0];
  const float* pe_ln1_g = (const float*)d_in[1];
  const float* pe_ln1_b = (const float*)d_in[2];
  const float* W_pe     = (const float*)d_in[3];
  const float* b_pe     = (const float*)d_in[4];
  const float* pe_ln2_g = (const float*)d_in[5];
  const float* pe_ln2_b = (const float*)d_in[6];
  const float* pos_h    = (const float*)d_in[7];
  const float* pos_w    = (const float*)d_in[8];
  const float* ln1_g    = (const float*)d_in[9];
  const float* ln1_b    = (const float*)d_in[10];
  const float* qn_g     = (const float*)d_in[11];
  const float* qn_b     = (const float*)d_in[12];
  const float* kn_g     = (const float*)d_in[13];
  const float* kn_b     = (const float*)d_in[14];
  const float* Wq       = (const float*)d_in[15];
  const float* Wkv      = (const float*)d_in[16];
  const float* Wo       = (const float*)d_in[17];
  const float* ln2_g    = (const float*)d_in[18];
  const float* ln2_b    = (const float*)d_in[19];
  const float* W1       = (const float*)d_in[20];
  const float* b1       = (const float*)d_in[21];
  const float* W2       = (const float*)d_in[22];
  const float* b2       = (const float*)d_in[23];
  const float* fin_g    = (const float*)d_in[24];
  const float* fin_b    = (const float*)d_in[25];
  const float* pool_q   = (const float*)d_in[26];
  const float* pl_ln_g  = (const float*)d_in[27];
  const float* pl_ln_b  = (const float*)d_in[28];
  const float* pl_qn_g  = (const float*)d_in[29];
  const float* pl_qn_b  = (const float*)d_in[30];
  const float* pl_kn_g  = (const float*)d_in[31];
  const float* pl_kn_b  = (const float*)d_in[32];
  const float* pl_Wq    = (const float*)d_in[33];
  const float* pl_Wkv   = (const float*)d_in[34];
  const float* pl_Wo    = (const float*)d_in[35];
  const float* head_g   = (const float*)d_in[36];
  const float* head_b   = (const float*)d_in[37];
  const float* W_head   = (const float*)d_in[38];
  const float* b_head   = (const float*)d_in[39];
  const int* h_idx      = (const int*)d_in[40];
  const int* w_idx      = (const int*)d_in[41];
  const int* image_ids  = (const int*)d_in[42];
  float* out = (float*)d_out;

  // ---- workspace layout ----
  const size_t SZ = (size_t)kB * kN * kD;        // 2,621,440
  char* p = (char*)d_ws;
  float* x    = (float*)p;           p += SZ * 4;                 // 10.5 MB
  bf16*  xnb  = (bf16*)p;            p += SZ * 2;                 // 5.2 MB
  char*  scratch = p;                p += 32u * 1024 * 1024;      // 32 MB
  char*  smalls = p;                 p += 1u * 1024 * 1024;       // 1 MB
  bf16*  wtbuf = (bf16*)p;                                        // 112 MB
  // scratch overlays
  bf16*  qkvbb = (bf16*)scratch;                         // [BN][3072] bf16
  bf16*  attno = (bf16*)(scratch + 16u * 1024 * 1024);   // [BN][1024] bf16
  bf16*  plnb  = (bf16*)scratch;                         // [BN][3072] bf16 (embed)
  float* emb   = (float*)(scratch + 16u * 1024 * 1024);  // [BN][1024] f32 (embed)
  bf16*  h1b   = (bf16*)scratch;                         // [BN][2048] bf16 (mlp)
  bf16*  kvpoolb = (bf16*)scratch;                       // [BN][2048] bf16 (pool)
  float* qpool   = (float*)smalls;
  bf16*  opoolb  = (bf16*)(smalls + 8192);
  float* pooled  = (float*)(smalls + 8192 + 163840);
  bf16*  pooledn = (bf16*)(smalls + 8192 + 163840 + 327680);
  int2*  spans   = (int2*)(smalls + 8192 + 163840 + 327680 + 163840);

  const int BN = kB * kN;          // 2560 rows
  const int nbyM = BN / 64;        // 40 row-blocks

  // ---- spans + all weight transposes (off critical path) ----
  span_kernel<<<dim3(kM + 1, kB), 64, 0, stream>>>(image_ids, spans);
  wt_all_kernel<<<dim3(192, 35), 256, 0, stream>>>(
      W_pe, Wq, Wkv, Wo, W1, W2, pl_Wq, pl_Wkv, pl_Wo, W_head, wtbuf);

  // ---- patch embedding ----
  ln_kernel<bf16><<<BN, 256, 0, stream>>>(patches, plnb, pe_ln1_g, pe_ln1_b, kPD);
  gemm64_kernel<2, false, false, false><<<(kD / 64) * nbyM, 256, 0, stream>>>(
      plnb, wtbuf + kOffPe, emb, nullptr, b_pe, nullptr, nullptr, nullptr, kPD, kD, kD / 64);
  ln_pos_kernel<<<BN, 256, 0, stream>>>(emb, x, pe_ln2_g, pe_ln2_b, pos_h, pos_w, h_idx, w_idx);

  // ---- transformer layers ----
  for (int l = 0; l < kDepth; ++l) {
    const bf16* lw = wtbuf + kLayer0 + (size_t)l * kLayerSz;
    ln_kernel<bf16><<<BN, 256, 0, stream>>>(x, xnb, ln1_g + (size_t)l * kD, ln1_b + (size_t)l * kD, kD);
    gemm64_kernel<2, true, false, false><<<(3 * kD / 64) * nbyM, 256, 0, stream>>>(
        xnb, lw, nullptr, qkvbb, nullptr, nullptr, nullptr, nullptr, kD, 3 * kD, 3 * kD / 64);
    attn_kernel<<<dim3(kH, kM + 1, kB), 256, 0, stream>>>(
        qkvbb, spans,
        qn_g + (size_t)l * kDH, qn_b + (size_t)l * kDH,
        kn_g + (size_t)l * kDH, kn_b + (size_t)l * kDH, attno);
    gemm64_kernel<2, false, false, false><<<(kD / 64) * nbyM, 256, 0, stream>>>(
        attno, lw + 3 * kMEG, x, nullptr, nullptr, x, nullptr, nullptr, kD, kD, kD / 64);
    ln_kernel<bf16><<<BN, 256, 0, stream>>>(x, xnb, ln2_g + (size_t)l * kD, ln2_b + (size_t)l * kD, kD);
    gemm64_kernel<2, true, true, false><<<(kMLP / 64) * nbyM, 256, 0, stream>>>(
        xnb, lw + 4 * kMEG, nullptr, h1b, b1 + (size_t)l * kMLP, nullptr, nullptr, nullptr, kD, kMLP, kMLP / 64);
    gemm64_kernel<2, false, false, false><<<(kD / 64) * nbyM, 256, 0, stream>>>(
        h1b, lw + 6 * kMEG, x, nullptr, b2 + (size_t)l * kD, x, nullptr, nullptr, kMLP, kD, kD / 64);
  }

  // ---- final LN (context for pooling) ----
  ln_kernel<bf16><<<BN, 256, 0, stream>>>(x, xnb, fin_g, fin_b, kD);

  // ---- attention pooling ----
  poolq_kernel<<<kH, 256, 0, stream>>>(
      pool_q, pl_ln_g, pl_ln_b, wtbuf + kOffPlWq, pl_qn_g, pl_qn_b, qpool);
  gemm64_kernel<4, true, false, true><<<(2 * kD / 128) * nbyM, 256, 0, stream>>>(
      xnb, wtbuf + kOffPlWkv, nullptr, kvpoolb, nullptr, nullptr, pl_kn_g, pl_kn_b, kD, 2 * kD, 2 * kD / 128);
  poolattn_kernel<<<kB * kM * kH, 64, 0, stream>>>(qpool, kvpoolb, spans, opoolb);
  gemm_tail_kernel<false><<<dim3(8, 2), 256, 0, stream>>>(
      opoolb, wtbuf + kOffPlWo, pooled, nullptr, nullptr, pool_q, kB * kM, kD, kD, kD, 2);

  // ---- classifier head ----
  ln_kernel<bf16><<<kB * kM, 256, 0, stream>>>(pooled, pooledn, head_g, head_b, kD);
  gemm_tail_kernel<false><<<dim3(8, 2), 256, 0, stream>>>(
      pooledn, wtbuf + kOffHead, out, nullptr, b_head, nullptr, kB * kM, kD, kNC, kNC, 0);
}